// Round 1
// baseline (551.004 us; speedup 1.0000x reference)
//
#include <hip/hip_runtime.h>
#include <hip/hip_bf16.h>
#include <math.h>

typedef __bf16 bf16;
typedef __attribute__((ext_vector_type(8))) __bf16 bf16x8;
typedef __attribute__((ext_vector_type(4))) __bf16 bf16x4;
typedef __attribute__((ext_vector_type(4))) float f32x4;

// ---------------------------------------------------------------- LN + route
// One block per token. Computes LayerNorm row (f32 in LDS, bf16 to global),
// then per-wave: 16 expert logits (dot over 1024), online softmax, and
// importance-weighted atomic accumulation into route_acc[slot][5][B][16].
__global__ __launch_bounds__(256) void ln_route_kernel(
    const float* __restrict__ x, const float* __restrict__ gam, const float* __restrict__ bet,
    const float* __restrict__ Wg, const float* __restrict__ imp,
    bf16* __restrict__ nxo, float* __restrict__ racc, int ngroups, int gbase)
{
  const int token = blockIdx.x;
  const int b = token >> 11;                 // S = 2048
  const int t = threadIdx.x, w = t >> 6, l = t & 63;
  __shared__ alignas(16) float row[1024];
  __shared__ float red1[4], red2[4];
  float4 xv = ((const float4*)(x + (size_t)token * 1024))[t];
  float s  = xv.x + xv.y + xv.z + xv.w;
  float sq = xv.x*xv.x + xv.y*xv.y + xv.z*xv.z + xv.w*xv.w;
  #pragma unroll
  for (int off = 32; off > 0; off >>= 1) { s += __shfl_xor(s, off); sq += __shfl_xor(sq, off); }
  if (l == 0) { red1[w] = s; red2[w] = sq; }
  __syncthreads();
  s  = red1[0] + red1[1] + red1[2] + red1[3];
  sq = red2[0] + red2[1] + red2[2] + red2[3];
  const float mu  = s * (1.f / 1024.f);
  const float var = sq * (1.f / 1024.f) - mu * mu;
  const float rs  = rsqrtf(var + 1e-5f);
  float4 gv = ((const float4*)gam)[t];
  float4 bv = ((const float4*)bet)[t];
  float n0 = (xv.x - mu) * rs * gv.x + bv.x;
  float n1 = (xv.y - mu) * rs * gv.y + bv.y;
  float n2 = (xv.z - mu) * rs * gv.z + bv.z;
  float n3 = (xv.w - mu) * rs * gv.w + bv.w;
  row[t*4+0] = n0; row[t*4+1] = n1; row[t*4+2] = n2; row[t*4+3] = n3;
  bf16x4 pk = {(bf16)n0, (bf16)n1, (bf16)n2, (bf16)n3};
  *(bf16x4*)(nxo + (size_t)token * 1024 + t * 4) = pk;
  __syncthreads();
  if (w < ngroups) {
    const float* Wbase = Wg + (size_t)w * 16 * 1024;
    float m_run = -INFINITY, s_run = 0.f, myv = 0.f;
    for (int e = 0; e < 16; ++e) {
      const float* wr = Wbase + e * 1024;
      float dv = 0.f;
      #pragma unroll
      for (int i = 0; i < 16; ++i) dv += row[l + i*64] * wr[l + i*64];
      #pragma unroll
      for (int off = 32; off > 0; off >>= 1) dv += __shfl_xor(dv, off);
      if (l == e) myv = dv;
      float mn = fmaxf(m_run, dv);
      s_run = s_run * __expf(m_run - mn) + __expf(dv - mn);
      m_run = mn;
    }
    if (l < 16) {
      float pref = __expf(myv - m_run) / s_run;
      atomicAdd(racc + ((((size_t)(token & 31)) * 5 + gbase + w) * 2 + b) * 16 + l,
                imp[token] * pref);
    }
  }
}

// ------------------------------------------------------------- route norm
__global__ void route_norm_kernel(const float* __restrict__ racc, float* __restrict__ rw,
                                  int g0, int ng)
{
  __shared__ float pooled[5][2][16];
  const int t = threadIdx.x;
  const int n = ng * 32;
  int g = 0, b = 0, e = 0;
  if (t < n) {
    g = g0 + (t >> 5); b = (t >> 4) & 1; e = t & 15;
    float s = 0.f;
    for (int sl = 0; sl < 32; ++sl) s += racc[(((size_t)sl * 5 + g) * 2 + b) * 16 + e];
    pooled[g][b][e] = s;
  }
  __syncthreads();
  if (t < n) {
    float den = 1e-8f;
    #pragma unroll
    for (int e2 = 0; e2 < 16; ++e2) den += pooled[g][b][e2];
    rw[((size_t)g * 2 + b) * 16 + e] = pooled[g][b][e] / den;
  }
}

// ----------------------------------------------------- pool mix (transposed)
// out[b][d2][d1] = sum_n w[b][n] * pool[n][d1][d2]   (bf16 out)
__global__ __launch_bounds__(256) void mix_t_kernel(
    const float* __restrict__ pool, const float* __restrict__ rwg,
    bf16* __restrict__ out, int dim1, int dim2)
{
  const int i0 = blockIdx.x * 64, j0 = blockIdx.y * 64, b = blockIdx.z;
  const int t = threadIdx.x;
  __shared__ float tile[64][65];
  float wn[16];
  #pragma unroll
  for (int n = 0; n < 16; ++n) wn[n] = rwg[b * 16 + n];
  float acc[16];
  #pragma unroll
  for (int k = 0; k < 16; ++k) acc[k] = 0.f;
  const int lj = t & 63, li = t >> 6;
  for (int n = 0; n < 16; ++n) {
    __syncthreads();
    #pragma unroll
    for (int it = 0; it < 16; ++it)
      tile[li + it*4][lj] = pool[((size_t)n * dim1 + i0 + li + it*4) * dim2 + j0 + lj];
    __syncthreads();
    const float wv = wn[n];
    #pragma unroll
    for (int it = 0; it < 16; ++it)
      acc[it] += wv * tile[lj][li + it*4];
  }
  #pragma unroll
  for (int it = 0; it < 16; ++it)
    out[((size_t)b * dim2 + j0 + li + it*4) * dim1 + i0 + lj] = (bf16)acc[it];
}

// ------------------------------------------------------------ f32 -> bf16
__global__ void cvt_bf16_kernel(const float* __restrict__ in, bf16* __restrict__ out, int n4)
{
  const int i = blockIdx.x * 256 + threadIdx.x;
  if (i < n4) {
    float4 v = ((const float4*)in)[i];
    bf16x4 o = {(bf16)v.x, (bf16)v.y, (bf16)v.z, (bf16)v.w};
    ((bf16x4*)out)[i] = o;
  }
}

// --------------------------------------------------------------- GEMM (Bt)
// C[M,N] = A[M,K] * Bt[N,K]^T ; 128x128 tile, BK=32, 4 waves 2x2, MFMA
// 16x16x32 bf16. CMODE: 0 = bf16 out, 1 = f32 out, 2 = f32 out + f32 resid.
template<int CMODE>
__global__ __launch_bounds__(256) void gemm_bt(
    const bf16* __restrict__ A, const bf16* __restrict__ Bt, void* __restrict__ Cp,
    const float* __restrict__ resid, int M, int N, int K,
    long sA, long sB, long sC, float scale)
{
  __shared__ alignas(16) bf16 As[128 * 32];
  __shared__ alignas(16) bf16 Bs[128 * 32];
  const int t = threadIdx.x, w = t >> 6, l = t & 63;
  const int llo = l & 15, lhi = l >> 4;
  const int wm = w >> 1, wn = w & 1;
  const int m0 = blockIdx.y * 128, n0 = blockIdx.x * 128;
  const bf16* Ab = A  + (size_t)blockIdx.z * sA;
  const bf16* Bb = Bt + (size_t)blockIdx.z * sB;
  f32x4 acc[4][4];
  #pragma unroll
  for (int i = 0; i < 4; ++i)
    #pragma unroll
    for (int j = 0; j < 4; ++j) acc[i][j] = (f32x4){0.f, 0.f, 0.f, 0.f};

  const int arow = t >> 2, akb = t & 3;          // 64 rows/pass, 4x16B per row
  const bf16* asrc = Ab + (size_t)(m0 + arow) * K + akb * 8;
  const bf16* bsrc = Bb + (size_t)(n0 + arow) * K + akb * 8;
  const size_t rstep = (size_t)64 * K;
  const int aoff0 = arow * 64 + ((akb * 16) ^ (((arow >> 1) & 3) << 4));
  const int aoff1 = aoff0 + 64 * 64;

  uint4 a0 = *(const uint4*)(asrc);
  uint4 a1 = *(const uint4*)(asrc + rstep);
  uint4 b0 = *(const uint4*)(bsrc);
  uint4 b1 = *(const uint4*)(bsrc + rstep);

  for (int kt = 0; kt < K; kt += 32) {
    __syncthreads();
    *(uint4*)((char*)As + aoff0) = a0;
    *(uint4*)((char*)As + aoff1) = a1;
    *(uint4*)((char*)Bs + aoff0) = b0;
    *(uint4*)((char*)Bs + aoff1) = b1;
    __syncthreads();
    if (kt + 32 < K) {
      a0 = *(const uint4*)(asrc + kt + 32);
      a1 = *(const uint4*)(asrc + rstep + kt + 32);
      b0 = *(const uint4*)(bsrc + kt + 32);
      b1 = *(const uint4*)(bsrc + rstep + kt + 32);
    }
    bf16x8 af[4], bfr[4];
    #pragma unroll
    for (int fi = 0; fi < 4; ++fi) {
      int r = wm * 64 + fi * 16 + llo;
      af[fi] = *(const bf16x8*)((const char*)As + (r * 64 + ((lhi * 16) ^ (((r >> 1) & 3) << 4))));
      int c = wn * 64 + fi * 16 + llo;
      bfr[fi] = *(const bf16x8*)((const char*)Bs + (c * 64 + ((lhi * 16) ^ (((c >> 1) & 3) << 4))));
    }
    #pragma unroll
    for (int fi = 0; fi < 4; ++fi)
      #pragma unroll
      for (int fj = 0; fj < 4; ++fj)
        acc[fi][fj] = __builtin_amdgcn_mfma_f32_16x16x32_bf16(af[fi], bfr[fj], acc[fi][fj], 0, 0, 0);
  }

  #pragma unroll
  for (int fi = 0; fi < 4; ++fi)
    #pragma unroll
    for (int fj = 0; fj < 4; ++fj)
      #pragma unroll
      for (int jj = 0; jj < 4; ++jj) {
        int r = m0 + wm * 64 + fi * 16 + lhi * 4 + jj;
        int c = n0 + wn * 64 + fj * 16 + llo;
        size_t idx = (size_t)blockIdx.z * sC + (size_t)r * N + c;
        float v = acc[fi][fj][jj] * scale;
        if (CMODE == 0) {
          ((bf16*)Cp)[idx] = (bf16)v;
        } else {
          if (CMODE == 2) v += resid[idx];
          ((float*)Cp)[idx] = v;
        }
      }
}

// ----------------------------------------------------------- flash attention
// grid (S/128, H, B). 4 waves x 32 q-rows. KV tiles of 64. K/V/P in LDS with
// XOR swizzle (128B rows would otherwise 16-way bank-conflict on b128 reads).
__global__ __launch_bounds__(256) void attn_kernel(
    const bf16* __restrict__ Qg, const bf16* __restrict__ Kg,
    const bf16* __restrict__ Vg, bf16* __restrict__ aog)
{
  const int qt = blockIdx.x, h = blockIdx.y, b = blockIdx.z;
  const int q0 = qt * 128;
  const int t = threadIdx.x, w = t >> 6, l = t & 63;
  const int llo = l & 15, lhi = l >> 4;
  __shared__ alignas(16) bf16 Ks[64 * 64];
  __shared__ alignas(16) bf16 Vt[64 * 64];     // [d][kv]
  __shared__ alignas(16) bf16 Ps[4][32 * 64];  // per-wave P tile
  const int qw = q0 + w * 32;

  bf16x8 qf[2][2];
  {
    const bf16* Qb = Qg + ((size_t)(b * 2048 + qw)) * 1024 + h * 64;
    #pragma unroll
    for (int fi = 0; fi < 2; ++fi)
      #pragma unroll
      for (int ks = 0; ks < 2; ++ks)
        qf[fi][ks] = *(const bf16x8*)(Qb + (size_t)(fi * 16 + llo) * 1024 + ks * 32 + lhi * 8);
  }

  float mm[2][4], ll[2][4];
  f32x4 o[2][4];
  #pragma unroll
  for (int i = 0; i < 2; ++i)
    #pragma unroll
    for (int j = 0; j < 4; ++j) { mm[i][j] = -INFINITY; ll[i][j] = 0.f; o[i][j] = (f32x4){0.f,0.f,0.f,0.f}; }

  const int nkv = q0 + 128;
  const int srow = t >> 3;            // 0..31
  const int sc8  = (t & 7) * 8;       // col base (elems)
  uint4 kreg[2]; bf16x8 vreg[2];
  auto prefetch = [&](int kv0) {
    #pragma unroll
    for (int p = 0; p < 2; ++p) {
      int r = p * 32 + srow;
      const bf16* kp = Kg + ((size_t)(b * 2048 + kv0 + r)) * 1024 + h * 64 + sc8;
      kreg[p] = *(const uint4*)kp;
      const bf16* vp = Vg + ((size_t)(b * 2048 + kv0 + r)) * 1024 + h * 64 + sc8;
      vreg[p] = *(const bf16x8*)vp;
    }
  };
  prefetch(0);

  for (int kv0 = 0; kv0 < nkv; kv0 += 64) {
    __syncthreads();
    #pragma unroll
    for (int p = 0; p < 2; ++p) {
      int r = p * 32 + srow;
      *(uint4*)((char*)Ks + ((r * 128 + sc8 * 2) ^ ((r & 7) << 4))) = kreg[p];
      #pragma unroll
      for (int j = 0; j < 8; ++j) {
        int d = sc8 + j;
        *(bf16*)((char*)Vt + ((d * 128 + r * 2) ^ ((d & 7) << 4))) = vreg[p][j];
      }
    }
    __syncthreads();
    if (kv0 + 64 < nkv) prefetch(kv0 + 64);

    if (kv0 <= qw + 31) {
      f32x4 sc[2][4];
      #pragma unroll
      for (int i = 0; i < 2; ++i)
        #pragma unroll
        for (int j = 0; j < 4; ++j) sc[i][j] = (f32x4){0.f,0.f,0.f,0.f};
      #pragma unroll
      for (int ks = 0; ks < 2; ++ks) {
        bf16x8 kf[4];
        #pragma unroll
        for (int kvt = 0; kvt < 4; ++kvt) {
          int r = kvt * 16 + llo;
          kf[kvt] = *(const bf16x8*)((const char*)Ks + ((r * 128 + ks * 64 + lhi * 16) ^ ((r & 7) << 4)));
        }
        #pragma unroll
        for (int fi = 0; fi < 2; ++fi)
          #pragma unroll
          for (int kvt = 0; kvt < 4; ++kvt)
            sc[fi][kvt] = __builtin_amdgcn_mfma_f32_16x16x32_bf16(qf[fi][ks], kf[kvt], sc[fi][kvt], 0, 0, 0);
      }
      const bool needmask = (kv0 + 63 > qw);
      bf16* Pw = Ps[w];
      #pragma unroll
      for (int fi = 0; fi < 2; ++fi) {
        #pragma unroll
        for (int jj = 0; jj < 4; ++jj) {
          float s0 = sc[fi][0][jj] * 0.125f, s1 = sc[fi][1][jj] * 0.125f;
          float s2 = sc[fi][2][jj] * 0.125f, s3 = sc[fi][3][jj] * 0.125f;
          if (needmask) {
            int qq = qw + fi * 16 + lhi * 4 + jj;
            if (kv0 +  0 + llo > qq) s0 = -INFINITY;
            if (kv0 + 16 + llo > qq) s1 = -INFINITY;
            if (kv0 + 32 + llo > qq) s2 = -INFINITY;
            if (kv0 + 48 + llo > qq) s3 = -INFINITY;
          }
          float tm = fmaxf(fmaxf(s0, s1), fmaxf(s2, s3));
          #pragma unroll
          for (int off = 1; off < 16; off <<= 1) tm = fmaxf(tm, __shfl_xor(tm, off));
          float mn = fmaxf(mm[fi][jj], tm);
          float alpha = __expf(mm[fi][jj] - mn);
          mm[fi][jj] = mn;
          float p0 = __expf(s0 - mn), p1 = __expf(s1 - mn);
          float p2 = __expf(s2 - mn), p3 = __expf(s3 - mn);
          float rsm = p0 + p1 + p2 + p3;
          #pragma unroll
          for (int off = 1; off < 16; off <<= 1) rsm += __shfl_xor(rsm, off);
          ll[fi][jj] = ll[fi][jj] * alpha + rsm;
          #pragma unroll
          for (int df = 0; df < 4; ++df) o[fi][df][jj] *= alpha;
          int qq2 = fi * 16 + lhi * 4 + jj;
          *(bf16*)((char*)Pw + ((qq2 * 128 + ( 0 + llo) * 2) ^ ((qq2 & 7) << 4))) = (bf16)p0;
          *(bf16*)((char*)Pw + ((qq2 * 128 + (16 + llo) * 2) ^ ((qq2 & 7) << 4))) = (bf16)p1;
          *(bf16*)((char*)Pw + ((qq2 * 128 + (32 + llo) * 2) ^ ((qq2 & 7) << 4))) = (bf16)p2;
          *(bf16*)((char*)Pw + ((qq2 * 128 + (48 + llo) * 2) ^ ((qq2 & 7) << 4))) = (bf16)p3;
        }
      }
      #pragma unroll
      for (int ks2 = 0; ks2 < 2; ++ks2) {
        bf16x8 pf[2], vf[4];
        #pragma unroll
        for (int fi = 0; fi < 2; ++fi) {
          int r = fi * 16 + llo;
          pf[fi] = *(const bf16x8*)((const char*)Pw + ((r * 128 + ks2 * 64 + lhi * 16) ^ ((r & 7) << 4)));
        }
        #pragma unroll
        for (int df = 0; df < 4; ++df) {
          int d = df * 16 + llo;
          vf[df] = *(const bf16x8*)((const char*)Vt + ((d * 128 + ks2 * 64 + lhi * 16) ^ ((d & 7) << 4)));
        }
        #pragma unroll
        for (int fi = 0; fi < 2; ++fi)
          #pragma unroll
          for (int df = 0; df < 4; ++df)
            o[fi][df] = __builtin_amdgcn_mfma_f32_16x16x32_bf16(pf[fi], vf[df], o[fi][df], 0, 0, 0);
      }
    }
  }

  #pragma unroll
  for (int fi = 0; fi < 2; ++fi)
    #pragma unroll
    for (int jj = 0; jj < 4; ++jj) {
      float inv = 1.0f / ll[fi][jj];
      int qq = qw + fi * 16 + lhi * 4 + jj;
      bf16* op = aog + ((size_t)(b * 2048 + qq)) * 1024 + h * 64 + llo;
      #pragma unroll
      for (int df = 0; df < 4; ++df)
        op[df * 16] = (bf16)(o[fi][df][jj] * inv);
    }
}

// ------------------------------------------------------------------ top-k
// One block per token: iterative top-8 extraction over 4096 scores (ties ->
// lower index, matching lax.top_k), softmax, gather of knowledge_V, add into out.
__global__ __launch_bounds__(256) void topk_kernel(
    const float* __restrict__ ms, const float* __restrict__ kV, float* __restrict__ outp)
{
  const int token = blockIdx.x;
  const int t = threadIdx.x, w = t >> 6, l = t & 63;
  __shared__ alignas(16) float row[4096];
  __shared__ float wv[8]; __shared__ int wi[8];
  __shared__ float cand[4]; __shared__ int candi[4];
  const float* mrow = ms + (size_t)token * 4096;
  #pragma unroll
  for (int p = 0; p < 4; ++p) {
    float4 v = ((const float4*)mrow)[t + p * 256];
    *(float4*)&row[(t + p * 256) * 4] = v;
  }
  __syncthreads();
  for (int k = 0; k < 8; ++k) {
    float bv = -INFINITY; int bi = 0;
    for (int i = t; i < 4096; i += 256) {
      float v = row[i];
      if (v > bv) { bv = v; bi = i; }
    }
    #pragma unroll
    for (int off = 32; off > 0; off >>= 1) {
      float ov = __shfl_xor(bv, off); int oi = __shfl_xor(bi, off);
      if (ov > bv || (ov == bv && oi < bi)) { bv = ov; bi = oi; }
    }
    if (l == 0) { cand[w] = bv; candi[w] = bi; }
    __syncthreads();
    if (t == 0) {
      float best = cand[0]; int besti = candi[0];
      for (int q = 1; q < 4; ++q)
        if (cand[q] > best || (cand[q] == best && candi[q] < besti)) { best = cand[q]; besti = candi[q]; }
      wv[k] = best; wi[k] = besti; row[besti] = -INFINITY;
    }
    __syncthreads();
  }
  if (t == 0) {
    float m = wv[0];
    #pragma unroll
    for (int k = 1; k < 8; ++k) m = fmaxf(m, wv[k]);
    float sden = 0.f; float ex[8];
    #pragma unroll
    for (int k = 0; k < 8; ++k) { ex[k] = __expf(wv[k] - m); sden += ex[k]; }
    #pragma unroll
    for (int k = 0; k < 8; ++k) wv[k] = ex[k] / sden;
  }
  __syncthreads();
  float a0 = 0, a1 = 0, a2 = 0, a3 = 0;
  #pragma unroll
  for (int k = 0; k < 8; ++k) {
    float wk = wv[k];
    float4 vr = *(const float4*)(kV + (size_t)wi[k] * 1024 + t * 4);
    a0 += wk * vr.x; a1 += wk * vr.y; a2 += wk * vr.z; a3 += wk * vr.w;
  }
  float4* op = (float4*)(outp + (size_t)token * 1024) + t;
  float4 cur = *op;
  cur.x += a0; cur.y += a1; cur.z += a2; cur.w += a3;
  *op = cur;
}

// ---------------------------------------------------------------- launcher
extern "C" void kernel_launch(void* const* d_in, const int* in_sizes, int n_in,
                              void* d_out, int out_size, void* d_ws, size_t ws_size,
                              hipStream_t stream)
{
  (void)in_sizes; (void)n_in; (void)out_size; (void)ws_size;
  const float* x    = (const float*)d_in[0];
  const float* imp  = (const float*)d_in[1];
  const float* Wc   = (const float*)d_in[2];
  const float* WQ   = (const float*)d_in[3];
  const float* WK   = (const float*)d_in[4];
  const float* WV   = (const float*)d_in[5];
  const float* Wm   = (const float*)d_in[6];
  const float* comp = (const float*)d_in[7];
  const float* expd = (const float*)d_in[8];
  const float* kK   = (const float*)d_in[9];
  const float* kV   = (const float*)d_in[10];
  const float* WO   = (const float*)d_in[11];
  const float* g1   = (const float*)d_in[12];
  const float* b1   = (const float*)d_in[13];
  const float* g2   = (const float*)d_in[14];
  const float* b2   = (const float*)d_in[15];
  float* out = (float*)d_out;
  char* ws = (char*)d_ws;
  const size_t MB = 1u << 20;
  float* racc = (float*)(ws);            // 32*5*2*16 f32 = 20480 B
  float* rw   = (float*)(ws + 24576);    // 5*2*16 f32
  float* Wcat = (float*)(ws + 32768);    // 80*1024 f32
  char* ar = ws + 512 * 1024;
  bf16* nx   = (bf16*)(ar);              // 8 MB
  bf16* sct  = (bf16*)(ar +  8 * MB);    // 1 MB  [b][R][D]
  bf16* eqt  = (bf16*)(ar +  9 * MB);    // 1 MB  [b][D][R]
  bf16* ekt  = (bf16*)(ar + 10 * MB);
  bf16* evt  = (bf16*)(ar + 11 * MB);
  bf16* hb   = (bf16*)(ar + 12 * MB);    // 2 MB  [b][S][R]
  bf16* Qb   = (bf16*)(ar + 14 * MB);    // 8 MB each
  bf16* Kb   = (bf16*)(ar + 22 * MB);
  bf16* Vb   = (bf16*)(ar + 30 * MB);
  bf16* aob  = (bf16*)(ar + 38 * MB);    // 8 MB
  bf16* WOb  = (bf16*)(ar + 46 * MB);    // 2 MB
  // phase B reuses the arena (phase-A buffers dead by then)
  bf16* nx2  = (bf16*)(ar);
  bf16* mct  = (bf16*)(ar +  8 * MB);
  bf16* Qmb  = (bf16*)(ar +  9 * MB);    // 2 MB
  bf16* kKb  = (bf16*)(ar + 11 * MB);    // 2 MB
  float* msb = (float*)(ar + 13 * MB);   // 64 MB

  hipMemsetAsync(racc, 0, 20480, stream);
  hipMemcpyAsync(Wcat + 0 * 16384, Wc, 65536, hipMemcpyDeviceToDevice, stream);
  hipMemcpyAsync(Wcat + 1 * 16384, WQ, 65536, hipMemcpyDeviceToDevice, stream);
  hipMemcpyAsync(Wcat + 2 * 16384, WK, 65536, hipMemcpyDeviceToDevice, stream);
  hipMemcpyAsync(Wcat + 3 * 16384, WV, 65536, hipMemcpyDeviceToDevice, stream);
  hipMemcpyAsync(Wcat + 4 * 16384, Wm, 65536, hipMemcpyDeviceToDevice, stream);

  ln_route_kernel<<<4096, 256, 0, stream>>>(x, g1, b1, Wcat, imp, nx, racc, 4, 0);
  route_norm_kernel<<<1, 256, 0, stream>>>(racc, rw, 0, 4);
  mix_t_kernel<<<dim3(16, 4, 2), 256, 0, stream>>>(comp, rw +  0, sct, 1024, 256);
  mix_t_kernel<<<dim3(4, 16, 2), 256, 0, stream>>>(expd, rw + 32, eqt, 256, 1024);
  mix_t_kernel<<<dim3(4, 16, 2), 256, 0, stream>>>(expd, rw + 64, ekt, 256, 1024);
  mix_t_kernel<<<dim3(4, 16, 2), 256, 0, stream>>>(expd, rw + 96, evt, 256, 1024);
  gemm_bt<0><<<dim3(2, 16, 2), 256, 0, stream>>>(nx, sct, hb, nullptr, 2048, 256, 1024,
        (long)2048 * 1024, (long)256 * 1024, (long)2048 * 256, 1.0f);
  gemm_bt<0><<<dim3(8, 16, 2), 256, 0, stream>>>(hb, eqt, Qb, nullptr, 2048, 1024, 256,
        (long)2048 * 256, (long)1024 * 256, (long)2048 * 1024, 1.0f);
  gemm_bt<0><<<dim3(8, 16, 2), 256, 0, stream>>>(hb, ekt, Kb, nullptr, 2048, 1024, 256,
        (long)2048 * 256, (long)1024 * 256, (long)2048 * 1024, 1.0f);
  gemm_bt<0><<<dim3(8, 16, 2), 256, 0, stream>>>(hb, evt, Vb, nullptr, 2048, 1024, 256,
        (long)2048 * 256, (long)1024 * 256, (long)2048 * 1024, 1.0f);
  attn_kernel<<<dim3(16, 16, 2), 256, 0, stream>>>(Qb, Kb, Vb, aob);
  cvt_bf16_kernel<<<1024, 256, 0, stream>>>(WO, WOb, 262144);
  gemm_bt<2><<<dim3(8, 32, 1), 256, 0, stream>>>(aob, WOb, out, x, 4096, 1024, 1024,
        0L, 0L, 0L, 1.0f);
  ln_route_kernel<<<4096, 256, 0, stream>>>(out, g2, b2, Wcat + 4 * 16384, imp, nx2, racc, 1, 4);
  route_norm_kernel<<<1, 256, 0, stream>>>(racc, rw, 4, 1);
  mix_t_kernel<<<dim3(16, 4, 2), 256, 0, stream>>>(comp, rw + 128, mct, 1024, 256);
  gemm_bt<0><<<dim3(2, 16, 2), 256, 0, stream>>>(nx2, mct, Qmb, nullptr, 2048, 256, 1024,
        (long)2048 * 1024, (long)256 * 1024, (long)2048 * 256, 1.0f);
  cvt_bf16_kernel<<<1024, 256, 0, stream>>>(kK, kKb, 262144);
  gemm_bt<1><<<dim3(32, 16, 2), 256, 0, stream>>>(Qmb, kKb, msb, nullptr, 2048, 4096, 256,
        (long)2048 * 256, 0L, (long)2048 * 4096, 0.0625f);
  topk_kernel<<<4096, 256, 0, stream>>>(msb, kV, out);
}

// Round 2
// 359.382 us; speedup vs baseline: 1.5332x; 1.5332x over previous
//
#include <hip/hip_runtime.h>
#include <hip/hip_bf16.h>
#include <math.h>

typedef __bf16 bf16;
typedef __attribute__((ext_vector_type(8))) __bf16 bf16x8;
typedef __attribute__((ext_vector_type(4))) __bf16 bf16x4;
typedef __attribute__((ext_vector_type(4))) float f32x4;
typedef __attribute__((ext_vector_type(16))) float f32x16;

// ---------------------------------------------------------------- LN + route
__global__ __launch_bounds__(256) void ln_route_kernel(
    const float* __restrict__ x, const float* __restrict__ gam, const float* __restrict__ bet,
    const float* __restrict__ Wg, const float* __restrict__ imp,
    bf16* __restrict__ nxo, float* __restrict__ racc, int ngroups, int gbase)
{
  const int token = blockIdx.x;
  const int b = token >> 11;                 // S = 2048
  const int t = threadIdx.x, w = t >> 6, l = t & 63;
  __shared__ alignas(16) float row[1024];
  __shared__ float red1[4], red2[4];
  float4 xv = ((const float4*)(x + (size_t)token * 1024))[t];
  float s  = xv.x + xv.y + xv.z + xv.w;
  float sq = xv.x*xv.x + xv.y*xv.y + xv.z*xv.z + xv.w*xv.w;
  #pragma unroll
  for (int off = 32; off > 0; off >>= 1) { s += __shfl_xor(s, off); sq += __shfl_xor(sq, off); }
  if (l == 0) { red1[w] = s; red2[w] = sq; }
  __syncthreads();
  s  = red1[0] + red1[1] + red1[2] + red1[3];
  sq = red2[0] + red2[1] + red2[2] + red2[3];
  const float mu  = s * (1.f / 1024.f);
  const float var = sq * (1.f / 1024.f) - mu * mu;
  const float rs  = rsqrtf(var + 1e-5f);
  float4 gv = ((const float4*)gam)[t];
  float4 bv = ((const float4*)bet)[t];
  float n0 = (xv.x - mu) * rs * gv.x + bv.x;
  float n1 = (xv.y - mu) * rs * gv.y + bv.y;
  float n2 = (xv.z - mu) * rs * gv.z + bv.z;
  float n3 = (xv.w - mu) * rs * gv.w + bv.w;
  row[t*4+0] = n0; row[t*4+1] = n1; row[t*4+2] = n2; row[t*4+3] = n3;
  bf16x4 pk = {(bf16)n0, (bf16)n1, (bf16)n2, (bf16)n3};
  *(bf16x4*)(nxo + (size_t)token * 1024 + t * 4) = pk;
  __syncthreads();
  if (w < ngroups) {
    const float* Wbase = Wg + (size_t)w * 16 * 1024;
    float m_run = -INFINITY, s_run = 0.f, myv = 0.f;
    for (int e = 0; e < 16; ++e) {
      const float* wr = Wbase + e * 1024;
      float dv = 0.f;
      #pragma unroll
      for (int i = 0; i < 16; ++i) dv += row[l + i*64] * wr[l + i*64];
      #pragma unroll
      for (int off = 32; off > 0; off >>= 1) dv += __shfl_xor(dv, off);
      if (l == e) myv = dv;
      float mn = fmaxf(m_run, dv);
      s_run = s_run * __expf(m_run - mn) + __expf(dv - mn);
      m_run = mn;
    }
    if (l < 16) {
      float pref = __expf(myv - m_run) / s_run;
      atomicAdd(racc + ((((size_t)(token & 31)) * 5 + gbase + w) * 2 + b) * 16 + l,
                imp[token] * pref);
    }
  }
}

// ------------------------------------------------------------- route norm
__global__ void route_norm_kernel(const float* __restrict__ racc, float* __restrict__ rw,
                                  int g0, int ng)
{
  __shared__ float pooled[5][2][16];
  const int t = threadIdx.x;
  const int n = ng * 32;
  int g = 0, b = 0, e = 0;
  if (t < n) {
    g = g0 + (t >> 5); b = (t >> 4) & 1; e = t & 15;
    float s = 0.f;
    for (int sl = 0; sl < 32; ++sl) s += racc[(((size_t)sl * 5 + g) * 2 + b) * 16 + e];
    pooled[g][b][e] = s;
  }
  __syncthreads();
  if (t < n) {
    float den = 1e-8f;
    #pragma unroll
    for (int e2 = 0; e2 < 16; ++e2) den += pooled[g][b][e2];
    rw[((size_t)g * 2 + b) * 16 + e] = pooled[g][b][e] / den;
  }
}

// ----------------------------------------------------- pool mix (transposed)
__global__ __launch_bounds__(256) void mix_t_kernel(
    const float* __restrict__ pool, const float* __restrict__ rwg,
    bf16* __restrict__ out, int dim1, int dim2)
{
  const int i0 = blockIdx.x * 64, j0 = blockIdx.y * 64, b = blockIdx.z;
  const int t = threadIdx.x;
  __shared__ float tile[64][65];
  float wn[16];
  #pragma unroll
  for (int n = 0; n < 16; ++n) wn[n] = rwg[b * 16 + n];
  float acc[16];
  #pragma unroll
  for (int k = 0; k < 16; ++k) acc[k] = 0.f;
  const int lj = t & 63, li = t >> 6;
  for (int n = 0; n < 16; ++n) {
    __syncthreads();
    #pragma unroll
    for (int it = 0; it < 16; ++it)
      tile[li + it*4][lj] = pool[((size_t)n * dim1 + i0 + li + it*4) * dim2 + j0 + lj];
    __syncthreads();
    const float wv = wn[n];
    #pragma unroll
    for (int it = 0; it < 16; ++it)
      acc[it] += wv * tile[lj][li + it*4];
  }
  #pragma unroll
  for (int it = 0; it < 16; ++it)
    out[((size_t)b * dim2 + j0 + li + it*4) * dim1 + i0 + lj] = (bf16)acc[it];
}

// ------------------------------------------------------------ f32 -> bf16
__global__ void cvt_bf16_kernel(const float* __restrict__ in, bf16* __restrict__ out, int n4)
{
  const int i = blockIdx.x * 256 + threadIdx.x;
  if (i < n4) {
    float4 v = ((const float4*)in)[i];
    bf16x4 o = {(bf16)v.x, (bf16)v.y, (bf16)v.z, (bf16)v.w};
    ((bf16x4*)out)[i] = o;
  }
}

// --------------------------------------------------------------- GEMM (Bt)
template<int CMODE>
__global__ __launch_bounds__(256) void gemm_bt(
    const bf16* __restrict__ A, const bf16* __restrict__ Bt, void* __restrict__ Cp,
    const float* __restrict__ resid, int M, int N, int K,
    long sA, long sB, long sC, float scale)
{
  __shared__ alignas(16) bf16 As[128 * 32];
  __shared__ alignas(16) bf16 Bs[128 * 32];
  const int t = threadIdx.x, w = t >> 6, l = t & 63;
  const int llo = l & 15, lhi = l >> 4;
  const int wm = w >> 1, wn = w & 1;
  const int m0 = blockIdx.y * 128, n0 = blockIdx.x * 128;
  const bf16* Ab = A  + (size_t)blockIdx.z * sA;
  const bf16* Bb = Bt + (size_t)blockIdx.z * sB;
  f32x4 acc[4][4];
  #pragma unroll
  for (int i = 0; i < 4; ++i)
    #pragma unroll
    for (int j = 0; j < 4; ++j) acc[i][j] = (f32x4){0.f, 0.f, 0.f, 0.f};

  const int arow = t >> 2, akb = t & 3;
  const bf16* asrc = Ab + (size_t)(m0 + arow) * K + akb * 8;
  const bf16* bsrc = Bb + (size_t)(n0 + arow) * K + akb * 8;
  const size_t rstep = (size_t)64 * K;
  const int aoff0 = arow * 64 + ((akb * 16) ^ (((arow >> 1) & 3) << 4));
  const int aoff1 = aoff0 + 64 * 64;

  uint4 a0 = *(const uint4*)(asrc);
  uint4 a1 = *(const uint4*)(asrc + rstep);
  uint4 b0 = *(const uint4*)(bsrc);
  uint4 b1 = *(const uint4*)(bsrc + rstep);

  for (int kt = 0; kt < K; kt += 32) {
    __syncthreads();
    *(uint4*)((char*)As + aoff0) = a0;
    *(uint4*)((char*)As + aoff1) = a1;
    *(uint4*)((char*)Bs + aoff0) = b0;
    *(uint4*)((char*)Bs + aoff1) = b1;
    __syncthreads();
    if (kt + 32 < K) {
      a0 = *(const uint4*)(asrc + kt + 32);
      a1 = *(const uint4*)(asrc + rstep + kt + 32);
      b0 = *(const uint4*)(bsrc + kt + 32);
      b1 = *(const uint4*)(bsrc + rstep + kt + 32);
    }
    bf16x8 af[4], bfr[4];
    #pragma unroll
    for (int fi = 0; fi < 4; ++fi) {
      int r = wm * 64 + fi * 16 + llo;
      af[fi] = *(const bf16x8*)((const char*)As + (r * 64 + ((lhi * 16) ^ (((r >> 1) & 3) << 4))));
      int c = wn * 64 + fi * 16 + llo;
      bfr[fi] = *(const bf16x8*)((const char*)Bs + (c * 64 + ((lhi * 16) ^ (((c >> 1) & 3) << 4))));
    }
    #pragma unroll
    for (int fi = 0; fi < 4; ++fi)
      #pragma unroll
      for (int fj = 0; fj < 4; ++fj)
        acc[fi][fj] = __builtin_amdgcn_mfma_f32_16x16x32_bf16(af[fi], bfr[fj], acc[fi][fj], 0, 0, 0);
  }

  #pragma unroll
  for (int fi = 0; fi < 4; ++fi)
    #pragma unroll
    for (int fj = 0; fj < 4; ++fj)
      #pragma unroll
      for (int jj = 0; jj < 4; ++jj) {
        int r = m0 + wm * 64 + fi * 16 + lhi * 4 + jj;
        int c = n0 + wn * 64 + fj * 16 + llo;
        size_t idx = (size_t)blockIdx.z * sC + (size_t)r * N + c;
        float v = acc[fi][fj][jj] * scale;
        if (CMODE == 0) {
          ((bf16*)Cp)[idx] = (bf16)v;
        } else {
          if (CMODE == 2) v += resid[idx];
          ((float*)Cp)[idx] = v;
        }
      }
}

// ----------------------------------------------------------- flash attention
// No-LDS, swapped-QK^T 32x32x16 structure. One wave owns a 32-row q-tile and
// processes the pair (j, 63-j) so every wave does exactly 65 kv-steps.
// K comes pre-scaled by 1/8 (folded into K-expand GEMM); V comes transposed
// in global (Vt[b][d][s]) so both MFMA operands are direct 16B row loads
// (per-head K/V slices are 256KB -> L2-resident; no LDS staging needed).
static __device__ __forceinline__ unsigned pk2f(float a, float b) {
  union { bf16 h[2]; unsigned u; } x;
  x.h[0] = (bf16)a; x.h[1] = (bf16)b; return x.u;
}

__global__ __launch_bounds__(256) void attn2_kernel(
    const bf16* __restrict__ Qg, const bf16* __restrict__ Kg,
    const bf16* __restrict__ Vtg, bf16* __restrict__ aog)
{
  const int h = blockIdx.y, b = blockIdx.z;
  const int t = threadIdx.x, w = t >> 6, l = t & 63;
  const int qi = l & 31, hi = l >> 5;       // q (or row) index, half-select
  const int gt = blockIdx.x * 4 + w;        // 0..31 -> tiles (gt, 63-gt)
  const bf16* Qb = Qg + ((size_t)b * 2048) * 1024 + h * 64;
  const bf16* Kb = Kg + ((size_t)b * 2048) * 1024 + h * 64;
  const bf16* Vb = Vtg + ((size_t)b * 1024 + h * 64) * 2048;
  bf16* Ob = aog + ((size_t)b * 2048) * 1024 + h * 64;

  for (int tsel = 0; tsel < 2; ++tsel) {
    const int j  = tsel ? (63 - gt) : gt;
    const int q0 = j * 32;

    bf16x8 qf[4];
    #pragma unroll
    for (int dc = 0; dc < 4; ++dc)
      qf[dc] = *(const bf16x8*)(Qb + (size_t)(q0 + qi) * 1024 + dc * 16 + hi * 8);

    f32x16 o0, o1;
    #pragma unroll
    for (int r = 0; r < 16; ++r) { o0[r] = 0.f; o1[r] = 0.f; }
    float m_run = -INFINITY, l_run = 0.f;

    bf16x8 kA[4], vA[4], kB[4], vB[4];

    auto LOADK = [&](bf16x8 (&kf)[4], int kv0) {
      #pragma unroll
      for (int dc = 0; dc < 4; ++dc)
        kf[dc] = *(const bf16x8*)(Kb + (size_t)(kv0 + qi) * 1024 + dc * 16 + hi * 8);
    };
    auto LOADV = [&](bf16x8 (&vf)[4], int kv0) {
      #pragma unroll
      for (int df = 0; df < 2; ++df)
        #pragma unroll
        for (int kc = 0; kc < 2; ++kc)
          vf[df*2+kc] = *(const bf16x8*)(Vb + (size_t)(32*df + qi) * 2048 + kv0 + kc*16 + hi*8);
    };

    auto STEP = [&](const bf16x8 (&kf)[4], const bf16x8 (&vf)[4], int kv0) {
      f32x16 s;
      #pragma unroll
      for (int r = 0; r < 16; ++r) s[r] = 0.f;
      #pragma unroll
      for (int dc = 0; dc < 4; ++dc)
        s = __builtin_amdgcn_mfma_f32_32x32x16_bf16(kf[dc], qf[dc], s, 0, 0, 0);
      if (kv0 == q0) {                       // diagonal: mask kv > q
        const int qe = qi - 4 * hi;
        #pragma unroll
        for (int r = 0; r < 16; ++r) {
          const int kvc = (r & 3) + 8 * (r >> 2);
          s[r] = (kvc > qe) ? -INFINITY : s[r];
        }
      }
      float tm = s[0];
      #pragma unroll
      for (int r = 1; r < 16; ++r) tm = fmaxf(tm, s[r]);
      tm = fmaxf(tm, __shfl_xor(tm, 32));
      const float mn = fmaxf(m_run, tm);
      const float alpha = __expf(m_run - mn);
      m_run = mn;
      float rs = 0.f;
      unsigned pk[8];
      #pragma unroll
      for (int i = 0; i < 8; ++i) {
        float pa = __expf(s[2*i]   - mn);
        float pb = __expf(s[2*i+1] - mn);
        rs += pa + pb;
        pk[i] = pk2f(pa, pb);
      }
      rs += __shfl_xor(rs, 32);
      l_run = l_run * alpha + rs;
      o0 *= alpha; o1 *= alpha;
      unsigned ot[8];
      #pragma unroll
      for (int i = 0; i < 8; ++i) ot[i] = __shfl_xor(pk[i], 32);
      #pragma unroll
      for (int kc = 0; kc < 2; ++kc) {
        union { unsigned u[4]; bf16x8 v; } pf;
        pf.u[0] = hi ? ot[4*kc+2] : pk[4*kc+0];
        pf.u[1] = hi ? ot[4*kc+3] : pk[4*kc+1];
        pf.u[2] = hi ? pk[4*kc+2] : ot[4*kc+0];
        pf.u[3] = hi ? pk[4*kc+3] : ot[4*kc+1];
        o0 = __builtin_amdgcn_mfma_f32_32x32x16_bf16(vf[kc],     pf.v, o0, 0, 0, 0);
        o1 = __builtin_amdgcn_mfma_f32_32x32x16_bf16(vf[2+kc],   pf.v, o1, 0, 0, 0);
      }
    };

    LOADK(kA, 0); LOADV(vA, 0);
    int kv0 = 0;
    while (true) {
      if (kv0 + 32 <= q0) { LOADK(kB, kv0 + 32); LOADV(vB, kv0 + 32); }
      STEP(kA, vA, kv0);
      kv0 += 32; if (kv0 > q0) break;
      if (kv0 + 32 <= q0) { LOADK(kA, kv0 + 32); LOADV(vA, kv0 + 32); }
      STEP(kB, vB, kv0);
      kv0 += 32; if (kv0 > q0) break;
    }

    const float inv = 1.0f / l_run;
    #pragma unroll
    for (int df = 0; df < 2; ++df) {
      #pragma unroll
      for (int rg = 0; rg < 4; ++rg) {
        union { bf16 h4[4]; unsigned long long u; } pr;
        #pragma unroll
        for (int e = 0; e < 4; ++e) {
          float v = (df ? o1[rg*4+e] : o0[rg*4+e]) * inv;
          pr.h4[e] = (bf16)v;
        }
        *(unsigned long long*)(Ob + (size_t)(q0 + qi) * 1024 + df*32 + rg*8 + hi*4) = pr.u;
      }
    }
  }
}

// ------------------------------------------------------------------ top-k
__global__ __launch_bounds__(256) void topk_kernel(
    const float* __restrict__ ms, const float* __restrict__ kV, float* __restrict__ outp)
{
  const int token = blockIdx.x;
  const int t = threadIdx.x, w = t >> 6, l = t & 63;
  __shared__ alignas(16) float row[4096];
  __shared__ float wv[8]; __shared__ int wi[8];
  __shared__ float cand[4]; __shared__ int candi[4];
  const float* mrow = ms + (size_t)token * 4096;
  #pragma unroll
  for (int p = 0; p < 4; ++p) {
    float4 v = ((const float4*)mrow)[t + p * 256];
    *(float4*)&row[(t + p * 256) * 4] = v;
  }
  __syncthreads();
  for (int k = 0; k < 8; ++k) {
    float bv = -INFINITY; int bi = 0;
    for (int i = t; i < 4096; i += 256) {
      float v = row[i];
      if (v > bv) { bv = v; bi = i; }
    }
    #pragma unroll
    for (int off = 32; off > 0; off >>= 1) {
      float ov = __shfl_xor(bv, off); int oi = __shfl_xor(bi, off);
      if (ov > bv || (ov == bv && oi < bi)) { bv = ov; bi = oi; }
    }
    if (l == 0) { cand[w] = bv; candi[w] = bi; }
    __syncthreads();
    if (t == 0) {
      float best = cand[0]; int besti = candi[0];
      for (int q = 1; q < 4; ++q)
        if (cand[q] > best || (cand[q] == best && candi[q] < besti)) { best = cand[q]; besti = candi[q]; }
      wv[k] = best; wi[k] = besti; row[besti] = -INFINITY;
    }
    __syncthreads();
  }
  if (t == 0) {
    float m = wv[0];
    #pragma unroll
    for (int k = 1; k < 8; ++k) m = fmaxf(m, wv[k]);
    float sden = 0.f; float ex[8];
    #pragma unroll
    for (int k = 0; k < 8; ++k) { ex[k] = __expf(wv[k] - m); sden += ex[k]; }
    #pragma unroll
    for (int k = 0; k < 8; ++k) wv[k] = ex[k] / sden;
  }
  __syncthreads();
  float a0 = 0, a1 = 0, a2 = 0, a3 = 0;
  #pragma unroll
  for (int k = 0; k < 8; ++k) {
    float wk = wv[k];
    float4 vr = *(const float4*)(kV + (size_t)wi[k] * 1024 + t * 4);
    a0 += wk * vr.x; a1 += wk * vr.y; a2 += wk * vr.z; a3 += wk * vr.w;
  }
  float4* op = (float4*)(outp + (size_t)token * 1024) + t;
  float4 cur = *op;
  cur.x += a0; cur.y += a1; cur.z += a2; cur.w += a3;
  *op = cur;
}

// ---------------------------------------------------------------- launcher
extern "C" void kernel_launch(void* const* d_in, const int* in_sizes, int n_in,
                              void* d_out, int out_size, void* d_ws, size_t ws_size,
                              hipStream_t stream)
{
  (void)in_sizes; (void)n_in; (void)out_size; (void)ws_size;
  const float* x    = (const float*)d_in[0];
  const float* imp  = (const float*)d_in[1];
  const float* Wc   = (const float*)d_in[2];
  const float* WQ   = (const float*)d_in[3];
  const float* WK   = (const float*)d_in[4];
  const float* WV   = (const float*)d_in[5];
  const float* Wm   = (const float*)d_in[6];
  const float* comp = (const float*)d_in[7];
  const float* expd = (const float*)d_in[8];
  const float* kK   = (const float*)d_in[9];
  const float* kV   = (const float*)d_in[10];
  const float* WO   = (const float*)d_in[11];
  const float* g1   = (const float*)d_in[12];
  const float* b1   = (const float*)d_in[13];
  const float* g2   = (const float*)d_in[14];
  const float* b2   = (const float*)d_in[15];
  float* out = (float*)d_out;
  char* ws = (char*)d_ws;
  const size_t MB = 1u << 20;
  float* racc = (float*)(ws);
  float* rw   = (float*)(ws + 24576);
  float* Wcat = (float*)(ws + 32768);
  char* ar = ws + 512 * 1024;
  bf16* nx   = (bf16*)(ar);              // 8 MB
  bf16* sct  = (bf16*)(ar +  8 * MB);    // 1 MB  [b][R][D]
  bf16* eqt  = (bf16*)(ar +  9 * MB);    // 1 MB  [b][D][R]
  bf16* ekt  = (bf16*)(ar + 10 * MB);
  bf16* evt  = (bf16*)(ar + 11 * MB);
  bf16* hb   = (bf16*)(ar + 12 * MB);    // 2 MB  [b][S][R]
  bf16* Qb   = (bf16*)(ar + 14 * MB);    // 8 MB each
  bf16* Kb   = (bf16*)(ar + 22 * MB);
  bf16* Vtb  = (bf16*)(ar + 30 * MB);    // 8 MB  [b][D][S]  (V transposed)
  bf16* aob  = (bf16*)(ar + 38 * MB);    // 8 MB
  bf16* WOb  = (bf16*)(ar + 46 * MB);    // 2 MB
  bf16* nx2  = (bf16*)(ar);
  bf16* mct  = (bf16*)(ar +  8 * MB);
  bf16* Qmb  = (bf16*)(ar +  9 * MB);    // 2 MB
  bf16* kKb  = (bf16*)(ar + 11 * MB);    // 2 MB
  float* msb = (float*)(ar + 13 * MB);   // 64 MB

  hipMemsetAsync(racc, 0, 20480, stream);
  hipMemcpyAsync(Wcat + 0 * 16384, Wc, 65536, hipMemcpyDeviceToDevice, stream);
  hipMemcpyAsync(Wcat + 1 * 16384, WQ, 65536, hipMemcpyDeviceToDevice, stream);
  hipMemcpyAsync(Wcat + 2 * 16384, WK, 65536, hipMemcpyDeviceToDevice, stream);
  hipMemcpyAsync(Wcat + 3 * 16384, WV, 65536, hipMemcpyDeviceToDevice, stream);
  hipMemcpyAsync(Wcat + 4 * 16384, Wm, 65536, hipMemcpyDeviceToDevice, stream);

  ln_route_kernel<<<4096, 256, 0, stream>>>(x, g1, b1, Wcat, imp, nx, racc, 4, 0);
  route_norm_kernel<<<1, 256, 0, stream>>>(racc, rw, 0, 4);
  mix_t_kernel<<<dim3(16, 4, 2), 256, 0, stream>>>(comp, rw +  0, sct, 1024, 256);
  mix_t_kernel<<<dim3(4, 16, 2), 256, 0, stream>>>(expd, rw + 32, eqt, 256, 1024);
  mix_t_kernel<<<dim3(4, 16, 2), 256, 0, stream>>>(expd, rw + 64, ekt, 256, 1024);
  mix_t_kernel<<<dim3(4, 16, 2), 256, 0, stream>>>(expd, rw + 96, evt, 256, 1024);
  gemm_bt<0><<<dim3(2, 16, 2), 256, 0, stream>>>(nx, sct, hb, nullptr, 2048, 256, 1024,
        (long)2048 * 1024, (long)256 * 1024, (long)2048 * 256, 1.0f);
  gemm_bt<0><<<dim3(8, 16, 2), 256, 0, stream>>>(hb, eqt, Qb, nullptr, 2048, 1024, 256,
        (long)2048 * 256, (long)1024 * 256, (long)2048 * 1024, 1.0f);
  // K pre-scaled by 1/sqrt(dh)=0.125 (folded attention score scale)
  gemm_bt<0><<<dim3(8, 16, 2), 256, 0, stream>>>(hb, ekt, Kb, nullptr, 2048, 1024, 256,
        (long)2048 * 256, (long)1024 * 256, (long)2048 * 1024, 0.125f);
  // V produced TRANSPOSED: Vt[b][d][s] = sum_r evt[b][d][r] * hb[b][s][r]
  gemm_bt<0><<<dim3(16, 8, 2), 256, 0, stream>>>(evt, hb, Vtb, nullptr, 1024, 2048, 256,
        (long)1024 * 256, (long)2048 * 256, (long)1024 * 2048, 1.0f);
  attn2_kernel<<<dim3(8, 16, 2), 256, 0, stream>>>(Qb, Kb, Vtb, aob);
  cvt_bf16_kernel<<<1024, 256, 0, stream>>>(WO, WOb, 262144);
  gemm_bt<2><<<dim3(8, 32, 1), 256, 0, stream>>>(aob, WOb, out, x, 4096, 1024, 1024,
        0L, 0L, 0L, 1.0f);
  ln_route_kernel<<<4096, 256, 0, stream>>>(out, g2, b2, Wcat + 4 * 16384, imp, nx2, racc, 1, 4);
  route_norm_kernel<<<1, 256, 0, stream>>>(racc, rw, 4, 1);
  mix_t_kernel<<<dim3(16, 4, 2), 256, 0, stream>>>(comp, rw + 128, mct, 1024, 256);
  gemm_bt<0><<<dim3(2, 16, 2), 256, 0, stream>>>(nx2, mct, Qmb, nullptr, 2048, 256, 1024,
        (long)2048 * 1024, (long)256 * 1024, (long)2048 * 256, 1.0f);
  cvt_bf16_kernel<<<1024, 256, 0, stream>>>(kK, kKb, 262144);
  gemm_bt<1><<<dim3(32, 16, 2), 256, 0, stream>>>(Qmb, kKb, msb, nullptr, 2048, 4096, 256,
        (long)2048 * 256, 0L, (long)2048 * 4096, 0.0625f);
  topk_kernel<<<4096, 256, 0, stream>>>(msb, kV, out);
}

// Round 3
// 357.090 us; speedup vs baseline: 1.5430x; 1.0064x over previous
//
#include <hip/hip_runtime.h>
#include <hip/hip_bf16.h>
#include <math.h>

typedef __bf16 bf16;
typedef __attribute__((ext_vector_type(8))) __bf16 bf16x8;
typedef __attribute__((ext_vector_type(4))) __bf16 bf16x4;
typedef __attribute__((ext_vector_type(4))) float f32x4;
typedef __attribute__((ext_vector_type(16))) float f32x16;

static __device__ __forceinline__ void gload_lds16(const bf16* g, bf16* l) {
  __builtin_amdgcn_global_load_lds((const __attribute__((address_space(1))) void*)g,
                                   (__attribute__((address_space(3))) void*)l, 16, 0, 0);
}

// ---------------------------------------------------------------- LN + route
__global__ __launch_bounds__(256) void ln_route_kernel(
    const float* __restrict__ x, const float* __restrict__ gam, const float* __restrict__ bet,
    const float* __restrict__ Wg, const float* __restrict__ imp,
    bf16* __restrict__ nxo, float* __restrict__ racc, int ngroups, int gbase)
{
  const int token = blockIdx.x;
  const int b = token >> 11;                 // S = 2048
  const int t = threadIdx.x, w = t >> 6, l = t & 63;
  __shared__ alignas(16) float row[1024];
  __shared__ float red1[4], red2[4];
  float4 xv = ((const float4*)(x + (size_t)token * 1024))[t];
  float s  = xv.x + xv.y + xv.z + xv.w;
  float sq = xv.x*xv.x + xv.y*xv.y + xv.z*xv.z + xv.w*xv.w;
  #pragma unroll
  for (int off = 32; off > 0; off >>= 1) { s += __shfl_xor(s, off); sq += __shfl_xor(sq, off); }
  if (l == 0) { red1[w] = s; red2[w] = sq; }
  __syncthreads();
  s  = red1[0] + red1[1] + red1[2] + red1[3];
  sq = red2[0] + red2[1] + red2[2] + red2[3];
  const float mu  = s * (1.f / 1024.f);
  const float var = sq * (1.f / 1024.f) - mu * mu;
  const float rs  = rsqrtf(var + 1e-5f);
  float4 gv = ((const float4*)gam)[t];
  float4 bv = ((const float4*)bet)[t];
  float n0 = (xv.x - mu) * rs * gv.x + bv.x;
  float n1 = (xv.y - mu) * rs * gv.y + bv.y;
  float n2 = (xv.z - mu) * rs * gv.z + bv.z;
  float n3 = (xv.w - mu) * rs * gv.w + bv.w;
  row[t*4+0] = n0; row[t*4+1] = n1; row[t*4+2] = n2; row[t*4+3] = n3;
  bf16x4 pk = {(bf16)n0, (bf16)n1, (bf16)n2, (bf16)n3};
  *(bf16x4*)(nxo + (size_t)token * 1024 + t * 4) = pk;
  __syncthreads();
  if (w < ngroups) {
    const float* Wbase = Wg + (size_t)w * 16 * 1024;
    float m_run = -INFINITY, s_run = 0.f, myv = 0.f;
    for (int e = 0; e < 16; ++e) {
      const float* wr = Wbase + e * 1024;
      float dv = 0.f;
      #pragma unroll
      for (int i = 0; i < 16; ++i) dv += row[l + i*64] * wr[l + i*64];
      #pragma unroll
      for (int off = 32; off > 0; off >>= 1) dv += __shfl_xor(dv, off);
      if (l == e) myv = dv;
      float mn = fmaxf(m_run, dv);
      s_run = s_run * __expf(m_run - mn) + __expf(dv - mn);
      m_run = mn;
    }
    if (l < 16) {
      float pref = __expf(myv - m_run) / s_run;
      atomicAdd(racc + ((((size_t)(token & 31)) * 5 + gbase + w) * 2 + b) * 16 + l,
                imp[token] * pref);
    }
  }
}

// ------------------------------------------------------------- route norm
__global__ void route_norm_kernel(const float* __restrict__ racc, float* __restrict__ rw,
                                  int g0, int ng)
{
  __shared__ float pooled[5][2][16];
  const int t = threadIdx.x;
  const int n = ng * 32;
  int g = 0, b = 0, e = 0;
  if (t < n) {
    g = g0 + (t >> 5); b = (t >> 4) & 1; e = t & 15;
    float s = 0.f;
    for (int sl = 0; sl < 32; ++sl) s += racc[(((size_t)sl * 5 + g) * 2 + b) * 16 + e];
    pooled[g][b][e] = s;
  }
  __syncthreads();
  if (t < n) {
    float den = 1e-8f;
    #pragma unroll
    for (int e2 = 0; e2 < 16; ++e2) den += pooled[g][b][e2];
    rw[((size_t)g * 2 + b) * 16 + e] = pooled[g][b][e] / den;
  }
}

// ----------------------------------------------------- pool mix (transposed)
__global__ __launch_bounds__(256) void mix_t_kernel(
    const float* __restrict__ pool, const float* __restrict__ rwg,
    bf16* __restrict__ out, int dim1, int dim2)
{
  const int i0 = blockIdx.x * 64, j0 = blockIdx.y * 64, b = blockIdx.z;
  const int t = threadIdx.x;
  __shared__ float tile[64][65];
  float wn[16];
  #pragma unroll
  for (int n = 0; n < 16; ++n) wn[n] = rwg[b * 16 + n];
  float acc[16];
  #pragma unroll
  for (int k = 0; k < 16; ++k) acc[k] = 0.f;
  const int lj = t & 63, li = t >> 6;
  for (int n = 0; n < 16; ++n) {
    __syncthreads();
    #pragma unroll
    for (int it = 0; it < 16; ++it)
      tile[li + it*4][lj] = pool[((size_t)n * dim1 + i0 + li + it*4) * dim2 + j0 + lj];
    __syncthreads();
    const float wv = wn[n];
    #pragma unroll
    for (int it = 0; it < 16; ++it)
      acc[it] += wv * tile[lj][li + it*4];
  }
  #pragma unroll
  for (int it = 0; it < 16; ++it)
    out[((size_t)b * dim2 + j0 + li + it*4) * dim1 + i0 + lj] = (bf16)acc[it];
}

// ------------------------------------------------------------ f32 -> bf16
__global__ void cvt_bf16_kernel(const float* __restrict__ in, bf16* __restrict__ out, int n4)
{
  const int i = blockIdx.x * 256 + threadIdx.x;
  if (i < n4) {
    float4 v = ((const float4*)in)[i];
    bf16x4 o = {(bf16)v.x, (bf16)v.y, (bf16)v.z, (bf16)v.w};
    ((bf16x4*)out)[i] = o;
  }
}

// --------------------------------------------------------------- GEMM (Bt)
// CMODE: 0 = bf16 out, 1 = f32 out, 2 = f32 out + f32 resid,
//        3 = bf16 out in head-major layout [b][h=c/64][r][64].
template<int CMODE>
__global__ __launch_bounds__(256) void gemm_bt(
    const bf16* __restrict__ A, const bf16* __restrict__ Bt, void* __restrict__ Cp,
    const float* __restrict__ resid, int M, int N, int K,
    long sA, long sB, long sC, float scale)
{
  __shared__ alignas(16) bf16 As[128 * 32];
  __shared__ alignas(16) bf16 Bs[128 * 32];
  const int t = threadIdx.x, w = t >> 6, l = t & 63;
  const int llo = l & 15, lhi = l >> 4;
  const int wm = w >> 1, wn = w & 1;
  const int m0 = blockIdx.y * 128, n0 = blockIdx.x * 128;
  const bf16* Ab = A  + (size_t)blockIdx.z * sA;
  const bf16* Bb = Bt + (size_t)blockIdx.z * sB;
  f32x4 acc[4][4];
  #pragma unroll
  for (int i = 0; i < 4; ++i)
    #pragma unroll
    for (int j = 0; j < 4; ++j) acc[i][j] = (f32x4){0.f, 0.f, 0.f, 0.f};

  const int arow = t >> 2, akb = t & 3;
  const bf16* asrc = Ab + (size_t)(m0 + arow) * K + akb * 8;
  const bf16* bsrc = Bb + (size_t)(n0 + arow) * K + akb * 8;
  const size_t rstep = (size_t)64 * K;
  const int aoff0 = arow * 64 + ((akb * 16) ^ (((arow >> 1) & 3) << 4));
  const int aoff1 = aoff0 + 64 * 64;

  uint4 a0 = *(const uint4*)(asrc);
  uint4 a1 = *(const uint4*)(asrc + rstep);
  uint4 b0 = *(const uint4*)(bsrc);
  uint4 b1 = *(const uint4*)(bsrc + rstep);

  for (int kt = 0; kt < K; kt += 32) {
    __syncthreads();
    *(uint4*)((char*)As + aoff0) = a0;
    *(uint4*)((char*)As + aoff1) = a1;
    *(uint4*)((char*)Bs + aoff0) = b0;
    *(uint4*)((char*)Bs + aoff1) = b1;
    __syncthreads();
    if (kt + 32 < K) {
      a0 = *(const uint4*)(asrc + kt + 32);
      a1 = *(const uint4*)(asrc + rstep + kt + 32);
      b0 = *(const uint4*)(bsrc + kt + 32);
      b1 = *(const uint4*)(bsrc + rstep + kt + 32);
    }
    bf16x8 af[4], bfr[4];
    #pragma unroll
    for (int fi = 0; fi < 4; ++fi) {
      int r = wm * 64 + fi * 16 + llo;
      af[fi] = *(const bf16x8*)((const char*)As + (r * 64 + ((lhi * 16) ^ (((r >> 1) & 3) << 4))));
      int c = wn * 64 + fi * 16 + llo;
      bfr[fi] = *(const bf16x8*)((const char*)Bs + (c * 64 + ((lhi * 16) ^ (((c >> 1) & 3) << 4))));
    }
    #pragma unroll
    for (int fi = 0; fi < 4; ++fi)
      #pragma unroll
      for (int fj = 0; fj < 4; ++fj)
        acc[fi][fj] = __builtin_amdgcn_mfma_f32_16x16x32_bf16(af[fi], bfr[fj], acc[fi][fj], 0, 0, 0);
  }

  #pragma unroll
  for (int fi = 0; fi < 4; ++fi)
    #pragma unroll
    for (int fj = 0; fj < 4; ++fj)
      #pragma unroll
      for (int jj = 0; jj < 4; ++jj) {
        int r = m0 + wm * 64 + fi * 16 + lhi * 4 + jj;
        int c = n0 + wn * 64 + fj * 16 + llo;
        size_t idx = (size_t)blockIdx.z * sC + (size_t)r * N + c;
        float v = acc[fi][fj][jj] * scale;
        if (CMODE == 0) {
          ((bf16*)Cp)[idx] = (bf16)v;
        } else if (CMODE == 3) {
          size_t idx3 = (((size_t)blockIdx.z * 16 + (c >> 6)) * 2048 + r) * 64 + (c & 63);
          ((bf16*)Cp)[idx3] = (bf16)v;
        } else {
          if (CMODE == 2) v += resid[idx];
          ((float*)Cp)[idx] = v;
        }
      }
}

// ----------------------------------------------------------- flash attention
// Block = 4 waves x 32 q-rows = 128 rows; per (h,b) the 8 blocks handle the
// supertile pair (jj, 15-jj) -> uniform 34 kv-stages/block. K/V staged into
// LDS once per block (4x reuse) via global_load_lds w=16 with pre-swizzled
// source; fragments read back with the matching XOR swizzle (conflict-free).
// Double-buffered with counted vmcnt(4) + raw s_barrier. Swapped-QK^T
// register softmax with exact defer-max. K head-major, pre-scaled by 1/8.
static __device__ __forceinline__ unsigned pk2f(float a, float b) {
  union { bf16 h[2]; unsigned u; } x;
  x.h[0] = (bf16)a; x.h[1] = (bf16)b; return x.u;
}

__global__ __launch_bounds__(256) void attn3_kernel(
    const bf16* __restrict__ Qg, const bf16* __restrict__ Khg,
    const bf16* __restrict__ Vtg, bf16* __restrict__ aog)
{
  __shared__ alignas(16) bf16 KS[2][64 * 64];
  __shared__ alignas(16) bf16 VS[2][64 * 64];
  const int lin = blockIdx.x;
  // XCD grouping: blocks sharing (h,b) share lin%8 -> same XCD L2
  const int hb = (lin & 7) + 8 * (lin >> 6);    // 0..31
  const int jj = (lin >> 3) & 7;                // 0..7
  const int h = hb >> 1, b = hb & 1;
  const int t = threadIdx.x, w = t >> 6, l = t & 63;
  const int qi = l & 31, hi = l >> 5;
  const bf16* Qb = Qg  + ((size_t)b * 2048) * 1024 + h * 64;
  const bf16* Kh = Khg + ((size_t)(b * 16 + h)) * 2048 * 64;
  const bf16* Vh = Vtg + ((size_t)b * 1024 + h * 64) * 2048;
  bf16* Ob = aog + ((size_t)b * 2048) * 1024 + h * 64;

  auto ISSUE = [&](int bi, int kv0) {
    #pragma unroll
    for (int i = 0; i < 2; ++i) {
      int c = w * 128 + i * 64 + l;
      int row = c >> 3;
      int scol = (c & 7) ^ (row & 7);
      gload_lds16(Kh + (size_t)(kv0 + row) * 64 + scol * 8,
                  (bf16*)((char*)KS[bi] + w * 2048 + i * 1024));
    }
    #pragma unroll
    for (int i = 0; i < 2; ++i) {
      int c = w * 128 + i * 64 + l;
      int row = c >> 3;
      int scol = (c & 7) ^ (row & 7);
      gload_lds16(Vh + (size_t)row * 2048 + kv0 + scol * 8,
                  (bf16*)((char*)VS[bi] + w * 2048 + i * 1024));
    }
  };

  #pragma unroll 1
  for (int tsel = 0; tsel < 2; ++tsel) {
    const int T = tsel ? (15 - jj) : jj;
    const int q0 = T * 128 + w * 32;
    const int nst = 2 * T + 2;

    bf16x8 qf[4];
    #pragma unroll
    for (int dc = 0; dc < 4; ++dc)
      qf[dc] = *(const bf16x8*)(Qb + (size_t)(q0 + qi) * 1024 + dc * 16 + hi * 8);

    f32x16 o0, o1;
    #pragma unroll
    for (int r = 0; r < 16; ++r) { o0[r] = 0.f; o1[r] = 0.f; }
    float m_run = -INFINITY, l_run = 0.f;

    ISSUE(0, 0);

    auto SUBSTEP = [&](int bi, int kv0, int s) {
      bf16x8 kf[4], vf[4];
      const int krow = s * 32 + qi;
      #pragma unroll
      for (int dc = 0; dc < 4; ++dc)
        kf[dc] = *(const bf16x8*)((const char*)KS[bi] + krow * 128 +
                                  (((dc * 2 + hi) ^ (krow & 7)) << 4));
      #pragma unroll
      for (int df = 0; df < 2; ++df)
        #pragma unroll
        for (int kc = 0; kc < 2; ++kc) {
          const int d = df * 32 + qi;
          vf[df * 2 + kc] = *(const bf16x8*)((const char*)VS[bi] + d * 128 +
                                             (((s * 4 + kc * 2 + hi) ^ (d & 7)) << 4));
        }
      f32x16 sv;
      #pragma unroll
      for (int r = 0; r < 16; ++r) sv[r] = 0.f;
      #pragma unroll
      for (int dc = 0; dc < 4; ++dc)
        sv = __builtin_amdgcn_mfma_f32_32x32x16_bf16(kf[dc], qf[dc], sv, 0, 0, 0);
      if (kv0 == q0) {                       // diagonal: mask kv > q
        const int qe = qi - 4 * hi;
        #pragma unroll
        for (int r = 0; r < 16; ++r) {
          const int kvc = (r & 3) + 8 * (r >> 2);
          sv[r] = (kvc > qe) ? -INFINITY : sv[r];
        }
      }
      float tm = sv[0];
      #pragma unroll
      for (int r = 1; r < 16; ++r) tm = fmaxf(tm, sv[r]);
      tm = fmaxf(tm, __shfl_xor(tm, 32));
      if (!__all(tm <= m_run)) {             // exact defer-max
        const float mn = fmaxf(m_run, tm);
        const float alpha = __expf(m_run - mn);
        m_run = mn;
        l_run *= alpha;
        o0 *= alpha; o1 *= alpha;
      }
      float rs = 0.f;
      unsigned pk[8];
      #pragma unroll
      for (int i = 0; i < 8; ++i) {
        float pa = __expf(sv[2 * i]     - m_run);
        float pb = __expf(sv[2 * i + 1] - m_run);
        rs += pa + pb;
        pk[i] = pk2f(pa, pb);
      }
      rs += __shfl_xor(rs, 32);
      l_run += rs;
      unsigned ot[8];
      #pragma unroll
      for (int i = 0; i < 8; ++i) ot[i] = __shfl_xor(pk[i], 32);
      #pragma unroll
      for (int kc = 0; kc < 2; ++kc) {
        union { unsigned u[4]; bf16x8 v; } pf;
        pf.u[0] = hi ? ot[4 * kc + 2] : pk[4 * kc + 0];
        pf.u[1] = hi ? ot[4 * kc + 3] : pk[4 * kc + 1];
        pf.u[2] = hi ? pk[4 * kc + 2] : ot[4 * kc + 0];
        pf.u[3] = hi ? pk[4 * kc + 3] : ot[4 * kc + 1];
        o0 = __builtin_amdgcn_mfma_f32_32x32x16_bf16(vf[kc],     pf.v, o0, 0, 0, 0);
        o1 = __builtin_amdgcn_mfma_f32_32x32x16_bf16(vf[2 + kc], pf.v, o1, 0, 0, 0);
      }
    };

    #pragma unroll 1
    for (int st = 0; st < nst; ++st) {
      const int bi = st & 1;
      if (st + 1 < nst) {
        ISSUE(bi ^ 1, (st + 1) * 64);
        asm volatile("s_waitcnt vmcnt(4)" ::: "memory");
      } else {
        asm volatile("s_waitcnt vmcnt(0)" ::: "memory");
      }
      __builtin_amdgcn_s_barrier();
      const int s0 = st * 64;
      if (s0 <= q0)      SUBSTEP(bi, s0,      0);
      if (s0 + 32 <= q0) SUBSTEP(bi, s0 + 32, 1);
      __builtin_amdgcn_s_barrier();
    }

    const float inv = 1.0f / l_run;
    #pragma unroll
    for (int df = 0; df < 2; ++df) {
      #pragma unroll
      for (int rg = 0; rg < 4; ++rg) {
        union { bf16 h4[4]; unsigned long long u; } pr;
        #pragma unroll
        for (int e = 0; e < 4; ++e) {
          float v = (df ? o1[rg * 4 + e] : o0[rg * 4 + e]) * inv;
          pr.h4[e] = (bf16)v;
        }
        *(unsigned long long*)(Ob + (size_t)(q0 + qi) * 1024 + df * 32 + rg * 8 + hi * 4) = pr.u;
      }
    }
  }
}

// ------------------------------------------------------------------ top-k
__global__ __launch_bounds__(256) void topk_kernel(
    const float* __restrict__ ms, const float* __restrict__ kV, float* __restrict__ outp)
{
  const int token = blockIdx.x;
  const int t = threadIdx.x, w = t >> 6, l = t & 63;
  __shared__ alignas(16) float row[4096];
  __shared__ float wv[8]; __shared__ int wi[8];
  __shared__ float cand[4]; __shared__ int candi[4];
  const float* mrow = ms + (size_t)token * 4096;
  #pragma unroll
  for (int p = 0; p < 4; ++p) {
    float4 v = ((const float4*)mrow)[t + p * 256];
    *(float4*)&row[(t + p * 256) * 4] = v;
  }
  __syncthreads();
  for (int k = 0; k < 8; ++k) {
    float bv = -INFINITY; int bi = 0;
    for (int i = t; i < 4096; i += 256) {
      float v = row[i];
      if (v > bv) { bv = v; bi = i; }
    }
    #pragma unroll
    for (int off = 32; off > 0; off >>= 1) {
      float ov = __shfl_xor(bv, off); int oi = __shfl_xor(bi, off);
      if (ov > bv || (ov == bv && oi < bi)) { bv = ov; bi = oi; }
    }
    if (l == 0) { cand[w] = bv; candi[w] = bi; }
    __syncthreads();
    if (t == 0) {
      float best = cand[0]; int besti = candi[0];
      for (int q = 1; q < 4; ++q)
        if (cand[q] > best || (cand[q] == best && candi[q] < besti)) { best = cand[q]; besti = candi[q]; }
      wv[k] = best; wi[k] = besti; row[besti] = -INFINITY;
    }
    __syncthreads();
  }
  if (t == 0) {
    float m = wv[0];
    #pragma unroll
    for (int k = 1; k < 8; ++k) m = fmaxf(m, wv[k]);
    float sden = 0.f; float ex[8];
    #pragma unroll
    for (int k = 0; k < 8; ++k) { ex[k] = __expf(wv[k] - m); sden += ex[k]; }
    #pragma unroll
    for (int k = 0; k < 8; ++k) wv[k] = ex[k] / sden;
  }
  __syncthreads();
  float a0 = 0, a1 = 0, a2 = 0, a3 = 0;
  #pragma unroll
  for (int k = 0; k < 8; ++k) {
    float wk = wv[k];
    float4 vr = *(const float4*)(kV + (size_t)wi[k] * 1024 + t * 4);
    a0 += wk * vr.x; a1 += wk * vr.y; a2 += wk * vr.z; a3 += wk * vr.w;
  }
  float4* op = (float4*)(outp + (size_t)token * 1024) + t;
  float4 cur = *op;
  cur.x += a0; cur.y += a1; cur.z += a2; cur.w += a3;
  *op = cur;
}

// ---------------------------------------------------------------- launcher
extern "C" void kernel_launch(void* const* d_in, const int* in_sizes, int n_in,
                              void* d_out, int out_size, void* d_ws, size_t ws_size,
                              hipStream_t stream)
{
  (void)in_sizes; (void)n_in; (void)out_size; (void)ws_size;
  const float* x    = (const float*)d_in[0];
  const float* imp  = (const float*)d_in[1];
  const float* Wc   = (const float*)d_in[2];
  const float* WQ   = (const float*)d_in[3];
  const float* WK   = (const float*)d_in[4];
  const float* WV   = (const float*)d_in[5];
  const float* Wm   = (const float*)d_in[6];
  const float* comp = (const float*)d_in[7];
  const float* expd = (const float*)d_in[8];
  const float* kK   = (const float*)d_in[9];
  const float* kV   = (const float*)d_in[10];
  const float* WO   = (const float*)d_in[11];
  const float* g1   = (const float*)d_in[12];
  const float* b1   = (const float*)d_in[13];
  const float* g2   = (const float*)d_in[14];
  const float* b2   = (const float*)d_in[15];
  float* out = (float*)d_out;
  char* ws = (char*)d_ws;
  const size_t MB = 1u << 20;
  float* racc = (float*)(ws);
  float* rw   = (float*)(ws + 24576);
  float* Wcat = (float*)(ws + 32768);
  char* ar = ws + 512 * 1024;
  bf16* nx   = (bf16*)(ar);              // 8 MB
  bf16* sct  = (bf16*)(ar +  8 * MB);    // 1 MB  [b][R][D]
  bf16* eqt  = (bf16*)(ar +  9 * MB);    // 1 MB  [b][D][R]
  bf16* ekt  = (bf16*)(ar + 10 * MB);
  bf16* evt  = (bf16*)(ar + 11 * MB);
  bf16* hb   = (bf16*)(ar + 12 * MB);    // 2 MB  [b][S][R]
  bf16* Qb   = (bf16*)(ar + 14 * MB);    // 8 MB each
  bf16* Kb   = (bf16*)(ar + 22 * MB);    // head-major [b][h][s][64]
  bf16* Vtb  = (bf16*)(ar + 30 * MB);    // 8 MB  [b][D][S]  (V transposed)
  bf16* aob  = (bf16*)(ar + 38 * MB);    // 8 MB
  bf16* WOb  = (bf16*)(ar + 46 * MB);    // 2 MB
  bf16* nx2  = (bf16*)(ar);
  bf16* mct  = (bf16*)(ar +  8 * MB);
  bf16* Qmb  = (bf16*)(ar +  9 * MB);    // 2 MB
  bf16* kKb  = (bf16*)(ar + 11 * MB);    // 2 MB
  float* msb = (float*)(ar + 13 * MB);   // 64 MB

  hipMemsetAsync(racc, 0, 20480, stream);
  hipMemcpyAsync(Wcat + 0 * 16384, Wc, 65536, hipMemcpyDeviceToDevice, stream);
  hipMemcpyAsync(Wcat + 1 * 16384, WQ, 65536, hipMemcpyDeviceToDevice, stream);
  hipMemcpyAsync(Wcat + 2 * 16384, WK, 65536, hipMemcpyDeviceToDevice, stream);
  hipMemcpyAsync(Wcat + 3 * 16384, WV, 65536, hipMemcpyDeviceToDevice, stream);
  hipMemcpyAsync(Wcat + 4 * 16384, Wm, 65536, hipMemcpyDeviceToDevice, stream);

  ln_route_kernel<<<4096, 256, 0, stream>>>(x, g1, b1, Wcat, imp, nx, racc, 4, 0);
  route_norm_kernel<<<1, 256, 0, stream>>>(racc, rw, 0, 4);
  mix_t_kernel<<<dim3(16, 4, 2), 256, 0, stream>>>(comp, rw +  0, sct, 1024, 256);
  mix_t_kernel<<<dim3(4, 16, 2), 256, 0, stream>>>(expd, rw + 32, eqt, 256, 1024);
  mix_t_kernel<<<dim3(4, 16, 2), 256, 0, stream>>>(expd, rw + 64, ekt, 256, 1024);
  mix_t_kernel<<<dim3(4, 16, 2), 256, 0, stream>>>(expd, rw + 96, evt, 256, 1024);
  gemm_bt<0><<<dim3(2, 16, 2), 256, 0, stream>>>(nx, sct, hb, nullptr, 2048, 256, 1024,
        (long)2048 * 1024, (long)256 * 1024, (long)2048 * 256, 1.0f);
  gemm_bt<0><<<dim3(8, 16, 2), 256, 0, stream>>>(hb, eqt, Qb, nullptr, 2048, 1024, 256,
        (long)2048 * 256, (long)1024 * 256, (long)2048 * 1024, 1.0f);
  // K head-major + pre-scaled by 1/sqrt(dh)=0.125
  gemm_bt<3><<<dim3(8, 16, 2), 256, 0, stream>>>(hb, ekt, Kb, nullptr, 2048, 1024, 256,
        (long)2048 * 256, (long)1024 * 256, 0L, 0.125f);
  // V produced TRANSPOSED: Vt[b][d][s]
  gemm_bt<0><<<dim3(16, 8, 2), 256, 0, stream>>>(evt, hb, Vtb, nullptr, 1024, 2048, 256,
        (long)1024 * 256, (long)2048 * 256, (long)1024 * 2048, 1.0f);
  attn3_kernel<<<256, 256, 0, stream>>>(Qb, Kb, Vtb, aob);
  cvt_bf16_kernel<<<1024, 256, 0, stream>>>(WO, WOb, 262144);
  gemm_bt<2><<<dim3(8, 32, 1), 256, 0, stream>>>(aob, WOb, out, x, 4096, 1024, 1024,
        0L, 0L, 0L, 1.0f);
  ln_route_kernel<<<4096, 256, 0, stream>>>(out, g2, b2, Wcat + 4 * 16384, imp, nx2, racc, 1, 4);
  route_norm_kernel<<<1, 256, 0, stream>>>(racc, rw, 4, 1);
  mix_t_kernel<<<dim3(16, 4, 2), 256, 0, stream>>>(comp, rw + 128, mct, 1024, 256);
  gemm_bt<0><<<dim3(2, 16, 2), 256, 0, stream>>>(nx2, mct, Qmb, nullptr, 2048, 256, 1024,
        (long)2048 * 1024, (long)256 * 1024, (long)2048 * 256, 1.0f);
  cvt_bf16_kernel<<<1024, 256, 0, stream>>>(kK, kKb, 262144);
  gemm_bt<1><<<dim3(32, 16, 2), 256, 0, stream>>>(Qmb, kKb, msb, nullptr, 2048, 4096, 256,
        (long)2048 * 256, 0L, (long)2048 * 4096, 0.0625f);
  topk_kernel<<<4096, 256, 0, stream>>>(msb, kV, out);
}

// Round 4
// 352.389 us; speedup vs baseline: 1.5636x; 1.0133x over previous
//
#include <hip/hip_runtime.h>
#include <hip/hip_bf16.h>
#include <math.h>

typedef __bf16 bf16;
typedef __attribute__((ext_vector_type(8))) __bf16 bf16x8;
typedef __attribute__((ext_vector_type(4))) __bf16 bf16x4;
typedef __attribute__((ext_vector_type(4))) float f32x4;
typedef __attribute__((ext_vector_type(16))) float f32x16;

static __device__ __forceinline__ void gload_lds16(const bf16* g, bf16* l) {
  __builtin_amdgcn_global_load_lds((const __attribute__((address_space(1))) void*)g,
                                   (__attribute__((address_space(3))) void*)l, 16, 0, 0);
}

// ---------------------------------------------------------------- LN + route
__global__ __launch_bounds__(256) void ln_route_kernel(
    const float* __restrict__ x, const float* __restrict__ gam, const float* __restrict__ bet,
    const float* __restrict__ Wg, const float* __restrict__ imp,
    bf16* __restrict__ nxo, float* __restrict__ racc, int ngroups, int gbase)
{
  const int token = blockIdx.x;
  const int b = token >> 11;                 // S = 2048
  const int t = threadIdx.x, w = t >> 6, l = t & 63;
  __shared__ alignas(16) float row[1024];
  __shared__ float red1[4], red2[4];
  float4 xv = ((const float4*)(x + (size_t)token * 1024))[t];
  float s  = xv.x + xv.y + xv.z + xv.w;
  float sq = xv.x*xv.x + xv.y*xv.y + xv.z*xv.z + xv.w*xv.w;
  #pragma unroll
  for (int off = 32; off > 0; off >>= 1) { s += __shfl_xor(s, off); sq += __shfl_xor(sq, off); }
  if (l == 0) { red1[w] = s; red2[w] = sq; }
  __syncthreads();
  s  = red1[0] + red1[1] + red1[2] + red1[3];
  sq = red2[0] + red2[1] + red2[2] + red2[3];
  const float mu  = s * (1.f / 1024.f);
  const float var = sq * (1.f / 1024.f) - mu * mu;
  const float rs  = rsqrtf(var + 1e-5f);
  float4 gv = ((const float4*)gam)[t];
  float4 bv = ((const float4*)bet)[t];
  float n0 = (xv.x - mu) * rs * gv.x + bv.x;
  float n1 = (xv.y - mu) * rs * gv.y + bv.y;
  float n2 = (xv.z - mu) * rs * gv.z + bv.z;
  float n3 = (xv.w - mu) * rs * gv.w + bv.w;
  row[t*4+0] = n0; row[t*4+1] = n1; row[t*4+2] = n2; row[t*4+3] = n3;
  bf16x4 pk = {(bf16)n0, (bf16)n1, (bf16)n2, (bf16)n3};
  *(bf16x4*)(nxo + (size_t)token * 1024 + t * 4) = pk;
  __syncthreads();
  if (w < ngroups) {
    const float* Wbase = Wg + (size_t)w * 16 * 1024;
    float m_run = -INFINITY, s_run = 0.f, myv = 0.f;
    for (int e = 0; e < 16; ++e) {
      const float* wr = Wbase + e * 1024;
      float dv = 0.f;
      #pragma unroll
      for (int i = 0; i < 16; ++i) dv += row[l + i*64] * wr[l + i*64];
      #pragma unroll
      for (int off = 32; off > 0; off >>= 1) dv += __shfl_xor(dv, off);
      if (l == e) myv = dv;
      float mn = fmaxf(m_run, dv);
      s_run = s_run * __expf(m_run - mn) + __expf(dv - mn);
      m_run = mn;
    }
    if (l < 16) {
      float pref = __expf(myv - m_run) / s_run;
      atomicAdd(racc + ((((size_t)(token & 31)) * 5 + gbase + w) * 2 + b) * 16 + l,
                imp[token] * pref);
    }
  }
}

// ------------------------------------------------------------- route norm
__global__ void route_norm_kernel(const float* __restrict__ racc, float* __restrict__ rw,
                                  int g0, int ng)
{
  __shared__ float pooled[5][2][16];
  const int t = threadIdx.x;
  const int n = ng * 32;
  int g = 0, b = 0, e = 0;
  if (t < n) {
    g = g0 + (t >> 5); b = (t >> 4) & 1; e = t & 15;
    float s = 0.f;
    for (int sl = 0; sl < 32; ++sl) s += racc[(((size_t)sl * 5 + g) * 2 + b) * 16 + e];
    pooled[g][b][e] = s;
  }
  __syncthreads();
  if (t < n) {
    float den = 1e-8f;
    #pragma unroll
    for (int e2 = 0; e2 < 16; ++e2) den += pooled[g][b][e2];
    rw[((size_t)g * 2 + b) * 16 + e] = pooled[g][b][e] / den;
  }
}

// ----------------------------------------------------- pool mix (transposed)
__global__ __launch_bounds__(256) void mix_t_kernel(
    const float* __restrict__ pool, const float* __restrict__ rwg,
    bf16* __restrict__ out, int dim1, int dim2)
{
  const int i0 = blockIdx.x * 64, j0 = blockIdx.y * 64, b = blockIdx.z;
  const int t = threadIdx.x;
  __shared__ float tile[64][65];
  float wn[16];
  #pragma unroll
  for (int n = 0; n < 16; ++n) wn[n] = rwg[b * 16 + n];
  float acc[16];
  #pragma unroll
  for (int k = 0; k < 16; ++k) acc[k] = 0.f;
  const int lj = t & 63, li = t >> 6;
  for (int n = 0; n < 16; ++n) {
    __syncthreads();
    #pragma unroll
    for (int it = 0; it < 16; ++it)
      tile[li + it*4][lj] = pool[((size_t)n * dim1 + i0 + li + it*4) * dim2 + j0 + lj];
    __syncthreads();
    const float wv = wn[n];
    #pragma unroll
    for (int it = 0; it < 16; ++it)
      acc[it] += wv * tile[lj][li + it*4];
  }
  #pragma unroll
  for (int it = 0; it < 16; ++it)
    out[((size_t)b * dim2 + j0 + li + it*4) * dim1 + i0 + lj] = (bf16)acc[it];
}

// ------------------------------------------------------------ f32 -> bf16
__global__ void cvt_bf16_kernel(const float* __restrict__ in, bf16* __restrict__ out, int n4)
{
  const int i = blockIdx.x * 256 + threadIdx.x;
  if (i < n4) {
    float4 v = ((const float4*)in)[i];
    bf16x4 o = {(bf16)v.x, (bf16)v.y, (bf16)v.z, (bf16)v.w};
    ((bf16x4*)out)[i] = o;
  }
}

// --------------------------------------------------------------- GEMM (Bt)
// CMODE: 0 = bf16 out, 1 = f32 out, 2 = f32 out + f32 resid,
//        3 = bf16 out in head-major layout [b][h=c/64][r][64].
template<int CMODE>
__global__ __launch_bounds__(256) void gemm_bt(
    const bf16* __restrict__ A, const bf16* __restrict__ Bt, void* __restrict__ Cp,
    const float* __restrict__ resid, int M, int N, int K,
    long sA, long sB, long sC, float scale)
{
  __shared__ alignas(16) bf16 As[128 * 32];
  __shared__ alignas(16) bf16 Bs[128 * 32];
  const int t = threadIdx.x, w = t >> 6, l = t & 63;
  const int llo = l & 15, lhi = l >> 4;
  const int wm = w >> 1, wn = w & 1;
  const int m0 = blockIdx.y * 128, n0 = blockIdx.x * 128;
  const bf16* Ab = A  + (size_t)blockIdx.z * sA;
  const bf16* Bb = Bt + (size_t)blockIdx.z * sB;
  f32x4 acc[4][4];
  #pragma unroll
  for (int i = 0; i < 4; ++i)
    #pragma unroll
    for (int j = 0; j < 4; ++j) acc[i][j] = (f32x4){0.f, 0.f, 0.f, 0.f};

  const int arow = t >> 2, akb = t & 3;
  const bf16* asrc = Ab + (size_t)(m0 + arow) * K + akb * 8;
  const bf16* bsrc = Bb + (size_t)(n0 + arow) * K + akb * 8;
  const size_t rstep = (size_t)64 * K;
  const int aoff0 = arow * 64 + ((akb * 16) ^ (((arow >> 1) & 3) << 4));
  const int aoff1 = aoff0 + 64 * 64;

  uint4 a0 = *(const uint4*)(asrc);
  uint4 a1 = *(const uint4*)(asrc + rstep);
  uint4 b0 = *(const uint4*)(bsrc);
  uint4 b1 = *(const uint4*)(bsrc + rstep);

  for (int kt = 0; kt < K; kt += 32) {
    __syncthreads();
    *(uint4*)((char*)As + aoff0) = a0;
    *(uint4*)((char*)As + aoff1) = a1;
    *(uint4*)((char*)Bs + aoff0) = b0;
    *(uint4*)((char*)Bs + aoff1) = b1;
    __syncthreads();
    if (kt + 32 < K) {
      a0 = *(const uint4*)(asrc + kt + 32);
      a1 = *(const uint4*)(asrc + rstep + kt + 32);
      b0 = *(const uint4*)(bsrc + kt + 32);
      b1 = *(const uint4*)(bsrc + rstep + kt + 32);
    }
    bf16x8 af[4], bfr[4];
    #pragma unroll
    for (int fi = 0; fi < 4; ++fi) {
      int r = wm * 64 + fi * 16 + llo;
      af[fi] = *(const bf16x8*)((const char*)As + (r * 64 + ((lhi * 16) ^ (((r >> 1) & 3) << 4))));
      int c = wn * 64 + fi * 16 + llo;
      bfr[fi] = *(const bf16x8*)((const char*)Bs + (c * 64 + ((lhi * 16) ^ (((c >> 1) & 3) << 4))));
    }
    #pragma unroll
    for (int fi = 0; fi < 4; ++fi)
      #pragma unroll
      for (int fj = 0; fj < 4; ++fj)
        acc[fi][fj] = __builtin_amdgcn_mfma_f32_16x16x32_bf16(af[fi], bfr[fj], acc[fi][fj], 0, 0, 0);
  }

  #pragma unroll
  for (int fi = 0; fi < 4; ++fi)
    #pragma unroll
    for (int fj = 0; fj < 4; ++fj)
      #pragma unroll
      for (int jj = 0; jj < 4; ++jj) {
        int r = m0 + wm * 64 + fi * 16 + lhi * 4 + jj;
        int c = n0 + wn * 64 + fj * 16 + llo;
        size_t idx = (size_t)blockIdx.z * sC + (size_t)r * N + c;
        float v = acc[fi][fj][jj] * scale;
        if (CMODE == 0) {
          ((bf16*)Cp)[idx] = (bf16)v;
        } else if (CMODE == 3) {
          size_t idx3 = (((size_t)blockIdx.z * 16 + (c >> 6)) * 2048 + r) * 64 + (c & 63);
          ((bf16*)Cp)[idx3] = (bf16)v;
        } else {
          if (CMODE == 2) v += resid[idx];
          ((float*)Cp)[idx] = v;
        }
      }
}

// ----------------------------------------------------------- flash attention
// attn4: one 128-row supertile per block (grid 512 = 2 blocks/CU, 2 waves/SIMD
// -> stall cycles of one block's serial softmax chain filled by the other).
// Heavy/light T interleaved in dispatch order; blocks sharing (h,b) share
// idx%8 -> same XCD L2. Merged 64-kv step: one max-tree/shfl/defer-branch/
// rescale per 64 kv (was per 32). K/V LDS double-buffer via global_load_lds
// w=16, pre-swizzled source + XOR-swizzled b128 reads, counted vmcnt(4).
static __device__ __forceinline__ unsigned pk2f(float a, float b) {
  union { bf16 h[2]; unsigned u; } x;
  x.h[0] = (bf16)a; x.h[1] = (bf16)b; return x.u;
}

__global__ __launch_bounds__(256) void attn4_kernel(
    const bf16* __restrict__ Qg, const bf16* __restrict__ Khg,
    const bf16* __restrict__ Vtg, bf16* __restrict__ aog)
{
  __shared__ alignas(16) bf16 KS[2][64 * 64];
  __shared__ alignas(16) bf16 VS[2][64 * 64];
  const int idx = blockIdx.x;
  const int hb = idx & 31, g = idx >> 5;
  const int T = (g & 1) ? (g >> 1) : (15 - (g >> 1));   // 15,0,14,1,... interleave
  const int h = hb >> 1, b = hb & 1;
  const int t = threadIdx.x, w = t >> 6, l = t & 63;
  const int qi = l & 31, hi = l >> 5;
  const bf16* Qb = Qg  + ((size_t)b * 2048) * 1024 + h * 64;
  const bf16* Kh = Khg + ((size_t)(b * 16 + h)) * 2048 * 64;
  const bf16* Vh = Vtg + ((size_t)b * 1024 + h * 64) * 2048;
  bf16* Ob = aog + ((size_t)b * 2048) * 1024 + h * 64;
  const int q0 = T * 128 + w * 32;
  const int nst = 2 * T + 2;

  auto ISSUE = [&](int bi, int kv0) {
    #pragma unroll
    for (int i = 0; i < 2; ++i) {
      int c = w * 128 + i * 64 + l;
      int row = c >> 3;
      int scol = (c & 7) ^ (row & 7);
      gload_lds16(Kh + (size_t)(kv0 + row) * 64 + scol * 8,
                  (bf16*)((char*)KS[bi] + w * 2048 + i * 1024));
    }
    #pragma unroll
    for (int i = 0; i < 2; ++i) {
      int c = w * 128 + i * 64 + l;
      int row = c >> 3;
      int scol = (c & 7) ^ (row & 7);
      gload_lds16(Vh + (size_t)row * 2048 + kv0 + scol * 8,
                  (bf16*)((char*)VS[bi] + w * 2048 + i * 1024));
    }
  };

  bf16x8 qf[4];
  #pragma unroll
  for (int dc = 0; dc < 4; ++dc)
    qf[dc] = *(const bf16x8*)(Qb + (size_t)(q0 + qi) * 1024 + dc * 16 + hi * 8);

  f32x16 o0, o1;
  #pragma unroll
  for (int r = 0; r < 16; ++r) { o0[r] = 0.f; o1[r] = 0.f; }
  float m_run = -INFINITY, l_run = 0.f;

  ISSUE(0, 0);

  auto STEP64 = [&](int bi, int s0) {
    const bool h2 = (s0 + 32 <= q0);
    bf16x8 kf[8];
    const int kr1 = qi, kr2 = 32 + qi;
    #pragma unroll
    for (int dc = 0; dc < 4; ++dc) {
      kf[dc]     = *(const bf16x8*)((const char*)KS[bi] + kr1 * 128 +
                                    (((dc * 2 + hi) ^ (kr1 & 7)) << 4));
      kf[4 + dc] = *(const bf16x8*)((const char*)KS[bi] + kr2 * 128 +
                                    (((dc * 2 + hi) ^ (kr2 & 7)) << 4));
    }
    f32x16 sv1, sv2;
    #pragma unroll
    for (int r = 0; r < 16; ++r) { sv1[r] = 0.f; sv2[r] = 0.f; }
    __builtin_amdgcn_s_setprio(1);
    #pragma unroll
    for (int dc = 0; dc < 4; ++dc)
      sv1 = __builtin_amdgcn_mfma_f32_32x32x16_bf16(kf[dc], qf[dc], sv1, 0, 0, 0);
    if (h2) {
      #pragma unroll
      for (int dc = 0; dc < 4; ++dc)
        sv2 = __builtin_amdgcn_mfma_f32_32x32x16_bf16(kf[4 + dc], qf[dc], sv2, 0, 0, 0);
    }
    __builtin_amdgcn_s_setprio(0);
    const int qe = qi - 4 * hi;
    if (s0 == q0) {                           // diagonal in first half
      #pragma unroll
      for (int r = 0; r < 16; ++r) {
        const int kvc = (r & 3) + 8 * (r >> 2);
        sv1[r] = (kvc > qe) ? -INFINITY : sv1[r];
      }
    }
    if (h2 && s0 + 32 == q0) {                // diagonal in second half
      #pragma unroll
      for (int r = 0; r < 16; ++r) {
        const int kvc = (r & 3) + 8 * (r >> 2);
        sv2[r] = (kvc > qe) ? -INFINITY : sv2[r];
      }
    }
    float tm = sv1[0];
    #pragma unroll
    for (int r = 1; r < 16; ++r) tm = fmaxf(tm, sv1[r]);
    if (h2) {
      #pragma unroll
      for (int r = 0; r < 16; ++r) tm = fmaxf(tm, sv2[r]);
    }
    tm = fmaxf(tm, __shfl_xor(tm, 32));
    if (!__all(tm <= m_run)) {                // exact defer-max
      const float mn = fmaxf(m_run, tm);
      const float alpha = __expf(m_run - mn);
      m_run = mn;
      l_run *= alpha;
      o0 *= alpha; o1 *= alpha;
    }
    float rs = 0.f;
    unsigned pk[16], ot[16];
    #pragma unroll
    for (int i = 0; i < 8; ++i) {
      float pa = __expf(sv1[2 * i]     - m_run);
      float pb = __expf(sv1[2 * i + 1] - m_run);
      rs += pa + pb;
      pk[i] = pk2f(pa, pb);
    }
    if (h2) {
      #pragma unroll
      for (int i = 0; i < 8; ++i) {
        float pa = __expf(sv2[2 * i]     - m_run);
        float pb = __expf(sv2[2 * i + 1] - m_run);
        rs += pa + pb;
        pk[8 + i] = pk2f(pa, pb);
      }
    }
    rs += __shfl_xor(rs, 32);
    l_run += rs;
    #pragma unroll
    for (int i = 0; i < 8; ++i) ot[i] = __shfl_xor(pk[i], 32);
    if (h2) {
      #pragma unroll
      for (int i = 0; i < 8; ++i) ot[8 + i] = __shfl_xor(pk[8 + i], 32);
    }
    __builtin_amdgcn_s_setprio(1);
    #pragma unroll
    for (int c2 = 0; c2 < 4; ++c2) {
      if (c2 < 2 || h2) {
        union { unsigned u[4]; bf16x8 v; } pf;
        pf.u[0] = hi ? ot[4 * c2 + 2] : pk[4 * c2 + 0];
        pf.u[1] = hi ? ot[4 * c2 + 3] : pk[4 * c2 + 1];
        pf.u[2] = hi ? pk[4 * c2 + 2] : ot[4 * c2 + 0];
        pf.u[3] = hi ? pk[4 * c2 + 3] : ot[4 * c2 + 1];
        const int d0 = qi, d1 = 32 + qi;
        bf16x8 v0 = *(const bf16x8*)((const char*)VS[bi] + d0 * 128 +
                                     (((c2 * 2 + hi) ^ (d0 & 7)) << 4));
        bf16x8 v1 = *(const bf16x8*)((const char*)VS[bi] + d1 * 128 +
                                     (((c2 * 2 + hi) ^ (d1 & 7)) << 4));
        o0 = __builtin_amdgcn_mfma_f32_32x32x16_bf16(v0, pf.v, o0, 0, 0, 0);
        o1 = __builtin_amdgcn_mfma_f32_32x32x16_bf16(v1, pf.v, o1, 0, 0, 0);
      }
    }
    __builtin_amdgcn_s_setprio(0);
  };

  #pragma unroll 1
  for (int st = 0; st < nst; ++st) {
    const int bi = st & 1;
    if (st + 1 < nst) {
      ISSUE(bi ^ 1, (st + 1) * 64);
      asm volatile("s_waitcnt vmcnt(4)" ::: "memory");
    } else {
      asm volatile("s_waitcnt vmcnt(0)" ::: "memory");
    }
    __builtin_amdgcn_s_barrier();
    const int s0 = st * 64;
    if (s0 <= q0) STEP64(bi, s0);
    __builtin_amdgcn_s_barrier();
  }

  const float inv = 1.0f / l_run;
  #pragma unroll
  for (int df = 0; df < 2; ++df) {
    #pragma unroll
    for (int rg = 0; rg < 4; ++rg) {
      union { bf16 h4[4]; unsigned long long u; } pr;
      #pragma unroll
      for (int e = 0; e < 4; ++e) {
        float v = (df ? o1[rg * 4 + e] : o0[rg * 4 + e]) * inv;
        pr.h4[e] = (bf16)v;
      }
      *(unsigned long long*)(Ob + (size_t)(q0 + qi) * 1024 + df * 32 + rg * 8 + hi * 4) = pr.u;
    }
  }
}

// ------------------------------------------------------------------ top-k
__global__ __launch_bounds__(256) void topk_kernel(
    const float* __restrict__ ms, const float* __restrict__ kV, float* __restrict__ outp)
{
  const int token = blockIdx.x;
  const int t = threadIdx.x, w = t >> 6, l = t & 63;
  __shared__ alignas(16) float row[4096];
  __shared__ float wv[8]; __shared__ int wi[8];
  __shared__ float cand[4]; __shared__ int candi[4];
  const float* mrow = ms + (size_t)token * 4096;
  #pragma unroll
  for (int p = 0; p < 4; ++p) {
    float4 v = ((const float4*)mrow)[t + p * 256];
    *(float4*)&row[(t + p * 256) * 4] = v;
  }
  __syncthreads();
  for (int k = 0; k < 8; ++k) {
    float bv = -INFINITY; int bi = 0;
    for (int i = t; i < 4096; i += 256) {
      float v = row[i];
      if (v > bv) { bv = v; bi = i; }
    }
    #pragma unroll
    for (int off = 32; off > 0; off >>= 1) {
      float ov = __shfl_xor(bv, off); int oi = __shfl_xor(bi, off);
      if (ov > bv || (ov == bv && oi < bi)) { bv = ov; bi = oi; }
    }
    if (l == 0) { cand[w] = bv; candi[w] = bi; }
    __syncthreads();
    if (t == 0) {
      float best = cand[0]; int besti = candi[0];
      for (int q = 1; q < 4; ++q)
        if (cand[q] > best || (cand[q] == best && candi[q] < besti)) { best = cand[q]; besti = candi[q]; }
      wv[k] = best; wi[k] = besti; row[besti] = -INFINITY;
    }
    __syncthreads();
  }
  if (t == 0) {
    float m = wv[0];
    #pragma unroll
    for (int k = 1; k < 8; ++k) m = fmaxf(m, wv[k]);
    float sden = 0.f; float ex[8];
    #pragma unroll
    for (int k = 0; k < 8; ++k) { ex[k] = __expf(wv[k] - m); sden += ex[k]; }
    #pragma unroll
    for (int k = 0; k < 8; ++k) wv[k] = ex[k] / sden;
  }
  __syncthreads();
  float a0 = 0, a1 = 0, a2 = 0, a3 = 0;
  #pragma unroll
  for (int k = 0; k < 8; ++k) {
    float wk = wv[k];
    float4 vr = *(const float4*)(kV + (size_t)wi[k] * 1024 + t * 4);
    a0 += wk * vr.x; a1 += wk * vr.y; a2 += wk * vr.z; a3 += wk * vr.w;
  }
  float4* op = (float4*)(outp + (size_t)token * 1024) + t;
  float4 cur = *op;
  cur.x += a0; cur.y += a1; cur.z += a2; cur.w += a3;
  *op = cur;
}

// ---------------------------------------------------------------- launcher
extern "C" void kernel_launch(void* const* d_in, const int* in_sizes, int n_in,
                              void* d_out, int out_size, void* d_ws, size_t ws_size,
                              hipStream_t stream)
{
  (void)in_sizes; (void)n_in; (void)out_size; (void)ws_size;
  const float* x    = (const float*)d_in[0];
  const float* imp  = (const float*)d_in[1];
  const float* Wc   = (const float*)d_in[2];
  const float* WQ   = (const float*)d_in[3];
  const float* WK   = (const float*)d_in[4];
  const float* WV   = (const float*)d_in[5];
  const float* Wm   = (const float*)d_in[6];
  const float* comp = (const float*)d_in[7];
  const float* expd = (const float*)d_in[8];
  const float* kK   = (const float*)d_in[9];
  const float* kV   = (const float*)d_in[10];
  const float* WO   = (const float*)d_in[11];
  const float* g1   = (const float*)d_in[12];
  const float* b1   = (const float*)d_in[13];
  const float* g2   = (const float*)d_in[14];
  const float* b2   = (const float*)d_in[15];
  float* out = (float*)d_out;
  char* ws = (char*)d_ws;
  const size_t MB = 1u << 20;
  float* racc = (float*)(ws);
  float* rw   = (float*)(ws + 24576);
  float* Wcat = (float*)(ws + 32768);
  char* ar = ws + 512 * 1024;
  bf16* nx   = (bf16*)(ar);              // 8 MB
  bf16* sct  = (bf16*)(ar +  8 * MB);    // 1 MB  [b][R][D]
  bf16* eqt  = (bf16*)(ar +  9 * MB);    // 1 MB  [b][D][R]
  bf16* ekt  = (bf16*)(ar + 10 * MB);
  bf16* evt  = (bf16*)(ar + 11 * MB);
  bf16* hb   = (bf16*)(ar + 12 * MB);    // 2 MB  [b][S][R]
  bf16* Qb   = (bf16*)(ar + 14 * MB);    // 8 MB each
  bf16* Kb   = (bf16*)(ar + 22 * MB);    // head-major [b][h][s][64]
  bf16* Vtb  = (bf16*)(ar + 30 * MB);    // 8 MB  [b][D][S]  (V transposed)
  bf16* aob  = (bf16*)(ar + 38 * MB);    // 8 MB
  bf16* WOb  = (bf16*)(ar + 46 * MB);    // 2 MB
  bf16* nx2  = (bf16*)(ar);
  bf16* mct  = (bf16*)(ar +  8 * MB);
  bf16* Qmb  = (bf16*)(ar +  9 * MB);    // 2 MB
  bf16* kKb  = (bf16*)(ar + 11 * MB);    // 2 MB
  float* msb = (float*)(ar + 13 * MB);   // 64 MB

  hipMemsetAsync(racc, 0, 20480, stream);
  hipMemcpyAsync(Wcat + 0 * 16384, Wc, 65536, hipMemcpyDeviceToDevice, stream);
  hipMemcpyAsync(Wcat + 1 * 16384, WQ, 65536, hipMemcpyDeviceToDevice, stream);
  hipMemcpyAsync(Wcat + 2 * 16384, WK, 65536, hipMemcpyDeviceToDevice, stream);
  hipMemcpyAsync(Wcat + 3 * 16384, WV, 65536, hipMemcpyDeviceToDevice, stream);
  hipMemcpyAsync(Wcat + 4 * 16384, Wm, 65536, hipMemcpyDeviceToDevice, stream);

  ln_route_kernel<<<4096, 256, 0, stream>>>(x, g1, b1, Wcat, imp, nx, racc, 4, 0);
  route_norm_kernel<<<1, 256, 0, stream>>>(racc, rw, 0, 4);
  mix_t_kernel<<<dim3(16, 4, 2), 256, 0, stream>>>(comp, rw +  0, sct, 1024, 256);
  mix_t_kernel<<<dim3(4, 16, 2), 256, 0, stream>>>(expd, rw + 32, eqt, 256, 1024);
  mix_t_kernel<<<dim3(4, 16, 2), 256, 0, stream>>>(expd, rw + 64, ekt, 256, 1024);
  mix_t_kernel<<<dim3(4, 16, 2), 256, 0, stream>>>(expd, rw + 96, evt, 256, 1024);
  gemm_bt<0><<<dim3(2, 16, 2), 256, 0, stream>>>(nx, sct, hb, nullptr, 2048, 256, 1024,
        (long)2048 * 1024, (long)256 * 1024, (long)2048 * 256, 1.0f);
  gemm_bt<0><<<dim3(8, 16, 2), 256, 0, stream>>>(hb, eqt, Qb, nullptr, 2048, 1024, 256,
        (long)2048 * 256, (long)1024 * 256, (long)2048 * 1024, 1.0f);
  // K head-major + pre-scaled by 1/sqrt(dh)=0.125
  gemm_bt<3><<<dim3(8, 16, 2), 256, 0, stream>>>(hb, ekt, Kb, nullptr, 2048, 1024, 256,
        (long)2048 * 256, (long)1024 * 256, 0L, 0.125f);
  // V produced TRANSPOSED: Vt[b][d][s]
  gemm_bt<0><<<dim3(16, 8, 2), 256, 0, stream>>>(evt, hb, Vtb, nullptr, 1024, 2048, 256,
        (long)1024 * 256, (long)2048 * 256, (long)1024 * 2048, 1.0f);
  attn4_kernel<<<512, 256, 0, stream>>>(Qb, Kb, Vtb, aob);
  cvt_bf16_kernel<<<1024, 256, 0, stream>>>(WO, WOb, 262144);
  gemm_bt<2><<<dim3(8, 32, 1), 256, 0, stream>>>(aob, WOb, out, x, 4096, 1024, 1024,
        0L, 0L, 0L, 1.0f);
  ln_route_kernel<<<4096, 256, 0, stream>>>(out, g2, b2, Wcat + 4 * 16384, imp, nx2, racc, 1, 4);
  route_norm_kernel<<<1, 256, 0, stream>>>(racc, rw, 4, 1);
  mix_t_kernel<<<dim3(16, 4, 2), 256, 0, stream>>>(comp, rw + 128, mct, 1024, 256);
  gemm_bt<0><<<dim3(2, 16, 2), 256, 0, stream>>>(nx2, mct, Qmb, nullptr, 2048, 256, 1024,
        (long)2048 * 1024, (long)256 * 1024, (long)2048 * 256, 1.0f);
  cvt_bf16_kernel<<<1024, 256, 0, stream>>>(kK, kKb, 262144);
  gemm_bt<1><<<dim3(32, 16, 2), 256, 0, stream>>>(Qmb, kKb, msb, nullptr, 2048, 4096, 256,
        (long)2048 * 256, 0L, (long)2048 * 4096, 0.0625f);
  topk_kernel<<<4096, 256, 0, stream>>>(msb, kV, out);
}

// Round 5
// 332.077 us; speedup vs baseline: 1.6593x; 1.0612x over previous
//
#include <hip/hip_runtime.h>
#include <hip/hip_bf16.h>
#include <math.h>

typedef __bf16 bf16;
typedef __attribute__((ext_vector_type(8))) __bf16 bf16x8;
typedef __attribute__((ext_vector_type(4))) __bf16 bf16x4;
typedef __attribute__((ext_vector_type(4))) float f32x4;
typedef __attribute__((ext_vector_type(16))) float f32x16;

static __device__ __forceinline__ void gload_lds16(const bf16* g, bf16* l) {
  __builtin_amdgcn_global_load_lds((const __attribute__((address_space(1))) void*)g,
                                   (__attribute__((address_space(3))) void*)l, 16, 0, 0);
}

// ---------------------------------------------------------------- LN + route
__global__ __launch_bounds__(256) void ln_route_kernel(
    const float* __restrict__ x, const float* __restrict__ gam, const float* __restrict__ bet,
    const float* __restrict__ Wg, const float* __restrict__ imp,
    bf16* __restrict__ nxo, float* __restrict__ racc, int ngroups, int gbase)
{
  const int token = blockIdx.x;
  const int b = token >> 11;                 // S = 2048
  const int t = threadIdx.x, w = t >> 6, l = t & 63;
  __shared__ alignas(16) float row[1024];
  __shared__ float red1[4], red2[4];
  float4 xv = ((const float4*)(x + (size_t)token * 1024))[t];
  float s  = xv.x + xv.y + xv.z + xv.w;
  float sq = xv.x*xv.x + xv.y*xv.y + xv.z*xv.z + xv.w*xv.w;
  #pragma unroll
  for (int off = 32; off > 0; off >>= 1) { s += __shfl_xor(s, off); sq += __shfl_xor(sq, off); }
  if (l == 0) { red1[w] = s; red2[w] = sq; }
  __syncthreads();
  s  = red1[0] + red1[1] + red1[2] + red1[3];
  sq = red2[0] + red2[1] + red2[2] + red2[3];
  const float mu  = s * (1.f / 1024.f);
  const float var = sq * (1.f / 1024.f) - mu * mu;
  const float rs  = rsqrtf(var + 1e-5f);
  float4 gv = ((const float4*)gam)[t];
  float4 bv = ((const float4*)bet)[t];
  float n0 = (xv.x - mu) * rs * gv.x + bv.x;
  float n1 = (xv.y - mu) * rs * gv.y + bv.y;
  float n2 = (xv.z - mu) * rs * gv.z + bv.z;
  float n3 = (xv.w - mu) * rs * gv.w + bv.w;
  row[t*4+0] = n0; row[t*4+1] = n1; row[t*4+2] = n2; row[t*4+3] = n3;
  bf16x4 pk = {(bf16)n0, (bf16)n1, (bf16)n2, (bf16)n3};
  *(bf16x4*)(nxo + (size_t)token * 1024 + t * 4) = pk;
  __syncthreads();
  if (w < ngroups) {
    const float* Wbase = Wg + (size_t)w * 16 * 1024;
    float m_run = -INFINITY, s_run = 0.f, myv = 0.f;
    for (int e = 0; e < 16; ++e) {
      const float* wr = Wbase + e * 1024;
      float dv = 0.f;
      #pragma unroll
      for (int i = 0; i < 16; ++i) dv += row[l + i*64] * wr[l + i*64];
      #pragma unroll
      for (int off = 32; off > 0; off >>= 1) dv += __shfl_xor(dv, off);
      if (l == e) myv = dv;
      float mn = fmaxf(m_run, dv);
      s_run = s_run * __expf(m_run - mn) + __expf(dv - mn);
      m_run = mn;
    }
    if (l < 16) {
      float pref = __expf(myv - m_run) / s_run;
      atomicAdd(racc + ((((size_t)(token & 31)) * 5 + gbase + w) * 2 + b) * 16 + l,
                imp[token] * pref);
    }
  }
}

// ------------------------------------------------------------- route norm
__global__ void route_norm_kernel(const float* __restrict__ racc, float* __restrict__ rw,
                                  int g0, int ng)
{
  __shared__ float pooled[5][2][16];
  const int t = threadIdx.x;
  const int n = ng * 32;
  int g = 0, b = 0, e = 0;
  if (t < n) {
    g = g0 + (t >> 5); b = (t >> 4) & 1; e = t & 15;
    float s = 0.f;
    for (int sl = 0; sl < 32; ++sl) s += racc[(((size_t)sl * 5 + g) * 2 + b) * 16 + e];
    pooled[g][b][e] = s;
  }
  __syncthreads();
  if (t < n) {
    float den = 1e-8f;
    #pragma unroll
    for (int e2 = 0; e2 < 16; ++e2) den += pooled[g][b][e2];
    rw[((size_t)g * 2 + b) * 16 + e] = pooled[g][b][e] / den;
  }
}

// ----------------------------------------------------- pool mix (transposed)
__global__ __launch_bounds__(256) void mix_t_kernel(
    const float* __restrict__ pool, const float* __restrict__ rwg,
    bf16* __restrict__ out, int dim1, int dim2)
{
  const int i0 = blockIdx.x * 64, j0 = blockIdx.y * 64, b = blockIdx.z;
  const int t = threadIdx.x;
  __shared__ float tile[64][65];
  float wn[16];
  #pragma unroll
  for (int n = 0; n < 16; ++n) wn[n] = rwg[b * 16 + n];
  float acc[16];
  #pragma unroll
  for (int k = 0; k < 16; ++k) acc[k] = 0.f;
  const int lj = t & 63, li = t >> 6;
  for (int n = 0; n < 16; ++n) {
    __syncthreads();
    #pragma unroll
    for (int it = 0; it < 16; ++it)
      tile[li + it*4][lj] = pool[((size_t)n * dim1 + i0 + li + it*4) * dim2 + j0 + lj];
    __syncthreads();
    const float wv = wn[n];
    #pragma unroll
    for (int it = 0; it < 16; ++it)
      acc[it] += wv * tile[lj][li + it*4];
  }
  #pragma unroll
  for (int it = 0; it < 16; ++it)
    out[((size_t)b * dim2 + j0 + li + it*4) * dim1 + i0 + lj] = (bf16)acc[it];
}

// ------------------------------------------------------------ f32 -> bf16
__global__ void cvt_bf16_kernel(const float* __restrict__ in, bf16* __restrict__ out, int n4)
{
  const int i = blockIdx.x * 256 + threadIdx.x;
  if (i < n4) {
    float4 v = ((const float4*)in)[i];
    bf16x4 o = {(bf16)v.x, (bf16)v.y, (bf16)v.z, (bf16)v.w};
    ((bf16x4*)out)[i] = o;
  }
}

// --------------------------------------------------------------- GEMM (Bt)
// CMODE: 0 = bf16 out, 1 = f32 out, 2 = f32 out + f32 resid,
//        3 = bf16 out in head-major layout [b][h=c/64][r][64].
template<int CMODE>
__global__ __launch_bounds__(256) void gemm_bt(
    const bf16* __restrict__ A, const bf16* __restrict__ Bt, void* __restrict__ Cp,
    const float* __restrict__ resid, int M, int N, int K,
    long sA, long sB, long sC, float scale)
{
  __shared__ alignas(16) bf16 As[128 * 32];
  __shared__ alignas(16) bf16 Bs[128 * 32];
  const int t = threadIdx.x, w = t >> 6, l = t & 63;
  const int llo = l & 15, lhi = l >> 4;
  const int wm = w >> 1, wn = w & 1;
  const int m0 = blockIdx.y * 128, n0 = blockIdx.x * 128;
  const bf16* Ab = A  + (size_t)blockIdx.z * sA;
  const bf16* Bb = Bt + (size_t)blockIdx.z * sB;
  f32x4 acc[4][4];
  #pragma unroll
  for (int i = 0; i < 4; ++i)
    #pragma unroll
    for (int j = 0; j < 4; ++j) acc[i][j] = (f32x4){0.f, 0.f, 0.f, 0.f};

  const int arow = t >> 2, akb = t & 3;
  const bf16* asrc = Ab + (size_t)(m0 + arow) * K + akb * 8;
  const bf16* bsrc = Bb + (size_t)(n0 + arow) * K + akb * 8;
  const size_t rstep = (size_t)64 * K;
  const int aoff0 = arow * 64 + ((akb * 16) ^ (((arow >> 1) & 3) << 4));
  const int aoff1 = aoff0 + 64 * 64;

  uint4 a0 = *(const uint4*)(asrc);
  uint4 a1 = *(const uint4*)(asrc + rstep);
  uint4 b0 = *(const uint4*)(bsrc);
  uint4 b1 = *(const uint4*)(bsrc + rstep);

  for (int kt = 0; kt < K; kt += 32) {
    __syncthreads();
    *(uint4*)((char*)As + aoff0) = a0;
    *(uint4*)((char*)As + aoff1) = a1;
    *(uint4*)((char*)Bs + aoff0) = b0;
    *(uint4*)((char*)Bs + aoff1) = b1;
    __syncthreads();
    if (kt + 32 < K) {
      a0 = *(const uint4*)(asrc + kt + 32);
      a1 = *(const uint4*)(asrc + rstep + kt + 32);
      b0 = *(const uint4*)(bsrc + kt + 32);
      b1 = *(const uint4*)(bsrc + rstep + kt + 32);
    }
    bf16x8 af[4], bfr[4];
    #pragma unroll
    for (int fi = 0; fi < 4; ++fi) {
      int r = wm * 64 + fi * 16 + llo;
      af[fi] = *(const bf16x8*)((const char*)As + (r * 64 + ((lhi * 16) ^ (((r >> 1) & 3) << 4))));
      int c = wn * 64 + fi * 16 + llo;
      bfr[fi] = *(const bf16x8*)((const char*)Bs + (c * 64 + ((lhi * 16) ^ (((c >> 1) & 3) << 4))));
    }
    #pragma unroll
    for (int fi = 0; fi < 4; ++fi)
      #pragma unroll
      for (int fj = 0; fj < 4; ++fj)
        acc[fi][fj] = __builtin_amdgcn_mfma_f32_16x16x32_bf16(af[fi], bfr[fj], acc[fi][fj], 0, 0, 0);
  }

  #pragma unroll
  for (int fi = 0; fi < 4; ++fi)
    #pragma unroll
    for (int fj = 0; fj < 4; ++fj)
      #pragma unroll
      for (int jj = 0; jj < 4; ++jj) {
        int r = m0 + wm * 64 + fi * 16 + lhi * 4 + jj;
        int c = n0 + wn * 64 + fj * 16 + llo;
        size_t idx = (size_t)blockIdx.z * sC + (size_t)r * N + c;
        float v = acc[fi][fj][jj] * scale;
        if (CMODE == 0) {
          ((bf16*)Cp)[idx] = (bf16)v;
        } else if (CMODE == 3) {
          size_t idx3 = (((size_t)blockIdx.z * 16 + (c >> 6)) * 2048 + r) * 64 + (c & 63);
          ((bf16*)Cp)[idx3] = (bf16)v;
        } else {
          if (CMODE == 2) v += resid[idx];
          ((float*)Cp)[idx] = v;
        }
      }
}

// ----------------------------------------------------------- flash attention
// attn6: 8-wave blocks (512 thr). Waves 0-3 = kv-half 0, waves 4-7 = kv-half 1
// of the supertile pair (jj, 15-jj): uniform 17 stages per half per block,
// grid 256 (1 block/CU, 2 waves/SIMD). Each half has its own 32KB K/V double
// buffer (64KB LDS). Flash-decode style in-block merge of (m,l,O) partials
// through LDS (f32, stride-65 padded) at the end of each supertile — no
// global partials. Swapped-QK^T register softmax, balanced max tree,
// exact defer-max, counted vmcnt(4), s_setprio around MFMA clusters.
static __device__ __forceinline__ unsigned pk2f(float a, float b) {
  union { bf16 h[2]; unsigned u; } x;
  x.h[0] = (bf16)a; x.h[1] = (bf16)b; return x.u;
}

__global__ __launch_bounds__(512, 2) void attn6_kernel(
    const bf16* __restrict__ Qg, const bf16* __restrict__ Khg,
    const bf16* __restrict__ Vtg, bf16* __restrict__ aog)
{
  __shared__ alignas(16) bf16 KS[2][2][4096];   // [half][dbuf][64x64]
  __shared__ alignas(16) bf16 VS[2][2][4096];
  const int lin = blockIdx.x;
  const int hb = lin & 31, jj = lin >> 5;       // same hb -> same lin%8 (XCD)
  const int h = hb >> 1, b = hb & 1;
  const int t = threadIdx.x, w = t >> 6, l = t & 63;
  const int half = w >> 2, wsub = w & 3;
  const int qi = l & 31, hi = l >> 5;
  const bf16* Qb = Qg  + ((size_t)b * 2048) * 1024 + h * 64;
  const bf16* Kh = Khg + ((size_t)(b * 16 + h)) * 2048 * 64;
  const bf16* Vh = Vtg + ((size_t)b * 1024 + h * 64) * 2048;
  bf16* Ob = aog + ((size_t)b * 2048) * 1024 + h * 64;

  float* PO = (float*)&KS[0][0][0];             // merge area: [wsub*32+qi][65]
  float* MM = (float*)((char*)&KS[0][0][0] + 40960);
  float* LL = MM + 128;

  auto ISSUE = [&](int bi, int kv0) {
    bf16* ksb = &KS[half][bi][0];
    bf16* vsb = &VS[half][bi][0];
    #pragma unroll
    for (int i = 0; i < 2; ++i) {
      int c = wsub * 128 + i * 64 + l;
      int row = c >> 3;
      int scol = (c & 7) ^ (row & 7);
      gload_lds16(Kh + (size_t)(kv0 + row) * 64 + scol * 8,
                  (bf16*)((char*)ksb + wsub * 2048 + i * 1024));
    }
    #pragma unroll
    for (int i = 0; i < 2; ++i) {
      int c = wsub * 128 + i * 64 + l;
      int row = c >> 3;
      int scol = (c & 7) ^ (row & 7);
      gload_lds16(Vh + (size_t)row * 2048 + kv0 + scol * 8,
                  (bf16*)((char*)vsb + wsub * 2048 + i * 1024));
    }
  };

  #pragma unroll 1
  for (int tsel = 0; tsel < 2; ++tsel) {
    const int T = tsel ? (15 - jj) : jj;
    const int q0 = T * 128 + wsub * 32;
    const int base_g = half * (T + 1);

    bf16x8 qf[4];
    #pragma unroll
    for (int dc = 0; dc < 4; ++dc)
      qf[dc] = *(const bf16x8*)(Qb + (size_t)(q0 + qi) * 1024 + dc * 16 + hi * 8);

    f32x16 o0, o1;
    #pragma unroll
    for (int r = 0; r < 16; ++r) { o0[r] = 0.f; o1[r] = 0.f; }
    float m_run = -INFINITY, l_run = 0.f;

    ISSUE(0, base_g * 64);

    auto STEP64 = [&](int bi, int s0) {
      const bool h2 = (s0 + 32 <= q0);
      bf16x8 kf[8];
      const bf16* ksb = &KS[half][bi][0];
      const bf16* vsb = &VS[half][bi][0];
      const int kr1 = qi, kr2 = 32 + qi;
      #pragma unroll
      for (int dc = 0; dc < 4; ++dc) {
        kf[dc]     = *(const bf16x8*)((const char*)ksb + kr1 * 128 +
                                      (((dc * 2 + hi) ^ (kr1 & 7)) << 4));
        kf[4 + dc] = *(const bf16x8*)((const char*)ksb + kr2 * 128 +
                                      (((dc * 2 + hi) ^ (kr2 & 7)) << 4));
      }
      f32x16 sv1, sv2;
      #pragma unroll
      for (int r = 0; r < 16; ++r) { sv1[r] = 0.f; sv2[r] = 0.f; }
      __builtin_amdgcn_s_setprio(1);
      #pragma unroll
      for (int dc = 0; dc < 4; ++dc)
        sv1 = __builtin_amdgcn_mfma_f32_32x32x16_bf16(kf[dc], qf[dc], sv1, 0, 0, 0);
      if (h2) {
        #pragma unroll
        for (int dc = 0; dc < 4; ++dc)
          sv2 = __builtin_amdgcn_mfma_f32_32x32x16_bf16(kf[4 + dc], qf[dc], sv2, 0, 0, 0);
      }
      __builtin_amdgcn_s_setprio(0);
      const int qe = qi - 4 * hi;
      if (s0 == q0) {
        #pragma unroll
        for (int r = 0; r < 16; ++r) {
          const int kvc = (r & 3) + 8 * (r >> 2);
          sv1[r] = (kvc > qe) ? -INFINITY : sv1[r];
        }
      }
      if (h2 && s0 + 32 == q0) {
        #pragma unroll
        for (int r = 0; r < 16; ++r) {
          const int kvc = (r & 3) + 8 * (r >> 2);
          sv2[r] = (kvc > qe) ? -INFINITY : sv2[r];
        }
      }
      // balanced max tree
      float mx[8];
      #pragma unroll
      for (int i = 0; i < 8; ++i) mx[i] = fmaxf(sv1[2 * i], sv1[2 * i + 1]);
      if (h2) {
        #pragma unroll
        for (int i = 0; i < 8; ++i) mx[i] = fmaxf(mx[i], fmaxf(sv2[2 * i], sv2[2 * i + 1]));
      }
      #pragma unroll
      for (int i = 0; i < 4; ++i) mx[i] = fmaxf(mx[i], mx[i + 4]);
      float tm = fmaxf(fmaxf(mx[0], mx[1]), fmaxf(mx[2], mx[3]));
      tm = fmaxf(tm, __shfl_xor(tm, 32));
      if (!__all(tm <= m_run)) {                // exact defer-max
        const float mn = fmaxf(m_run, tm);
        const float alpha = __expf(m_run - mn);
        m_run = mn;
        l_run *= alpha;
        o0 *= alpha; o1 *= alpha;
      }
      float rs = 0.f;
      unsigned pk[16], ot[16];
      #pragma unroll
      for (int i = 0; i < 8; ++i) {
        float pa = __expf(sv1[2 * i]     - m_run);
        float pb = __expf(sv1[2 * i + 1] - m_run);
        rs += pa + pb;
        pk[i] = pk2f(pa, pb);
      }
      if (h2) {
        #pragma unroll
        for (int i = 0; i < 8; ++i) {
          float pa = __expf(sv2[2 * i]     - m_run);
          float pb = __expf(sv2[2 * i + 1] - m_run);
          rs += pa + pb;
          pk[8 + i] = pk2f(pa, pb);
        }
      }
      rs += __shfl_xor(rs, 32);
      l_run += rs;
      #pragma unroll
      for (int i = 0; i < 8; ++i) ot[i] = __shfl_xor(pk[i], 32);
      if (h2) {
        #pragma unroll
        for (int i = 0; i < 8; ++i) ot[8 + i] = __shfl_xor(pk[8 + i], 32);
      }
      __builtin_amdgcn_s_setprio(1);
      #pragma unroll
      for (int c2 = 0; c2 < 4; ++c2) {
        if (c2 < 2 || h2) {
          union { unsigned u[4]; bf16x8 v; } pf;
          pf.u[0] = hi ? ot[4 * c2 + 2] : pk[4 * c2 + 0];
          pf.u[1] = hi ? ot[4 * c2 + 3] : pk[4 * c2 + 1];
          pf.u[2] = hi ? pk[4 * c2 + 2] : ot[4 * c2 + 0];
          pf.u[3] = hi ? pk[4 * c2 + 3] : ot[4 * c2 + 1];
          const int d0 = qi, d1 = 32 + qi;
          bf16x8 v0 = *(const bf16x8*)((const char*)vsb + d0 * 128 +
                                       (((c2 * 2 + hi) ^ (d0 & 7)) << 4));
          bf16x8 v1 = *(const bf16x8*)((const char*)vsb + d1 * 128 +
                                       (((c2 * 2 + hi) ^ (d1 & 7)) << 4));
          o0 = __builtin_amdgcn_mfma_f32_32x32x16_bf16(v0, pf.v, o0, 0, 0, 0);
          o1 = __builtin_amdgcn_mfma_f32_32x32x16_bf16(v1, pf.v, o1, 0, 0, 0);
        }
      }
      __builtin_amdgcn_s_setprio(0);
    };

    #pragma unroll 1
    for (int st = 0; st <= T; ++st) {
      const int bi = st & 1;
      if (st < T) {
        ISSUE(bi ^ 1, (base_g + st + 1) * 64);
        asm volatile("s_waitcnt vmcnt(4)" ::: "memory");
      } else {
        asm volatile("s_waitcnt vmcnt(0)" ::: "memory");
      }
      __builtin_amdgcn_s_barrier();
      const int s0 = (base_g + st) * 64;
      if (s0 <= q0) STEP64(bi, s0);
      __builtin_amdgcn_s_barrier();
    }

    // ---- in-block flash-decode merge of the two kv-halves ----
    if (half == 1) {
      #pragma unroll
      for (int r = 0; r < 16; ++r) {
        const int d0 = (r & 3) + 8 * (r >> 2) + 4 * hi;
        PO[(wsub * 32 + qi) * 65 + d0]      = o0[r];
        PO[(wsub * 32 + qi) * 65 + 32 + d0] = o1[r];
      }
      if (hi == 0) { MM[wsub * 32 + qi] = m_run; LL[wsub * 32 + qi] = l_run; }
    }
    __syncthreads();
    if (half == 0) {
      const float m1 = MM[wsub * 32 + qi], l1 = LL[wsub * 32 + qi];
      const float m = fmaxf(m_run, m1);
      const float a0 = __expf(m_run - m), a1 = __expf(m1 - m);
      const float inv = 1.0f / (a0 * l_run + a1 * l1);
      #pragma unroll
      for (int rg = 0; rg < 4; ++rg) {
        union { bf16 h4[4]; unsigned long long u; } pr0, pr1;
        #pragma unroll
        for (int e = 0; e < 4; ++e) {
          const int r = rg * 4 + e;
          const int d0 = (r & 3) + 8 * (r >> 2) + 4 * hi;
          pr0.h4[e] = (bf16)((a0 * o0[r] + a1 * PO[(wsub * 32 + qi) * 65 + d0])      * inv);
          pr1.h4[e] = (bf16)((a0 * o1[r] + a1 * PO[(wsub * 32 + qi) * 65 + 32 + d0]) * inv);
        }
        *(unsigned long long*)(Ob + (size_t)(q0 + qi) * 1024 +  0 + rg * 8 + hi * 4) = pr0.u;
        *(unsigned long long*)(Ob + (size_t)(q0 + qi) * 1024 + 32 + rg * 8 + hi * 4) = pr1.u;
      }
    }
    __syncthreads();
  }
}

// ------------------------------------------------------------------ top-k
__global__ __launch_bounds__(256) void topk_kernel(
    const float* __restrict__ ms, const float* __restrict__ kV, float* __restrict__ outp)
{
  const int token = blockIdx.x;
  const int t = threadIdx.x, w = t >> 6, l = t & 63;
  __shared__ alignas(16) float row[4096];
  __shared__ float wv[8]; __shared__ int wi[8];
  __shared__ float cand[4]; __shared__ int candi[4];
  const float* mrow = ms + (size_t)token * 4096;
  #pragma unroll
  for (int p = 0; p < 4; ++p) {
    float4 v = ((const float4*)mrow)[t + p * 256];
    *(float4*)&row[(t + p * 256) * 4] = v;
  }
  __syncthreads();
  for (int k = 0; k < 8; ++k) {
    float bv = -INFINITY; int bi = 0;
    for (int i = t; i < 4096; i += 256) {
      float v = row[i];
      if (v > bv) { bv = v; bi = i; }
    }
    #pragma unroll
    for (int off = 32; off > 0; off >>= 1) {
      float ov = __shfl_xor(bv, off); int oi = __shfl_xor(bi, off);
      if (ov > bv || (ov == bv && oi < bi)) { bv = ov; bi = oi; }
    }
    if (l == 0) { cand[w] = bv; candi[w] = bi; }
    __syncthreads();
    if (t == 0) {
      float best = cand[0]; int besti = candi[0];
      for (int q = 1; q < 4; ++q)
        if (cand[q] > best || (cand[q] == best && candi[q] < besti)) { best = cand[q]; besti = candi[q]; }
      wv[k] = best; wi[k] = besti; row[besti] = -INFINITY;
    }
    __syncthreads();
  }
  if (t == 0) {
    float m = wv[0];
    #pragma unroll
    for (int k = 1; k < 8; ++k) m = fmaxf(m, wv[k]);
    float sden = 0.f; float ex[8];
    #pragma unroll
    for (int k = 0; k < 8; ++k) { ex[k] = __expf(wv[k] - m); sden += ex[k]; }
    #pragma unroll
    for (int k = 0; k < 8; ++k) wv[k] = ex[k] / sden;
  }
  __syncthreads();
  float a0 = 0, a1 = 0, a2 = 0, a3 = 0;
  #pragma unroll
  for (int k = 0; k < 8; ++k) {
    float wk = wv[k];
    float4 vr = *(const float4*)(kV + (size_t)wi[k] * 1024 + t * 4);
    a0 += wk * vr.x; a1 += wk * vr.y; a2 += wk * vr.z; a3 += wk * vr.w;
  }
  float4* op = (float4*)(outp + (size_t)token * 1024) + t;
  float4 cur = *op;
  cur.x += a0; cur.y += a1; cur.z += a2; cur.w += a3;
  *op = cur;
}

// ---------------------------------------------------------------- launcher
extern "C" void kernel_launch(void* const* d_in, const int* in_sizes, int n_in,
                              void* d_out, int out_size, void* d_ws, size_t ws_size,
                              hipStream_t stream)
{
  (void)in_sizes; (void)n_in; (void)out_size; (void)ws_size;
  const float* x    = (const float*)d_in[0];
  const float* imp  = (const float*)d_in[1];
  const float* Wc   = (const float*)d_in[2];
  const float* WQ   = (const float*)d_in[3];
  const float* WK   = (const float*)d_in[4];
  const float* WV   = (const float*)d_in[5];
  const float* Wm   = (const float*)d_in[6];
  const float* comp = (const float*)d_in[7];
  const float* expd = (const float*)d_in[8];
  const float* kK   = (const float*)d_in[9];
  const float* kV   = (const float*)d_in[10];
  const float* WO   = (const float*)d_in[11];
  const float* g1   = (const float*)d_in[12];
  const float* b1   = (const float*)d_in[13];
  const float* g2   = (const float*)d_in[14];
  const float* b2   = (const float*)d_in[15];
  float* out = (float*)d_out;
  char* ws = (char*)d_ws;
  const size_t MB = 1u << 20;
  float* racc = (float*)(ws);
  float* rw   = (float*)(ws + 24576);
  float* Wcat = (float*)(ws + 32768);
  char* ar = ws + 512 * 1024;
  bf16* nx   = (bf16*)(ar);              // 8 MB
  bf16* sct  = (bf16*)(ar +  8 * MB);    // 1 MB  [b][R][D]
  bf16* eqt  = (bf16*)(ar +  9 * MB);    // 1 MB  [b][D][R]
  bf16* ekt  = (bf16*)(ar + 10 * MB);
  bf16* evt  = (bf16*)(ar + 11 * MB);
  bf16* hb   = (bf16*)(ar + 12 * MB);    // 2 MB  [b][S][R]
  bf16* Qb   = (bf16*)(ar + 14 * MB);    // 8 MB each
  bf16* Kb   = (bf16*)(ar + 22 * MB);    // head-major [b][h][s][64]
  bf16* Vtb  = (bf16*)(ar + 30 * MB);    // 8 MB  [b][D][S]  (V transposed)
  bf16* aob  = (bf16*)(ar + 38 * MB);    // 8 MB
  bf16* WOb  = (bf16*)(ar + 46 * MB);    // 2 MB
  bf16* nx2  = (bf16*)(ar);
  bf16* mct  = (bf16*)(ar +  8 * MB);
  bf16* Qmb  = (bf16*)(ar +  9 * MB);    // 2 MB
  bf16* kKb  = (bf16*)(ar + 11 * MB);    // 2 MB
  float* msb = (float*)(ar + 13 * MB);   // 64 MB

  hipMemsetAsync(racc, 0, 20480, stream);
  hipMemcpyAsync(Wcat + 0 * 16384, Wc, 65536, hipMemcpyDeviceToDevice, stream);
  hipMemcpyAsync(Wcat + 1 * 16384, WQ, 65536, hipMemcpyDeviceToDevice, stream);
  hipMemcpyAsync(Wcat + 2 * 16384, WK, 65536, hipMemcpyDeviceToDevice, stream);
  hipMemcpyAsync(Wcat + 3 * 16384, WV, 65536, hipMemcpyDeviceToDevice, stream);
  hipMemcpyAsync(Wcat + 4 * 16384, Wm, 65536, hipMemcpyDeviceToDevice, stream);

  ln_route_kernel<<<4096, 256, 0, stream>>>(x, g1, b1, Wcat, imp, nx, racc, 4, 0);
  route_norm_kernel<<<1, 256, 0, stream>>>(racc, rw, 0, 4);
  mix_t_kernel<<<dim3(16, 4, 2), 256, 0, stream>>>(comp, rw +  0, sct, 1024, 256);
  mix_t_kernel<<<dim3(4, 16, 2), 256, 0, stream>>>(expd, rw + 32, eqt, 256, 1024);
  mix_t_kernel<<<dim3(4, 16, 2), 256, 0, stream>>>(expd, rw + 64, ekt, 256, 1024);
  mix_t_kernel<<<dim3(4, 16, 2), 256, 0, stream>>>(expd, rw + 96, evt, 256, 1024);
  gemm_bt<0><<<dim3(2, 16, 2), 256, 0, stream>>>(nx, sct, hb, nullptr, 2048, 256, 1024,
        (long)2048 * 1024, (long)256 * 1024, (long)2048 * 256, 1.0f);
  gemm_bt<0><<<dim3(8, 16, 2), 256, 0, stream>>>(hb, eqt, Qb, nullptr, 2048, 1024, 256,
        (long)2048 * 256, (long)1024 * 256, (long)2048 * 1024, 1.0f);
  // K head-major + pre-scaled by 1/sqrt(dh)=0.125
  gemm_bt<3><<<dim3(8, 16, 2), 256, 0, stream>>>(hb, ekt, Kb, nullptr, 2048, 1024, 256,
        (long)2048 * 256, (long)1024 * 256, 0L, 0.125f);
  // V produced TRANSPOSED: Vt[b][d][s]
  gemm_bt<0><<<dim3(16, 8, 2), 256, 0, stream>>>(evt, hb, Vtb, nullptr, 1024, 2048, 256,
        (long)1024 * 256, (long)2048 * 256, (long)1024 * 2048, 1.0f);
  attn6_kernel<<<256, 512, 0, stream>>>(Qb, Kb, Vtb, aob);
  cvt_bf16_kernel<<<1024, 256, 0, stream>>>(WO, WOb, 262144);
  gemm_bt<2><<<dim3(8, 32, 1), 256, 0, stream>>>(aob, WOb, out, x, 4096, 1024, 1024,
        0L, 0L, 0L, 1.0f);
  ln_route_kernel<<<4096, 256, 0, stream>>>(out, g2, b2, Wcat + 4 * 16384, imp, nx2, racc, 1, 4);
  route_norm_kernel<<<1, 256, 0, stream>>>(racc, rw, 4, 1);
  mix_t_kernel<<<dim3(16, 4, 2), 256, 0, stream>>>(comp, rw + 128, mct, 1024, 256);
  gemm_bt<0><<<dim3(2, 16, 2), 256, 0, stream>>>(nx2, mct, Qmb, nullptr, 2048, 256, 1024,
        (long)2048 * 1024, (long)256 * 1024, (long)2048 * 256, 1.0f);
  cvt_bf16_kernel<<<1024, 256, 0, stream>>>(kK, kKb, 262144);
  gemm_bt<1><<<dim3(32, 16, 2), 256, 0, stream>>>(Qmb, kKb, msb, nullptr, 2048, 4096, 256,
        (long)2048 * 256, 0L, (long)2048 * 4096, 0.0625f);
  topk_kernel<<<4096, 256, 0, stream>>>(msb, kV, out);
}

// Round 6
// 321.567 us; speedup vs baseline: 1.7135x; 1.0327x over previous
//
#include <hip/hip_runtime.h>
#include <hip/hip_bf16.h>
#include <math.h>

typedef __bf16 bf16;
typedef __attribute__((ext_vector_type(8))) __bf16 bf16x8;
typedef __attribute__((ext_vector_type(4))) __bf16 bf16x4;
typedef __attribute__((ext_vector_type(4))) float f32x4;
typedef __attribute__((ext_vector_type(16))) float f32x16;

static __device__ __forceinline__ void gload_lds16(const bf16* g, bf16* l) {
  __builtin_amdgcn_global_load_lds((const __attribute__((address_space(1))) void*)g,
                                   (__attribute__((address_space(3))) void*)l, 16, 0, 0);
}

// ---------------------------------------------------------------- LN + route
__global__ __launch_bounds__(256) void ln_route_kernel(
    const float* __restrict__ x, const float* __restrict__ gam, const float* __restrict__ bet,
    const float* __restrict__ Wg, const float* __restrict__ imp,
    bf16* __restrict__ nxo, float* __restrict__ racc, int ngroups, int gbase)
{
  const int token = blockIdx.x;
  const int b = token >> 11;                 // S = 2048
  const int t = threadIdx.x, w = t >> 6, l = t & 63;
  __shared__ alignas(16) float row[1024];
  __shared__ float red1[4], red2[4];
  float4 xv = ((const float4*)(x + (size_t)token * 1024))[t];
  float s  = xv.x + xv.y + xv.z + xv.w;
  float sq = xv.x*xv.x + xv.y*xv.y + xv.z*xv.z + xv.w*xv.w;
  #pragma unroll
  for (int off = 32; off > 0; off >>= 1) { s += __shfl_xor(s, off); sq += __shfl_xor(sq, off); }
  if (l == 0) { red1[w] = s; red2[w] = sq; }
  __syncthreads();
  s  = red1[0] + red1[1] + red1[2] + red1[3];
  sq = red2[0] + red2[1] + red2[2] + red2[3];
  const float mu  = s * (1.f / 1024.f);
  const float var = sq * (1.f / 1024.f) - mu * mu;
  const float rs  = rsqrtf(var + 1e-5f);
  float4 gv = ((const float4*)gam)[t];
  float4 bv = ((const float4*)bet)[t];
  float n0 = (xv.x - mu) * rs * gv.x + bv.x;
  float n1 = (xv.y - mu) * rs * gv.y + bv.y;
  float n2 = (xv.z - mu) * rs * gv.z + bv.z;
  float n3 = (xv.w - mu) * rs * gv.w + bv.w;
  row[t*4+0] = n0; row[t*4+1] = n1; row[t*4+2] = n2; row[t*4+3] = n3;
  bf16x4 pk = {(bf16)n0, (bf16)n1, (bf16)n2, (bf16)n3};
  *(bf16x4*)(nxo + (size_t)token * 1024 + t * 4) = pk;
  __syncthreads();
  if (w < ngroups) {
    const float* Wbase = Wg + (size_t)w * 16 * 1024;
    float m_run = -INFINITY, s_run = 0.f, myv = 0.f;
    for (int e = 0; e < 16; ++e) {
      const float* wr = Wbase + e * 1024;
      float dv = 0.f;
      #pragma unroll
      for (int i = 0; i < 16; ++i) dv += row[l + i*64] * wr[l + i*64];
      #pragma unroll
      for (int off = 32; off > 0; off >>= 1) dv += __shfl_xor(dv, off);
      if (l == e) myv = dv;
      float mn = fmaxf(m_run, dv);
      s_run = s_run * __expf(m_run - mn) + __expf(dv - mn);
      m_run = mn;
    }
    if (l < 16) {
      float pref = __expf(myv - m_run) / s_run;
      atomicAdd(racc + ((((size_t)(token & 31)) * 5 + gbase + w) * 2 + b) * 16 + l,
                imp[token] * pref);
    }
  }
}

// ------------------------------------------------------------- route norm
__global__ void route_norm_kernel(const float* __restrict__ racc, float* __restrict__ rw,
                                  int g0, int ng)
{
  __shared__ float pooled[5][2][16];
  const int t = threadIdx.x;
  const int n = ng * 32;
  int g = 0, b = 0, e = 0;
  if (t < n) {
    g = g0 + (t >> 5); b = (t >> 4) & 1; e = t & 15;
    float s = 0.f;
    for (int sl = 0; sl < 32; ++sl) s += racc[(((size_t)sl * 5 + g) * 2 + b) * 16 + e];
    pooled[g][b][e] = s;
  }
  __syncthreads();
  if (t < n) {
    float den = 1e-8f;
    #pragma unroll
    for (int e2 = 0; e2 < 16; ++e2) den += pooled[g][b][e2];
    rw[((size_t)g * 2 + b) * 16 + e] = pooled[g][b][e] / den;
  }
}

// ----------------------------------------------------- pool mix (transposed)
__global__ __launch_bounds__(256) void mix_t_kernel(
    const float* __restrict__ pool, const float* __restrict__ rwg,
    bf16* __restrict__ out, int dim1, int dim2)
{
  const int i0 = blockIdx.x * 64, j0 = blockIdx.y * 64, b = blockIdx.z;
  const int t = threadIdx.x;
  __shared__ float tile[64][65];
  float wn[16];
  #pragma unroll
  for (int n = 0; n < 16; ++n) wn[n] = rwg[b * 16 + n];
  float acc[16];
  #pragma unroll
  for (int k = 0; k < 16; ++k) acc[k] = 0.f;
  const int lj = t & 63, li = t >> 6;
  for (int n = 0; n < 16; ++n) {
    __syncthreads();
    #pragma unroll
    for (int it = 0; it < 16; ++it)
      tile[li + it*4][lj] = pool[((size_t)n * dim1 + i0 + li + it*4) * dim2 + j0 + lj];
    __syncthreads();
    const float wv = wn[n];
    #pragma unroll
    for (int it = 0; it < 16; ++it)
      acc[it] += wv * tile[lj][li + it*4];
  }
  #pragma unroll
  for (int it = 0; it < 16; ++it)
    out[((size_t)b * dim2 + j0 + li + it*4) * dim1 + i0 + lj] = (bf16)acc[it];
}

// ------------------------------------------------------------ f32 -> bf16
__global__ void cvt_bf16_kernel(const float* __restrict__ in, bf16* __restrict__ out, int n4)
{
  const int i = blockIdx.x * 256 + threadIdx.x;
  if (i < n4) {
    float4 v = ((const float4*)in)[i];
    bf16x4 o = {(bf16)v.x, (bf16)v.y, (bf16)v.z, (bf16)v.w};
    ((bf16x4*)out)[i] = o;
  }
}

// --------------------------------------------------------------- GEMM (Bt)
// CMODE: 0 = bf16 out, 1 = f32 out, 2 = f32 out + f32 resid,
//        3 = bf16 out in head-major layout [b][h=c/64][r][64].
template<int CMODE>
__global__ __launch_bounds__(256) void gemm_bt(
    const bf16* __restrict__ A, const bf16* __restrict__ Bt, void* __restrict__ Cp,
    const float* __restrict__ resid, int M, int N, int K,
    long sA, long sB, long sC, float scale)
{
  __shared__ alignas(16) bf16 As[128 * 32];
  __shared__ alignas(16) bf16 Bs[128 * 32];
  const int t = threadIdx.x, w = t >> 6, l = t & 63;
  const int llo = l & 15, lhi = l >> 4;
  const int wm = w >> 1, wn = w & 1;
  const int m0 = blockIdx.y * 128, n0 = blockIdx.x * 128;
  const bf16* Ab = A  + (size_t)blockIdx.z * sA;
  const bf16* Bb = Bt + (size_t)blockIdx.z * sB;
  f32x4 acc[4][4];
  #pragma unroll
  for (int i = 0; i < 4; ++i)
    #pragma unroll
    for (int j = 0; j < 4; ++j) acc[i][j] = (f32x4){0.f, 0.f, 0.f, 0.f};

  const int arow = t >> 2, akb = t & 3;
  const bf16* asrc = Ab + (size_t)(m0 + arow) * K + akb * 8;
  const bf16* bsrc = Bb + (size_t)(n0 + arow) * K + akb * 8;
  const size_t rstep = (size_t)64 * K;
  const int aoff0 = arow * 64 + ((akb * 16) ^ (((arow >> 1) & 3) << 4));
  const int aoff1 = aoff0 + 64 * 64;

  uint4 a0 = *(const uint4*)(asrc);
  uint4 a1 = *(const uint4*)(asrc + rstep);
  uint4 b0 = *(const uint4*)(bsrc);
  uint4 b1 = *(const uint4*)(bsrc + rstep);

  for (int kt = 0; kt < K; kt += 32) {
    __syncthreads();
    *(uint4*)((char*)As + aoff0) = a0;
    *(uint4*)((char*)As + aoff1) = a1;
    *(uint4*)((char*)Bs + aoff0) = b0;
    *(uint4*)((char*)Bs + aoff1) = b1;
    __syncthreads();
    if (kt + 32 < K) {
      a0 = *(const uint4*)(asrc + kt + 32);
      a1 = *(const uint4*)(asrc + rstep + kt + 32);
      b0 = *(const uint4*)(bsrc + kt + 32);
      b1 = *(const uint4*)(bsrc + rstep + kt + 32);
    }
    bf16x8 af[4], bfr[4];
    #pragma unroll
    for (int fi = 0; fi < 4; ++fi) {
      int r = wm * 64 + fi * 16 + llo;
      af[fi] = *(const bf16x8*)((const char*)As + (r * 64 + ((lhi * 16) ^ (((r >> 1) & 3) << 4))));
      int c = wn * 64 + fi * 16 + llo;
      bfr[fi] = *(const bf16x8*)((const char*)Bs + (c * 64 + ((lhi * 16) ^ (((c >> 1) & 3) << 4))));
    }
    #pragma unroll
    for (int fi = 0; fi < 4; ++fi)
      #pragma unroll
      for (int fj = 0; fj < 4; ++fj)
        acc[fi][fj] = __builtin_amdgcn_mfma_f32_16x16x32_bf16(af[fi], bfr[fj], acc[fi][fj], 0, 0, 0);
  }

  #pragma unroll
  for (int fi = 0; fi < 4; ++fi)
    #pragma unroll
    for (int fj = 0; fj < 4; ++fj)
      #pragma unroll
      for (int jj = 0; jj < 4; ++jj) {
        int r = m0 + wm * 64 + fi * 16 + lhi * 4 + jj;
        int c = n0 + wn * 64 + fj * 16 + llo;
        size_t idx = (size_t)blockIdx.z * sC + (size_t)r * N + c;
        float v = acc[fi][fj][jj] * scale;
        if (CMODE == 0) {
          ((bf16*)Cp)[idx] = (bf16)v;
        } else if (CMODE == 3) {
          size_t idx3 = (((size_t)blockIdx.z * 16 + (c >> 6)) * 2048 + r) * 64 + (c & 63);
          ((bf16*)Cp)[idx3] = (bf16)v;
        } else {
          if (CMODE == 2) v += resid[idx];
          ((float*)Cp)[idx] = v;
        }
      }
}

// ----------------------------------------------------------- flash attention
static __device__ __forceinline__ unsigned pk2f(float a, float b) {
  union { bf16 h[2]; unsigned u; } x;
  x.h[0] = (bf16)a; x.h[1] = (bf16)b; return x.u;
}

__global__ __launch_bounds__(512, 2) void attn6_kernel(
    const bf16* __restrict__ Qg, const bf16* __restrict__ Khg,
    const bf16* __restrict__ Vtg, bf16* __restrict__ aog)
{
  __shared__ alignas(16) bf16 KS[2][2][4096];   // [half][dbuf][64x64]
  __shared__ alignas(16) bf16 VS[2][2][4096];
  const int lin = blockIdx.x;
  const int hb = lin & 31, jj = lin >> 5;       // same hb -> same lin%8 (XCD)
  const int h = hb >> 1, b = hb & 1;
  const int t = threadIdx.x, w = t >> 6, l = t & 63;
  const int half = w >> 2, wsub = w & 3;
  const int qi = l & 31, hi = l >> 5;
  const bf16* Qb = Qg  + ((size_t)b * 2048) * 1024 + h * 64;
  const bf16* Kh = Khg + ((size_t)(b * 16 + h)) * 2048 * 64;
  const bf16* Vh = Vtg + ((size_t)b * 1024 + h * 64) * 2048;
  bf16* Ob = aog + ((size_t)b * 2048) * 1024 + h * 64;

  float* PO = (float*)&KS[0][0][0];             // merge area: [wsub*32+qi][65]
  float* MM = (float*)((char*)&KS[0][0][0] + 40960);
  float* LL = MM + 128;

  auto ISSUE = [&](int bi, int kv0) {
    bf16* ksb = &KS[half][bi][0];
    bf16* vsb = &VS[half][bi][0];
    #pragma unroll
    for (int i = 0; i < 2; ++i) {
      int c = wsub * 128 + i * 64 + l;
      int row = c >> 3;
      int scol = (c & 7) ^ (row & 7);
      gload_lds16(Kh + (size_t)(kv0 + row) * 64 + scol * 8,
                  (bf16*)((char*)ksb + wsub * 2048 + i * 1024));
    }
    #pragma unroll
    for (int i = 0; i < 2; ++i) {
      int c = wsub * 128 + i * 64 + l;
      int row = c >> 3;
      int scol = (c & 7) ^ (row & 7);
      gload_lds16(Vh + (size_t)row * 2048 + kv0 + scol * 8,
                  (bf16*)((char*)vsb + wsub * 2048 + i * 1024));
    }
  };

  #pragma unroll 1
  for (int tsel = 0; tsel < 2; ++tsel) {
    const int T = tsel ? (15 - jj) : jj;
    const int q0 = T * 128 + wsub * 32;
    const int base_g = half * (T + 1);

    bf16x8 qf[4];
    #pragma unroll
    for (int dc = 0; dc < 4; ++dc)
      qf[dc] = *(const bf16x8*)(Qb + (size_t)(q0 + qi) * 1024 + dc * 16 + hi * 8);

    f32x16 o0, o1;
    #pragma unroll
    for (int r = 0; r < 16; ++r) { o0[r] = 0.f; o1[r] = 0.f; }
    float m_run = -INFINITY, l_run = 0.f;

    ISSUE(0, base_g * 64);

    auto STEP64 = [&](int bi, int s0) {
      const bool h2 = (s0 + 32 <= q0);
      bf16x8 kf[8];
      const bf16* ksb = &KS[half][bi][0];
      const bf16* vsb = &VS[half][bi][0];
      const int kr1 = qi, kr2 = 32 + qi;
      #pragma unroll
      for (int dc = 0; dc < 4; ++dc) {
        kf[dc]     = *(const bf16x8*)((const char*)ksb + kr1 * 128 +
                                      (((dc * 2 + hi) ^ (kr1 & 7)) << 4));
        kf[4 + dc] = *(const bf16x8*)((const char*)ksb + kr2 * 128 +
                                      (((dc * 2 + hi) ^ (kr2 & 7)) << 4));
      }
      f32x16 sv1, sv2;
      #pragma unroll
      for (int r = 0; r < 16; ++r) { sv1[r] = 0.f; sv2[r] = 0.f; }
      __builtin_amdgcn_s_setprio(1);
      #pragma unroll
      for (int dc = 0; dc < 4; ++dc)
        sv1 = __builtin_amdgcn_mfma_f32_32x32x16_bf16(kf[dc], qf[dc], sv1, 0, 0, 0);
      if (h2) {
        #pragma unroll
        for (int dc = 0; dc < 4; ++dc)
          sv2 = __builtin_amdgcn_mfma_f32_32x32x16_bf16(kf[4 + dc], qf[dc], sv2, 0, 0, 0);
      }
      __builtin_amdgcn_s_setprio(0);
      const int qe = qi - 4 * hi;
      if (s0 == q0) {
        #pragma unroll
        for (int r = 0; r < 16; ++r) {
          const int kvc = (r & 3) + 8 * (r >> 2);
          sv1[r] = (kvc > qe) ? -INFINITY : sv1[r];
        }
      }
      if (h2 && s0 + 32 == q0) {
        #pragma unroll
        for (int r = 0; r < 16; ++r) {
          const int kvc = (r & 3) + 8 * (r >> 2);
          sv2[r] = (kvc > qe) ? -INFINITY : sv2[r];
        }
      }
      float mx[8];
      #pragma unroll
      for (int i = 0; i < 8; ++i) mx[i] = fmaxf(sv1[2 * i], sv1[2 * i + 1]);
      if (h2) {
        #pragma unroll
        for (int i = 0; i < 8; ++i) mx[i] = fmaxf(mx[i], fmaxf(sv2[2 * i], sv2[2 * i + 1]));
      }
      #pragma unroll
      for (int i = 0; i < 4; ++i) mx[i] = fmaxf(mx[i], mx[i + 4]);
      float tm = fmaxf(fmaxf(mx[0], mx[1]), fmaxf(mx[2], mx[3]));
      tm = fmaxf(tm, __shfl_xor(tm, 32));
      if (!__all(tm <= m_run)) {                // exact defer-max
        const float mn = fmaxf(m_run, tm);
        const float alpha = __expf(m_run - mn);
        m_run = mn;
        l_run *= alpha;
        o0 *= alpha; o1 *= alpha;
      }
      float rs = 0.f;
      unsigned pk[16], ot[16];
      #pragma unroll
      for (int i = 0; i < 8; ++i) {
        float pa = __expf(sv1[2 * i]     - m_run);
        float pb = __expf(sv1[2 * i + 1] - m_run);
        rs += pa + pb;
        pk[i] = pk2f(pa, pb);
      }
      if (h2) {
        #pragma unroll
        for (int i = 0; i < 8; ++i) {
          float pa = __expf(sv2[2 * i]     - m_run);
          float pb = __expf(sv2[2 * i + 1] - m_run);
          rs += pa + pb;
          pk[8 + i] = pk2f(pa, pb);
        }
      }
      rs += __shfl_xor(rs, 32);
      l_run += rs;
      #pragma unroll
      for (int i = 0; i < 8; ++i) ot[i] = __shfl_xor(pk[i], 32);
      if (h2) {
        #pragma unroll
        for (int i = 0; i < 8; ++i) ot[8 + i] = __shfl_xor(pk[8 + i], 32);
      }
      __builtin_amdgcn_s_setprio(1);
      #pragma unroll
      for (int c2 = 0; c2 < 4; ++c2) {
        if (c2 < 2 || h2) {
          union { unsigned u[4]; bf16x8 v; } pf;
          pf.u[0] = hi ? ot[4 * c2 + 2] : pk[4 * c2 + 0];
          pf.u[1] = hi ? ot[4 * c2 + 3] : pk[4 * c2 + 1];
          pf.u[2] = hi ? pk[4 * c2 + 2] : ot[4 * c2 + 0];
          pf.u[3] = hi ? pk[4 * c2 + 3] : ot[4 * c2 + 1];
          const int d0 = qi, d1 = 32 + qi;
          bf16x8 v0 = *(const bf16x8*)((const char*)vsb + d0 * 128 +
                                       (((c2 * 2 + hi) ^ (d0 & 7)) << 4));
          bf16x8 v1 = *(const bf16x8*)((const char*)vsb + d1 * 128 +
                                       (((c2 * 2 + hi) ^ (d1 & 7)) << 4));
          o0 = __builtin_amdgcn_mfma_f32_32x32x16_bf16(v0, pf.v, o0, 0, 0, 0);
          o1 = __builtin_amdgcn_mfma_f32_32x32x16_bf16(v1, pf.v, o1, 0, 0, 0);
        }
      }
      __builtin_amdgcn_s_setprio(0);
    };

    #pragma unroll 1
    for (int st = 0; st <= T; ++st) {
      const int bi = st & 1;
      if (st < T) {
        ISSUE(bi ^ 1, (base_g + st + 1) * 64);
        asm volatile("s_waitcnt vmcnt(4)" ::: "memory");
      } else {
        asm volatile("s_waitcnt vmcnt(0)" ::: "memory");
      }
      __builtin_amdgcn_s_barrier();
      const int s0 = (base_g + st) * 64;
      if (s0 <= q0) STEP64(bi, s0);
      __builtin_amdgcn_s_barrier();
    }

    // ---- in-block flash-decode merge of the two kv-halves ----
    if (half == 1) {
      #pragma unroll
      for (int r = 0; r < 16; ++r) {
        const int d0 = (r & 3) + 8 * (r >> 2) + 4 * hi;
        PO[(wsub * 32 + qi) * 65 + d0]      = o0[r];
        PO[(wsub * 32 + qi) * 65 + 32 + d0] = o1[r];
      }
      if (hi == 0) { MM[wsub * 32 + qi] = m_run; LL[wsub * 32 + qi] = l_run; }
    }
    __syncthreads();
    if (half == 0) {
      const float m1 = MM[wsub * 32 + qi], l1 = LL[wsub * 32 + qi];
      const float m = fmaxf(m_run, m1);
      const float a0 = __expf(m_run - m), a1 = __expf(m1 - m);
      const float inv = 1.0f / (a0 * l_run + a1 * l1);
      #pragma unroll
      for (int rg = 0; rg < 4; ++rg) {
        union { bf16 h4[4]; unsigned long long u; } pr0, pr1;
        #pragma unroll
        for (int e = 0; e < 4; ++e) {
          const int r = rg * 4 + e;
          const int d0 = (r & 3) + 8 * (r >> 2) + 4 * hi;
          pr0.h4[e] = (bf16)((a0 * o0[r] + a1 * PO[(wsub * 32 + qi) * 65 + d0])      * inv);
          pr1.h4[e] = (bf16)((a0 * o1[r] + a1 * PO[(wsub * 32 + qi) * 65 + 32 + d0]) * inv);
        }
        *(unsigned long long*)(Ob + (size_t)(q0 + qi) * 1024 +  0 + rg * 8 + hi * 4) = pr0.u;
        *(unsigned long long*)(Ob + (size_t)(q0 + qi) * 1024 + 32 + rg * 8 + hi * 4) = pr1.u;
      }
    }
    __syncthreads();
  }
}

// ------------------------------------------------------------------ top-k v2
// Single-pass threshold filter. t8 = 8th-largest of the 256 per-thread group
// maxima (a subset of the row, so t8 <= true v8 -> filter v >= t8 keeps every
// top-8 element). Survivors (~10-30 expected; 4096-capacity buffer for
// unconditional safety) packed as u64 keys (monotonic-float, ~idx) so
// max(key) == (max value, min index) == lax.top_k tie semantics.
static __device__ __forceinline__ void ce_desc(float& a, float& b) {
  float hi = fmaxf(a, b), lo = fminf(a, b); a = hi; b = lo;
}
static __device__ __forceinline__ void merge8(float r[8], const float o[8]) {
  float c[8];
  #pragma unroll
  for (int i = 0; i < 8; ++i) c[i] = fmaxf(r[i], o[7 - i]);
  ce_desc(c[0], c[4]); ce_desc(c[1], c[5]); ce_desc(c[2], c[6]); ce_desc(c[3], c[7]);
  ce_desc(c[0], c[2]); ce_desc(c[1], c[3]); ce_desc(c[4], c[6]); ce_desc(c[5], c[7]);
  ce_desc(c[0], c[1]); ce_desc(c[2], c[3]); ce_desc(c[4], c[5]); ce_desc(c[6], c[7]);
  #pragma unroll
  for (int i = 0; i < 8; ++i) r[i] = c[i];
}
static __device__ __forceinline__ unsigned long long fkey(float v, int idx) {
  unsigned u = __float_as_uint(v);
  u = (u & 0x80000000u) ? ~u : (u | 0x80000000u);
  return ((unsigned long long)u << 32) | (unsigned)(0xFFFFFFFFu - (unsigned)idx);
}

__global__ __launch_bounds__(256) void topk2_kernel(
    const float* __restrict__ ms, const float* __restrict__ kV, float* __restrict__ outp)
{
  const int token = blockIdx.x;
  const int t = threadIdx.x, w = t >> 6, l = t & 63;
  __shared__ unsigned long long cand[4096];
  __shared__ float wmax[32];
  __shared__ float wv[8];
  __shared__ int   wi[8];
  __shared__ int   cnt;
  if (t == 0) cnt = 0;

  const float* mrow = ms + (size_t)token * 4096;
  float4 vp[4];
  #pragma unroll
  for (int p = 0; p < 4; ++p) vp[p] = ((const float4*)mrow)[t + p * 256];

  // per-thread max of 16
  float m = fmaxf(fmaxf(vp[0].x, vp[0].y), fmaxf(vp[0].z, vp[0].w));
  #pragma unroll
  for (int p = 1; p < 4; ++p)
    m = fmaxf(m, fmaxf(fmaxf(vp[p].x, vp[p].y), fmaxf(vp[p].z, vp[p].w)));

  // wave-level sorted top-8 of 64 lane-maxima (butterfly bitonic merge)
  float r[8];
  r[0] = m;
  #pragma unroll
  for (int i = 1; i < 8; ++i) r[i] = -INFINITY;
  #pragma unroll
  for (int st = 0; st < 6; ++st) {
    const int off = 1 << st;
    float o[8];
    #pragma unroll
    for (int i = 0; i < 8; ++i) o[i] = __shfl_xor(r[i], off);
    merge8(r, o);
  }
  if (l == 0) {
    #pragma unroll
    for (int i = 0; i < 8; ++i) wmax[w * 8 + i] = r[i];
  }
  __syncthreads();

  // cross-wave merge -> t8
  float a[8], bb[8];
  #pragma unroll
  for (int i = 0; i < 8; ++i) { a[i] = wmax[i]; bb[i] = wmax[8 + i]; }
  merge8(a, bb);
  #pragma unroll
  for (int i = 0; i < 8; ++i) bb[i] = wmax[16 + i];
  {
    float c2[8];
    #pragma unroll
    for (int i = 0; i < 8; ++i) c2[i] = wmax[24 + i];
    merge8(bb, c2);
  }
  merge8(a, bb);
  const float t8 = a[7];

  // filter & emit candidates
  #pragma unroll
  for (int p = 0; p < 4; ++p) {
    const int base = 4 * (t + p * 256);
    if (vp[p].x >= t8) { int pos = atomicAdd(&cnt, 1); cand[pos] = fkey(vp[p].x, base + 0); }
    if (vp[p].y >= t8) { int pos = atomicAdd(&cnt, 1); cand[pos] = fkey(vp[p].y, base + 1); }
    if (vp[p].z >= t8) { int pos = atomicAdd(&cnt, 1); cand[pos] = fkey(vp[p].z, base + 2); }
    if (vp[p].w >= t8) { int pos = atomicAdd(&cnt, 1); cand[pos] = fkey(vp[p].w, base + 3); }
  }
  __syncthreads();

  // wave 0: exact top-8 by descending unique keys
  if (w == 0) {
    const int n = cnt;
    unsigned long long prev = ~0ULL;
    float vk[8]; int ik[8];
    #pragma unroll
    for (int k = 0; k < 8; ++k) {
      unsigned long long best = 0;
      for (int i = l; i < n; i += 64) {
        unsigned long long c = cand[i];
        if (c < prev && c > best) best = c;
      }
      #pragma unroll
      for (int st = 0; st < 6; ++st) {
        const int off = 1 << st;
        unsigned bh = (unsigned)(best >> 32), bl = (unsigned)best;
        unsigned oh = __shfl_xor(bh, off), ol = __shfl_xor(bl, off);
        unsigned long long ob = ((unsigned long long)oh << 32) | ol;
        if (ob > best) best = ob;
      }
      prev = best;
      unsigned u = (unsigned)(best >> 32);
      u = (u & 0x80000000u) ? (u ^ 0x80000000u) : ~u;
      vk[k] = __uint_as_float(u);
      ik[k] = (int)(0xFFFFFFFFu - (unsigned)(best & 0xFFFFFFFFu));
    }
    if (l == 0) {
      const float mx = vk[0];
      float den = 0.f, ex[8];
      #pragma unroll
      for (int k = 0; k < 8; ++k) { ex[k] = __expf(vk[k] - mx); den += ex[k]; }
      const float inv = 1.0f / den;
      #pragma unroll
      for (int k = 0; k < 8; ++k) { wv[k] = ex[k] * inv; wi[k] = ik[k]; }
    }
  }
  __syncthreads();

  // gather + accumulate
  float a0 = 0, a1 = 0, a2 = 0, a3 = 0;
  #pragma unroll
  for (int k = 0; k < 8; ++k) {
    const float wk = wv[k];
    float4 vr = *(const float4*)(kV + (size_t)wi[k] * 1024 + t * 4);
    a0 += wk * vr.x; a1 += wk * vr.y; a2 += wk * vr.z; a3 += wk * vr.w;
  }
  float4* op = (float4*)(outp + (size_t)token * 1024) + t;
  float4 cur = *op;
  cur.x += a0; cur.y += a1; cur.z += a2; cur.w += a3;
  *op = cur;
}

// ---------------------------------------------------------------- launcher
extern "C" void kernel_launch(void* const* d_in, const int* in_sizes, int n_in,
                              void* d_out, int out_size, void* d_ws, size_t ws_size,
                              hipStream_t stream)
{
  (void)in_sizes; (void)n_in; (void)out_size; (void)ws_size;
  const float* x    = (const float*)d_in[0];
  const float* imp  = (const float*)d_in[1];
  const float* Wc   = (const float*)d_in[2];
  const float* WQ   = (const float*)d_in[3];
  const float* WK   = (const float*)d_in[4];
  const float* WV   = (const float*)d_in[5];
  const float* Wm   = (const float*)d_in[6];
  const float* comp = (const float*)d_in[7];
  const float* expd = (const float*)d_in[8];
  const float* kK   = (const float*)d_in[9];
  const float* kV   = (const float*)d_in[10];
  const float* WO   = (const float*)d_in[11];
  const float* g1   = (const float*)d_in[12];
  const float* b1   = (const float*)d_in[13];
  const float* g2   = (const float*)d_in[14];
  const float* b2   = (const float*)d_in[15];
  float* out = (float*)d_out;
  char* ws = (char*)d_ws;
  const size_t MB = 1u << 20;
  float* racc = (float*)(ws);
  float* rw   = (float*)(ws + 24576);
  float* Wcat = (float*)(ws + 32768);
  char* ar = ws + 512 * 1024;
  bf16* nx   = (bf16*)(ar);              // 8 MB
  bf16* sct  = (bf16*)(ar +  8 * MB);    // 1 MB  [b][R][D]
  bf16* eqt  = (bf16*)(ar +  9 * MB);    // 1 MB  [b][D][R]
  bf16* ekt  = (bf16*)(ar + 10 * MB);
  bf16* evt  = (bf16*)(ar + 11 * MB);
  bf16* hb   = (bf16*)(ar + 12 * MB);    // 2 MB  [b][S][R]
  bf16* Qb   = (bf16*)(ar + 14 * MB);    // 8 MB each
  bf16* Kb   = (bf16*)(ar + 22 * MB);    // head-major [b][h][s][64]
  bf16* Vtb  = (bf16*)(ar + 30 * MB);    // 8 MB  [b][D][S]  (V transposed)
  bf16* aob  = (bf16*)(ar + 38 * MB);    // 8 MB
  bf16* WOb  = (bf16*)(ar + 46 * MB);    // 2 MB
  bf16* nx2  = (bf16*)(ar);
  bf16* mct  = (bf16*)(ar +  8 * MB);
  bf16* Qmb  = (bf16*)(ar +  9 * MB);    // 2 MB
  bf16* kKb  = (bf16*)(ar + 11 * MB);    // 2 MB
  float* msb = (float*)(ar + 13 * MB);   // 64 MB

  hipMemsetAsync(racc, 0, 20480, stream);
  hipMemcpyAsync(Wcat + 0 * 16384, Wc, 65536, hipMemcpyDeviceToDevice, stream);
  hipMemcpyAsync(Wcat + 1 * 16384, WQ, 65536, hipMemcpyDeviceToDevice, stream);
  hipMemcpyAsync(Wcat + 2 * 16384, WK, 65536, hipMemcpyDeviceToDevice, stream);
  hipMemcpyAsync(Wcat + 3 * 16384, WV, 65536, hipMemcpyDeviceToDevice, stream);
  hipMemcpyAsync(Wcat + 4 * 16384, Wm, 65536, hipMemcpyDeviceToDevice, stream);

  ln_route_kernel<<<4096, 256, 0, stream>>>(x, g1, b1, Wcat, imp, nx, racc, 4, 0);
  route_norm_kernel<<<1, 256, 0, stream>>>(racc, rw, 0, 4);
  mix_t_kernel<<<dim3(16, 4, 2), 256, 0, stream>>>(comp, rw +  0, sct, 1024, 256);
  mix_t_kernel<<<dim3(4, 16, 2), 256, 0, stream>>>(expd, rw + 32, eqt, 256, 1024);
  mix_t_kernel<<<dim3(4, 16, 2), 256, 0, stream>>>(expd, rw + 64, ekt, 256, 1024);
  mix_t_kernel<<<dim3(4, 16, 2), 256, 0, stream>>>(expd, rw + 96, evt, 256, 1024);
  gemm_bt<0><<<dim3(2, 16, 2), 256, 0, stream>>>(nx, sct, hb, nullptr, 2048, 256, 1024,
        (long)2048 * 1024, (long)256 * 1024, (long)2048 * 256, 1.0f);
  gemm_bt<0><<<dim3(8, 16, 2), 256, 0, stream>>>(hb, eqt, Qb, nullptr, 2048, 1024, 256,
        (long)2048 * 256, (long)1024 * 256, (long)2048 * 1024, 1.0f);
  // K head-major + pre-scaled by 1/sqrt(dh)=0.125
  gemm_bt<3><<<dim3(8, 16, 2), 256, 0, stream>>>(hb, ekt, Kb, nullptr, 2048, 1024, 256,
        (long)2048 * 256, (long)1024 * 256, 0L, 0.125f);
  // V produced TRANSPOSED: Vt[b][d][s]
  gemm_bt<0><<<dim3(16, 8, 2), 256, 0, stream>>>(evt, hb, Vtb, nullptr, 1024, 2048, 256,
        (long)1024 * 256, (long)2048 * 256, (long)1024 * 2048, 1.0f);
  attn6_kernel<<<256, 512, 0, stream>>>(Qb, Kb, Vtb, aob);
  cvt_bf16_kernel<<<1024, 256, 0, stream>>>(WO, WOb, 262144);
  gemm_bt<2><<<dim3(8, 32, 1), 256, 0, stream>>>(aob, WOb, out, x, 4096, 1024, 1024,
        0L, 0L, 0L, 1.0f);
  ln_route_kernel<<<4096, 256, 0, stream>>>(out, g2, b2, Wcat + 4 * 16384, imp, nx2, racc, 1, 4);
  route_norm_kernel<<<1, 256, 0, stream>>>(racc, rw, 4, 1);
  mix_t_kernel<<<dim3(16, 4, 2), 256, 0, stream>>>(comp, rw + 128, mct, 1024, 256);
  gemm_bt<0><<<dim3(2, 16, 2), 256, 0, stream>>>(nx2, mct, Qmb, nullptr, 2048, 256, 1024,
        (long)2048 * 1024, (long)256 * 1024, (long)2048 * 256, 1.0f);
  cvt_bf16_kernel<<<1024, 256, 0, stream>>>(kK, kKb, 262144);
  gemm_bt<1><<<dim3(32, 16, 2), 256, 0, stream>>>(Qmb, kKb, msb, nullptr, 2048, 4096, 256,
        (long)2048 * 256, 0L, (long)2048 * 4096, 0.0625f);
  topk2_kernel<<<4096, 256, 0, stream>>>(msb, kV, out);
}

// Round 7
// 315.597 us; speedup vs baseline: 1.7459x; 1.0189x over previous
//
#include <hip/hip_runtime.h>
#include <hip/hip_bf16.h>
#include <math.h>

typedef __bf16 bf16;
typedef __attribute__((ext_vector_type(8))) __bf16 bf16x8;
typedef __attribute__((ext_vector_type(4))) __bf16 bf16x4;
typedef __attribute__((ext_vector_type(4))) float f32x4;
typedef __attribute__((ext_vector_type(16))) float f32x16;

static __device__ __forceinline__ void gload_lds16(const bf16* g, bf16* l) {
  __builtin_amdgcn_global_load_lds((const __attribute__((address_space(1))) void*)g,
                                   (__attribute__((address_space(3))) void*)l, 16, 0, 0);
}

// ---------------------------------------------------------------- LayerNorm
__global__ __launch_bounds__(256) void ln_kernel(
    const float* __restrict__ x, const float* __restrict__ gam, const float* __restrict__ bet,
    bf16* __restrict__ nxo)
{
  const int token = blockIdx.x;
  const int t = threadIdx.x, w = t >> 6, l = t & 63;
  __shared__ float red1[4], red2[4];
  float4 xv = ((const float4*)(x + (size_t)token * 1024))[t];
  float s  = xv.x + xv.y + xv.z + xv.w;
  float sq = xv.x*xv.x + xv.y*xv.y + xv.z*xv.z + xv.w*xv.w;
  #pragma unroll
  for (int off = 32; off > 0; off >>= 1) { s += __shfl_xor(s, off); sq += __shfl_xor(sq, off); }
  if (l == 0) { red1[w] = s; red2[w] = sq; }
  __syncthreads();
  s  = red1[0] + red1[1] + red1[2] + red1[3];
  sq = red2[0] + red2[1] + red2[2] + red2[3];
  const float mu  = s * (1.f / 1024.f);
  const float var = sq * (1.f / 1024.f) - mu * mu;
  const float rs  = rsqrtf(var + 1e-5f);
  float4 gv = ((const float4*)gam)[t];
  float4 bv = ((const float4*)bet)[t];
  bf16x4 pk = {(bf16)((xv.x - mu) * rs * gv.x + bv.x),
               (bf16)((xv.y - mu) * rs * gv.y + bv.y),
               (bf16)((xv.z - mu) * rs * gv.z + bv.z),
               (bf16)((xv.w - mu) * rs * gv.w + bv.w)};
  *(bf16x4*)(nxo + (size_t)token * 1024 + t * 4) = pk;
}

// --------------------------------------------------- route pool (from logits)
// wave w handles token blk*4+w; lane = g*16+e; 16-lane segment softmax.
__global__ __launch_bounds__(256) void route_pool_kernel(
    const float* __restrict__ logits, const float* __restrict__ imp,
    float* __restrict__ racc, int ng, int gbase)
{
  const int w = threadIdx.x >> 6, l = threadIdx.x & 63;
  const int token = blockIdx.x * 4 + w;
  const int b = token >> 11;
  const int g = l >> 4, e = l & 15;
  if (g < ng) {
    float v = logits[(size_t)token * 128 + g * 16 + e];
    float mx = v;
    #pragma unroll
    for (int off = 1; off < 16; off <<= 1) mx = fmaxf(mx, __shfl_xor(mx, off));
    float ex = __expf(v - mx);
    float sm = ex;
    #pragma unroll
    for (int off = 1; off < 16; off <<= 1) sm += __shfl_xor(sm, off);
    atomicAdd(racc + ((((size_t)(token & 31)) * 5 + gbase + g) * 2 + b) * 16 + e,
              imp[token] * (ex / sm));
  }
}

// ------------------------------------------------------------- route norm
__global__ void route_norm_kernel(const float* __restrict__ racc, float* __restrict__ rw,
                                  int g0, int ng)
{
  __shared__ float pooled[5][2][16];
  const int t = threadIdx.x;
  const int n = ng * 32;
  int g = 0, b = 0, e = 0;
  if (t < n) {
    g = g0 + (t >> 5); b = (t >> 4) & 1; e = t & 15;
    float s = 0.f;
    for (int sl = 0; sl < 32; ++sl) s += racc[(((size_t)sl * 5 + g) * 2 + b) * 16 + e];
    pooled[g][b][e] = s;
  }
  __syncthreads();
  if (t < n) {
    float den = 1e-8f;
    #pragma unroll
    for (int e2 = 0; e2 < 16; ++e2) den += pooled[g][b][e2];
    rw[((size_t)g * 2 + b) * 16 + e] = pooled[g][b][e] / den;
  }
}

// ----------------------------------------------------- pool mix (transposed)
__global__ __launch_bounds__(256) void mix_t_kernel(
    const float* __restrict__ pool, const float* __restrict__ rwg,
    bf16* __restrict__ out, int dim1, int dim2)
{
  const int i0 = blockIdx.x * 64, j0 = blockIdx.y * 64, b = blockIdx.z;
  const int t = threadIdx.x;
  __shared__ float tile[64][65];
  float wn[16];
  #pragma unroll
  for (int n = 0; n < 16; ++n) wn[n] = rwg[b * 16 + n];
  float acc[16];
  #pragma unroll
  for (int k = 0; k < 16; ++k) acc[k] = 0.f;
  const int lj = t & 63, li = t >> 6;
  for (int n = 0; n < 16; ++n) {
    __syncthreads();
    #pragma unroll
    for (int it = 0; it < 16; ++it)
      tile[li + it*4][lj] = pool[((size_t)n * dim1 + i0 + li + it*4) * dim2 + j0 + lj];
    __syncthreads();
    const float wv = wn[n];
    #pragma unroll
    for (int it = 0; it < 16; ++it)
      acc[it] += wv * tile[lj][li + it*4];
  }
  #pragma unroll
  for (int it = 0; it < 16; ++it)
    out[((size_t)b * dim2 + j0 + li + it*4) * dim1 + i0 + lj] = (bf16)acc[it];
}

// ------------------------------------------------------------ f32 -> bf16
__global__ void cvt_bf16_kernel(const float* __restrict__ in, bf16* __restrict__ out, int n4)
{
  const int i = blockIdx.x * 256 + threadIdx.x;
  if (i < n4) {
    float4 v = ((const float4*)in)[i];
    bf16x4 o = {(bf16)v.x, (bf16)v.y, (bf16)v.z, (bf16)v.w};
    ((bf16x4*)out)[i] = o;
  }
}

// --------------------------------------------------------------- GEMM (Bt)
// CMODE: 0 = bf16 out, 1 = f32 out, 2 = f32 out + f32 resid,
//        3 = bf16 out in head-major layout [b][h=c/64][r][64].
template<int CMODE>
__global__ __launch_bounds__(256) void gemm_bt(
    const bf16* __restrict__ A, const bf16* __restrict__ Bt, void* __restrict__ Cp,
    const float* __restrict__ resid, int M, int N, int K,
    long sA, long sB, long sC, float scale)
{
  __shared__ alignas(16) bf16 As[128 * 32];
  __shared__ alignas(16) bf16 Bs[128 * 32];
  const int t = threadIdx.x, w = t >> 6, l = t & 63;
  const int llo = l & 15, lhi = l >> 4;
  const int wm = w >> 1, wn = w & 1;
  const int m0 = blockIdx.y * 128, n0 = blockIdx.x * 128;
  const bf16* Ab = A  + (size_t)blockIdx.z * sA;
  const bf16* Bb = Bt + (size_t)blockIdx.z * sB;
  f32x4 acc[4][4];
  #pragma unroll
  for (int i = 0; i < 4; ++i)
    #pragma unroll
    for (int j = 0; j < 4; ++j) acc[i][j] = (f32x4){0.f, 0.f, 0.f, 0.f};

  const int arow = t >> 2, akb = t & 3;
  const bf16* asrc = Ab + (size_t)(m0 + arow) * K + akb * 8;
  const bf16* bsrc = Bb + (size_t)(n0 + arow) * K + akb * 8;
  const size_t rstep = (size_t)64 * K;
  const int aoff0 = arow * 64 + ((akb * 16) ^ (((arow >> 1) & 3) << 4));
  const int aoff1 = aoff0 + 64 * 64;

  uint4 a0 = *(const uint4*)(asrc);
  uint4 a1 = *(const uint4*)(asrc + rstep);
  uint4 b0 = *(const uint4*)(bsrc);
  uint4 b1 = *(const uint4*)(bsrc + rstep);

  for (int kt = 0; kt < K; kt += 32) {
    __syncthreads();
    *(uint4*)((char*)As + aoff0) = a0;
    *(uint4*)((char*)As + aoff1) = a1;
    *(uint4*)((char*)Bs + aoff0) = b0;
    *(uint4*)((char*)Bs + aoff1) = b1;
    __syncthreads();
    if (kt + 32 < K) {
      a0 = *(const uint4*)(asrc + kt + 32);
      a1 = *(const uint4*)(asrc + rstep + kt + 32);
      b0 = *(const uint4*)(bsrc + kt + 32);
      b1 = *(const uint4*)(bsrc + rstep + kt + 32);
    }
    bf16x8 af[4], bfr[4];
    #pragma unroll
    for (int fi = 0; fi < 4; ++fi) {
      int r = wm * 64 + fi * 16 + llo;
      af[fi] = *(const bf16x8*)((const char*)As + (r * 64 + ((lhi * 16) ^ (((r >> 1) & 3) << 4))));
      int c = wn * 64 + fi * 16 + llo;
      bfr[fi] = *(const bf16x8*)((const char*)Bs + (c * 64 + ((lhi * 16) ^ (((c >> 1) & 3) << 4))));
    }
    #pragma unroll
    for (int fi = 0; fi < 4; ++fi)
      #pragma unroll
      for (int fj = 0; fj < 4; ++fj)
        acc[fi][fj] = __builtin_amdgcn_mfma_f32_16x16x32_bf16(af[fi], bfr[fj], acc[fi][fj], 0, 0, 0);
  }

  #pragma unroll
  for (int fi = 0; fi < 4; ++fi)
    #pragma unroll
    for (int fj = 0; fj < 4; ++fj)
      #pragma unroll
      for (int jj = 0; jj < 4; ++jj) {
        int r = m0 + wm * 64 + fi * 16 + lhi * 4 + jj;
        int c = n0 + wn * 64 + fj * 16 + llo;
        size_t idx = (size_t)blockIdx.z * sC + (size_t)r * N + c;
        float v = acc[fi][fj][jj] * scale;
        if (CMODE == 0) {
          ((bf16*)Cp)[idx] = (bf16)v;
        } else if (CMODE == 3) {
          size_t idx3 = (((size_t)blockIdx.z * 16 + (c >> 6)) * 2048 + r) * 64 + (c & 63);
          ((bf16*)Cp)[idx3] = (bf16)v;
        } else {
          if (CMODE == 2) v += resid[idx];
          ((float*)Cp)[idx] = v;
        }
      }
}

// ----------------------------------------------------------- flash attention
static __device__ __forceinline__ unsigned pk2f(float a, float b) {
  union { bf16 h[2]; unsigned u; } x;
  x.h[0] = (bf16)a; x.h[1] = (bf16)b; return x.u;
}

__global__ __launch_bounds__(512, 2) void attn6_kernel(
    const bf16* __restrict__ Qg, const bf16* __restrict__ Khg,
    const bf16* __restrict__ Vtg, bf16* __restrict__ aog)
{
  __shared__ alignas(16) bf16 KS[2][2][4096];   // [half][dbuf][64x64]
  __shared__ alignas(16) bf16 VS[2][2][4096];
  const int lin = blockIdx.x;
  const int hb = lin & 31, jj = lin >> 5;       // same hb -> same lin%8 (XCD)
  const int h = hb >> 1, b = hb & 1;
  const int t = threadIdx.x, w = t >> 6, l = t & 63;
  const int half = w >> 2, wsub = w & 3;
  const int qi = l & 31, hi = l >> 5;
  const bf16* Qb = Qg  + ((size_t)b * 2048) * 1024 + h * 64;
  const bf16* Kh = Khg + ((size_t)(b * 16 + h)) * 2048 * 64;
  const bf16* Vh = Vtg + ((size_t)b * 1024 + h * 64) * 2048;
  bf16* Ob = aog + ((size_t)b * 2048) * 1024 + h * 64;

  float* PO = (float*)&KS[0][0][0];             // merge area: [wsub*32+qi][65]
  float* MM = (float*)((char*)&KS[0][0][0] + 40960);
  float* LL = MM + 128;

  auto ISSUE = [&](int bi, int kv0) {
    bf16* ksb = &KS[half][bi][0];
    bf16* vsb = &VS[half][bi][0];
    #pragma unroll
    for (int i = 0; i < 2; ++i) {
      int c = wsub * 128 + i * 64 + l;
      int row = c >> 3;
      int scol = (c & 7) ^ (row & 7);
      gload_lds16(Kh + (size_t)(kv0 + row) * 64 + scol * 8,
                  (bf16*)((char*)ksb + wsub * 2048 + i * 1024));
    }
    #pragma unroll
    for (int i = 0; i < 2; ++i) {
      int c = wsub * 128 + i * 64 + l;
      int row = c >> 3;
      int scol = (c & 7) ^ (row & 7);
      gload_lds16(Vh + (size_t)row * 2048 + kv0 + scol * 8,
                  (bf16*)((char*)vsb + wsub * 2048 + i * 1024));
    }
  };

  #pragma unroll 1
  for (int tsel = 0; tsel < 2; ++tsel) {
    const int T = tsel ? (15 - jj) : jj;
    const int q0 = T * 128 + wsub * 32;
    const int base_g = half * (T + 1);

    bf16x8 qf[4];
    #pragma unroll
    for (int dc = 0; dc < 4; ++dc)
      qf[dc] = *(const bf16x8*)(Qb + (size_t)(q0 + qi) * 1024 + dc * 16 + hi * 8);

    f32x16 o0, o1;
    #pragma unroll
    for (int r = 0; r < 16; ++r) { o0[r] = 0.f; o1[r] = 0.f; }
    float m_run = -INFINITY, l_run = 0.f;

    ISSUE(0, base_g * 64);

    auto STEP64 = [&](int bi, int s0) {
      const bool h2 = (s0 + 32 <= q0);
      bf16x8 kf[8];
      const bf16* ksb = &KS[half][bi][0];
      const bf16* vsb = &VS[half][bi][0];
      const int kr1 = qi, kr2 = 32 + qi;
      #pragma unroll
      for (int dc = 0; dc < 4; ++dc) {
        kf[dc]     = *(const bf16x8*)((const char*)ksb + kr1 * 128 +
                                      (((dc * 2 + hi) ^ (kr1 & 7)) << 4));
        kf[4 + dc] = *(const bf16x8*)((const char*)ksb + kr2 * 128 +
                                      (((dc * 2 + hi) ^ (kr2 & 7)) << 4));
      }
      f32x16 sv1, sv2;
      #pragma unroll
      for (int r = 0; r < 16; ++r) { sv1[r] = 0.f; sv2[r] = 0.f; }
      __builtin_amdgcn_s_setprio(1);
      #pragma unroll
      for (int dc = 0; dc < 4; ++dc)
        sv1 = __builtin_amdgcn_mfma_f32_32x32x16_bf16(kf[dc], qf[dc], sv1, 0, 0, 0);
      if (h2) {
        #pragma unroll
        for (int dc = 0; dc < 4; ++dc)
          sv2 = __builtin_amdgcn_mfma_f32_32x32x16_bf16(kf[4 + dc], qf[dc], sv2, 0, 0, 0);
      }
      __builtin_amdgcn_s_setprio(0);
      const int qe = qi - 4 * hi;
      if (s0 == q0) {
        #pragma unroll
        for (int r = 0; r < 16; ++r) {
          const int kvc = (r & 3) + 8 * (r >> 2);
          sv1[r] = (kvc > qe) ? -INFINITY : sv1[r];
        }
      }
      if (h2 && s0 + 32 == q0) {
        #pragma unroll
        for (int r = 0; r < 16; ++r) {
          const int kvc = (r & 3) + 8 * (r >> 2);
          sv2[r] = (kvc > qe) ? -INFINITY : sv2[r];
        }
      }
      float mx[8];
      #pragma unroll
      for (int i = 0; i < 8; ++i) mx[i] = fmaxf(sv1[2 * i], sv1[2 * i + 1]);
      if (h2) {
        #pragma unroll
        for (int i = 0; i < 8; ++i) mx[i] = fmaxf(mx[i], fmaxf(sv2[2 * i], sv2[2 * i + 1]));
      }
      #pragma unroll
      for (int i = 0; i < 4; ++i) mx[i] = fmaxf(mx[i], mx[i + 4]);
      float tm = fmaxf(fmaxf(mx[0], mx[1]), fmaxf(mx[2], mx[3]));
      tm = fmaxf(tm, __shfl_xor(tm, 32));
      if (!__all(tm <= m_run)) {                // exact defer-max
        const float mn = fmaxf(m_run, tm);
        const float alpha = __expf(m_run - mn);
        m_run = mn;
        l_run *= alpha;
        o0 *= alpha; o1 *= alpha;
      }
      float rs = 0.f;
      unsigned pk[16], ot[16];
      #pragma unroll
      for (int i = 0; i < 8; ++i) {
        float pa = __expf(sv1[2 * i]     - m_run);
        float pb = __expf(sv1[2 * i + 1] - m_run);
        rs += pa + pb;
        pk[i] = pk2f(pa, pb);
      }
      if (h2) {
        #pragma unroll
        for (int i = 0; i < 8; ++i) {
          float pa = __expf(sv2[2 * i]     - m_run);
          float pb = __expf(sv2[2 * i + 1] - m_run);
          rs += pa + pb;
          pk[8 + i] = pk2f(pa, pb);
        }
      }
      rs += __shfl_xor(rs, 32);
      l_run += rs;
      #pragma unroll
      for (int i = 0; i < 8; ++i) ot[i] = __shfl_xor(pk[i], 32);
      if (h2) {
        #pragma unroll
        for (int i = 0; i < 8; ++i) ot[8 + i] = __shfl_xor(pk[8 + i], 32);
      }
      __builtin_amdgcn_s_setprio(1);
      #pragma unroll
      for (int c2 = 0; c2 < 4; ++c2) {
        if (c2 < 2 || h2) {
          union { unsigned u[4]; bf16x8 v; } pf;
          pf.u[0] = hi ? ot[4 * c2 + 2] : pk[4 * c2 + 0];
          pf.u[1] = hi ? ot[4 * c2 + 3] : pk[4 * c2 + 1];
          pf.u[2] = hi ? pk[4 * c2 + 2] : ot[4 * c2 + 0];
          pf.u[3] = hi ? pk[4 * c2 + 3] : ot[4 * c2 + 1];
          const int d0 = qi, d1 = 32 + qi;
          bf16x8 v0 = *(const bf16x8*)((const char*)vsb + d0 * 128 +
                                       (((c2 * 2 + hi) ^ (d0 & 7)) << 4));
          bf16x8 v1 = *(const bf16x8*)((const char*)vsb + d1 * 128 +
                                       (((c2 * 2 + hi) ^ (d1 & 7)) << 4));
          o0 = __builtin_amdgcn_mfma_f32_32x32x16_bf16(v0, pf.v, o0, 0, 0, 0);
          o1 = __builtin_amdgcn_mfma_f32_32x32x16_bf16(v1, pf.v, o1, 0, 0, 0);
        }
      }
      __builtin_amdgcn_s_setprio(0);
    };

    #pragma unroll 1
    for (int st = 0; st <= T; ++st) {
      const int bi = st & 1;
      if (st < T) {
        ISSUE(bi ^ 1, (base_g + st + 1) * 64);
        asm volatile("s_waitcnt vmcnt(4)" ::: "memory");
      } else {
        asm volatile("s_waitcnt vmcnt(0)" ::: "memory");
      }
      __builtin_amdgcn_s_barrier();
      const int s0 = (base_g + st) * 64;
      if (s0 <= q0) STEP64(bi, s0);
      __builtin_amdgcn_s_barrier();
    }

    // ---- in-block flash-decode merge of the two kv-halves ----
    if (half == 1) {
      #pragma unroll
      for (int r = 0; r < 16; ++r) {
        const int d0 = (r & 3) + 8 * (r >> 2) + 4 * hi;
        PO[(wsub * 32 + qi) * 65 + d0]      = o0[r];
        PO[(wsub * 32 + qi) * 65 + 32 + d0] = o1[r];
      }
      if (hi == 0) { MM[wsub * 32 + qi] = m_run; LL[wsub * 32 + qi] = l_run; }
    }
    __syncthreads();
    if (half == 0) {
      const float m1 = MM[wsub * 32 + qi], l1 = LL[wsub * 32 + qi];
      const float m = fmaxf(m_run, m1);
      const float a0 = __expf(m_run - m), a1 = __expf(m1 - m);
      const float inv = 1.0f / (a0 * l_run + a1 * l1);
      #pragma unroll
      for (int rg = 0; rg < 4; ++rg) {
        union { bf16 h4[4]; unsigned long long u; } pr0, pr1;
        #pragma unroll
        for (int e = 0; e < 4; ++e) {
          const int r = rg * 4 + e;
          const int d0 = (r & 3) + 8 * (r >> 2) + 4 * hi;
          pr0.h4[e] = (bf16)((a0 * o0[r] + a1 * PO[(wsub * 32 + qi) * 65 + d0])      * inv);
          pr1.h4[e] = (bf16)((a0 * o1[r] + a1 * PO[(wsub * 32 + qi) * 65 + 32 + d0]) * inv);
        }
        *(unsigned long long*)(Ob + (size_t)(q0 + qi) * 1024 +  0 + rg * 8 + hi * 4) = pr0.u;
        *(unsigned long long*)(Ob + (size_t)(q0 + qi) * 1024 + 32 + rg * 8 + hi * 4) = pr1.u;
      }
    }
    __syncthreads();
  }
}

// ------------------------------------------------------------------ top-k v2
static __device__ __forceinline__ void ce_desc(float& a, float& b) {
  float hi = fmaxf(a, b), lo = fminf(a, b); a = hi; b = lo;
}
static __device__ __forceinline__ void merge8(float r[8], const float o[8]) {
  float c[8];
  #pragma unroll
  for (int i = 0; i < 8; ++i) c[i] = fmaxf(r[i], o[7 - i]);
  ce_desc(c[0], c[4]); ce_desc(c[1], c[5]); ce_desc(c[2], c[6]); ce_desc(c[3], c[7]);
  ce_desc(c[0], c[2]); ce_desc(c[1], c[3]); ce_desc(c[4], c[6]); ce_desc(c[5], c[7]);
  ce_desc(c[0], c[1]); ce_desc(c[2], c[3]); ce_desc(c[4], c[5]); ce_desc(c[6], c[7]);
  #pragma unroll
  for (int i = 0; i < 8; ++i) r[i] = c[i];
}
static __device__ __forceinline__ unsigned long long fkey(float v, int idx) {
  unsigned u = __float_as_uint(v);
  u = (u & 0x80000000u) ? ~u : (u | 0x80000000u);
  return ((unsigned long long)u << 32) | (unsigned)(0xFFFFFFFFu - (unsigned)idx);
}

__global__ __launch_bounds__(256) void topk2_kernel(
    const float* __restrict__ ms, const float* __restrict__ kV, float* __restrict__ outp)
{
  const int token = blockIdx.x;
  const int t = threadIdx.x, w = t >> 6, l = t & 63;
  __shared__ unsigned long long cand[4096];
  __shared__ float wmax[32];
  __shared__ float wv[8];
  __shared__ int   wi[8];
  __shared__ int   cnt;
  if (t == 0) cnt = 0;

  const float* mrow = ms + (size_t)token * 4096;
  float4 vp[4];
  #pragma unroll
  for (int p = 0; p < 4; ++p) vp[p] = ((const float4*)mrow)[t + p * 256];

  float m = fmaxf(fmaxf(vp[0].x, vp[0].y), fmaxf(vp[0].z, vp[0].w));
  #pragma unroll
  for (int p = 1; p < 4; ++p)
    m = fmaxf(m, fmaxf(fmaxf(vp[p].x, vp[p].y), fmaxf(vp[p].z, vp[p].w)));

  float r[8];
  r[0] = m;
  #pragma unroll
  for (int i = 1; i < 8; ++i) r[i] = -INFINITY;
  #pragma unroll
  for (int st = 0; st < 6; ++st) {
    const int off = 1 << st;
    float o[8];
    #pragma unroll
    for (int i = 0; i < 8; ++i) o[i] = __shfl_xor(r[i], off);
    merge8(r, o);
  }
  if (l == 0) {
    #pragma unroll
    for (int i = 0; i < 8; ++i) wmax[w * 8 + i] = r[i];
  }
  __syncthreads();

  float a[8], bb[8];
  #pragma unroll
  for (int i = 0; i < 8; ++i) { a[i] = wmax[i]; bb[i] = wmax[8 + i]; }
  merge8(a, bb);
  #pragma unroll
  for (int i = 0; i < 8; ++i) bb[i] = wmax[16 + i];
  {
    float c2[8];
    #pragma unroll
    for (int i = 0; i < 8; ++i) c2[i] = wmax[24 + i];
    merge8(bb, c2);
  }
  merge8(a, bb);
  const float t8 = a[7];

  #pragma unroll
  for (int p = 0; p < 4; ++p) {
    const int base = 4 * (t + p * 256);
    if (vp[p].x >= t8) { int pos = atomicAdd(&cnt, 1); cand[pos] = fkey(vp[p].x, base + 0); }
    if (vp[p].y >= t8) { int pos = atomicAdd(&cnt, 1); cand[pos] = fkey(vp[p].y, base + 1); }
    if (vp[p].z >= t8) { int pos = atomicAdd(&cnt, 1); cand[pos] = fkey(vp[p].z, base + 2); }
    if (vp[p].w >= t8) { int pos = atomicAdd(&cnt, 1); cand[pos] = fkey(vp[p].w, base + 3); }
  }
  __syncthreads();

  if (w == 0) {
    const int n = cnt;
    unsigned long long prev = ~0ULL;
    float vk[8]; int ik[8];
    #pragma unroll
    for (int k = 0; k < 8; ++k) {
      unsigned long long best = 0;
      for (int i = l; i < n; i += 64) {
        unsigned long long c = cand[i];
        if (c < prev && c > best) best = c;
      }
      #pragma unroll
      for (int st = 0; st < 6; ++st) {
        const int off = 1 << st;
        unsigned bh = (unsigned)(best >> 32), bl = (unsigned)best;
        unsigned oh = __shfl_xor(bh, off), ol = __shfl_xor(bl, off);
        unsigned long long ob = ((unsigned long long)oh << 32) | ol;
        if (ob > best) best = ob;
      }
      prev = best;
      unsigned u = (unsigned)(best >> 32);
      u = (u & 0x80000000u) ? (u ^ 0x80000000u) : ~u;
      vk[k] = __uint_as_float(u);
      ik[k] = (int)(0xFFFFFFFFu - (unsigned)(best & 0xFFFFFFFFu));
    }
    if (l == 0) {
      const float mx = vk[0];
      float den = 0.f, ex[8];
      #pragma unroll
      for (int k = 0; k < 8; ++k) { ex[k] = __expf(vk[k] - mx); den += ex[k]; }
      const float inv = 1.0f / den;
      #pragma unroll
      for (int k = 0; k < 8; ++k) { wv[k] = ex[k] * inv; wi[k] = ik[k]; }
    }
  }
  __syncthreads();

  float a0 = 0, a1 = 0, a2 = 0, a3 = 0;
  #pragma unroll
  for (int k = 0; k < 8; ++k) {
    const float wk = wv[k];
    float4 vr = *(const float4*)(kV + (size_t)wi[k] * 1024 + t * 4);
    a0 += wk * vr.x; a1 += wk * vr.y; a2 += wk * vr.z; a3 += wk * vr.w;
  }
  float4* op = (float4*)(outp + (size_t)token * 1024) + t;
  float4 cur = *op;
  cur.x += a0; cur.y += a1; cur.z += a2; cur.w += a3;
  *op = cur;
}

// ---------------------------------------------------------------- launcher
extern "C" void kernel_launch(void* const* d_in, const int* in_sizes, int n_in,
                              void* d_out, int out_size, void* d_ws, size_t ws_size,
                              hipStream_t stream)
{
  (void)in_sizes; (void)n_in; (void)out_size; (void)ws_size;
  const float* x    = (const float*)d_in[0];
  const float* imp  = (const float*)d_in[1];
  const float* Wc   = (const float*)d_in[2];
  const float* WQ   = (const float*)d_in[3];
  const float* WK   = (const float*)d_in[4];
  const float* WV   = (const float*)d_in[5];
  const float* Wm   = (const float*)d_in[6];
  const float* comp = (const float*)d_in[7];
  const float* expd = (const float*)d_in[8];
  const float* kK   = (const float*)d_in[9];
  const float* kV   = (const float*)d_in[10];
  const float* WO   = (const float*)d_in[11];
  const float* g1   = (const float*)d_in[12];
  const float* b1   = (const float*)d_in[13];
  const float* g2   = (const float*)d_in[14];
  const float* b2   = (const float*)d_in[15];
  float* out = (float*)d_out;
  char* ws = (char*)d_ws;
  const size_t MB = 1u << 20;
  float* racc  = (float*)(ws);            // 20480 B
  float* rw    = (float*)(ws + 24576);
  float* Wcat  = (float*)(ws + 32768);    // 80*1024 f32 (320 KB)
  bf16*  Wcatb = (bf16*)(ws + 512 * 1024);// 128*1024 bf16 (256 KB, zero-padded)
  char* ar = ws + 1 * MB;
  bf16* nx   = (bf16*)(ar);              // 8 MB
  bf16* sct  = (bf16*)(ar +  8 * MB);    // 1 MB  [b][R][D]
  bf16* eqt  = (bf16*)(ar +  9 * MB);    // 1 MB  [b][D][R]
  bf16* ekt  = (bf16*)(ar + 10 * MB);
  bf16* evt  = (bf16*)(ar + 11 * MB);
  bf16* hb   = (bf16*)(ar + 12 * MB);    // 2 MB  [b][S][R]
  bf16* Qb   = (bf16*)(ar + 14 * MB);    // 8 MB each
  bf16* Kb   = (bf16*)(ar + 22 * MB);    // head-major [b][h][s][64]
  bf16* Vtb  = (bf16*)(ar + 30 * MB);    // 8 MB  [b][D][S]  (V transposed)
  bf16* aob  = (bf16*)(ar + 38 * MB);    // 8 MB
  bf16* WOb  = (bf16*)(ar + 46 * MB);    // 2 MB
  float* logits = (float*)(ar + 48 * MB);// 2 MB  [4096][128]
  bf16* nx2  = (bf16*)(ar);
  bf16* mct  = (bf16*)(ar +  8 * MB);
  bf16* Qmb  = (bf16*)(ar +  9 * MB);    // 2 MB
  bf16* kKb  = (bf16*)(ar + 11 * MB);    // 2 MB
  float* msb = (float*)(ar + 13 * MB);   // 64 MB (logits region overlaps its
                                         // tail but is consumed before ms GEMM)

  hipMemsetAsync(racc, 0, 20480, stream);
  hipMemcpyAsync(Wcat + 0 * 16384, Wc, 65536, hipMemcpyDeviceToDevice, stream);
  hipMemcpyAsync(Wcat + 1 * 16384, WQ, 65536, hipMemcpyDeviceToDevice, stream);
  hipMemcpyAsync(Wcat + 2 * 16384, WK, 65536, hipMemcpyDeviceToDevice, stream);
  hipMemcpyAsync(Wcat + 3 * 16384, WV, 65536, hipMemcpyDeviceToDevice, stream);
  hipMemcpyAsync(Wcat + 4 * 16384, Wm, 65536, hipMemcpyDeviceToDevice, stream);
  hipMemsetAsync(Wcatb, 0, 128 * 1024 * sizeof(bf16), stream);
  cvt_bf16_kernel<<<80, 256, 0, stream>>>(Wcat, Wcatb, 20480);

  ln_kernel<<<4096, 256, 0, stream>>>(x, g1, b1, nx);
  gemm_bt<1><<<dim3(1, 32, 1), 256, 0, stream>>>(nx, Wcatb, logits, nullptr, 4096, 128, 1024,
        0L, 0L, 0L, 1.0f);
  route_pool_kernel<<<1024, 256, 0, stream>>>(logits, imp, racc, 4, 0);
  route_norm_kernel<<<1, 256, 0, stream>>>(racc, rw, 0, 4);
  mix_t_kernel<<<dim3(16, 4, 2), 256, 0, stream>>>(comp, rw +  0, sct, 1024, 256);
  mix_t_kernel<<<dim3(4, 16, 2), 256, 0, stream>>>(expd, rw + 32, eqt, 256, 1024);
  mix_t_kernel<<<dim3(4, 16, 2), 256, 0, stream>>>(expd, rw + 64, ekt, 256, 1024);
  mix_t_kernel<<<dim3(4, 16, 2), 256, 0, stream>>>(expd, rw + 96, evt, 256, 1024);
  gemm_bt<0><<<dim3(2, 16, 2), 256, 0, stream>>>(nx, sct, hb, nullptr, 2048, 256, 1024,
        (long)2048 * 1024, (long)256 * 1024, (long)2048 * 256, 1.0f);
  gemm_bt<0><<<dim3(8, 16, 2), 256, 0, stream>>>(hb, eqt, Qb, nullptr, 2048, 1024, 256,
        (long)2048 * 256, (long)1024 * 256, (long)2048 * 1024, 1.0f);
  // K head-major + pre-scaled by 1/sqrt(dh)=0.125
  gemm_bt<3><<<dim3(8, 16, 2), 256, 0, stream>>>(hb, ekt, Kb, nullptr, 2048, 1024, 256,
        (long)2048 * 256, (long)1024 * 256, 0L, 0.125f);
  // V produced TRANSPOSED: Vt[b][d][s]
  gemm_bt<0><<<dim3(16, 8, 2), 256, 0, stream>>>(evt, hb, Vtb, nullptr, 1024, 2048, 256,
        (long)1024 * 256, (long)2048 * 256, (long)1024 * 2048, 1.0f);
  attn6_kernel<<<256, 512, 0, stream>>>(Qb, Kb, Vtb, aob);
  cvt_bf16_kernel<<<1024, 256, 0, stream>>>(WO, WOb, 262144);
  gemm_bt<2><<<dim3(8, 32, 1), 256, 0, stream>>>(aob, WOb, out, x, 4096, 1024, 1024,
        0L, 0L, 0L, 1.0f);
  ln_kernel<<<4096, 256, 0, stream>>>(out, g2, b2, nx2);
  gemm_bt<1><<<dim3(1, 32, 1), 256, 0, stream>>>(nx2, Wcatb + 64 * 1024, logits, nullptr,
        4096, 128, 1024, 0L, 0L, 0L, 1.0f);
  route_pool_kernel<<<1024, 256, 0, stream>>>(logits, imp, racc, 1, 4);
  route_norm_kernel<<<1, 256, 0, stream>>>(racc, rw, 4, 1);
  mix_t_kernel<<<dim3(16, 4, 2), 256, 0, stream>>>(comp, rw + 128, mct, 1024, 256);
  gemm_bt<0><<<dim3(2, 16, 2), 256, 0, stream>>>(nx2, mct, Qmb, nullptr, 2048, 256, 1024,
        (long)2048 * 1024, (long)256 * 1024, (long)2048 * 256, 1.0f);
  cvt_bf16_kernel<<<1024, 256, 0, stream>>>(kK, kKb, 262144);
  gemm_bt<1><<<dim3(32, 16, 2), 256, 0, stream>>>(Qmb, kKb, msb, nullptr, 2048, 4096, 256,
        (long)2048 * 256, 0L, (long)2048 * 4096, 0.0625f);
  topk2_kernel<<<4096, 256, 0, stream>>>(msb, kV, out);
}